// Round 9
// baseline (78173.975 us; speedup 1.0000x reference)
//
#include <hip/hip_runtime.h>
#include <math.h>
#include <stdint.h>

// Problem constants
#define NBATCH 16
#define NK     32
#define NTDS   768      // 3*DS
#define NMM    676      // BM*BM
#define NBM    26
#define NBB    832      // B = K*BM
#define NOCC2  128
#define NPAIR  496      // K*(K-1)/2
#define FSCALE 1.0e-4f
#define A0C    0.5291772f

// ---------------- workspace layout (in floats) ----------------
#define OFF_ACOPY 0ull
#define SZ_ACOPY  (16ull*832*832)
#define OFF_X     (OFF_ACOPY + SZ_ACOPY)
#define SZ_X      (16ull*32*768)
#define OFF_S     (OFF_X + SZ_X)
#define SZ_S      (16ull*768)
#define OFF_D     (OFF_S + SZ_S)
#define OFF_SUB   (OFF_D   + 16ull*832)
#define OFF_TAU   (OFF_SUB + 16ull*832)
#define OFF_EIG   (OFF_TAU + 16ull*832)
#define OFF_UTRI  (OFF_EIG + 16ull*832)
#define SZ_UTRI   (16ull*128*832)
#define OFF_UOCC  (OFF_UTRI + SZ_UTRI)
#define OFF_C     OFF_UTRI   /* C overlays Utri (dead after backxform) */
// tridiag scratch overlays the Utri region (Utri written only later by k_invit)
#define PB   32   // panel width
#define GW   32   // workgroups per matrix (R9: was 16)
#define NSET 2    // sequential matrix sets (8 matrices in flight at a time)
#define TPW  512  // threads per workgroup
#define QMAX 26   // max own rows per WG (832/32)
#define SLOTSTR 2176
#define OFF_WPAN  OFF_UTRI                        /* 16*832*32 = 425,984 */
#define OFF_CBUF  (OFF_WPAN + 16ull*832*32)       /* 16*832 */
#define OFF_SLOT  (OFF_CBUF + 16ull*832)          /* 16*2176 */
#define OFF_BARC  (OFF_SLOT + 16ull*SLOTSTR)      /* 16 ints */

__device__ __forceinline__ void pair_decode(int t, int& k, int& l) {
  int kk = (int)((1.0f + sqrtf(1.0f + 8.0f*(float)t)) * 0.5f);
  while (kk*(kk-1)/2 > t) --kk;
  while ((kk+1)*kk/2 <= t) ++kk;
  k = kk; l = t - kk*(kk-1)/2;
}

// Cross-WG READ: agent-scope bypass load (sc0 sc1) — reads through to the MALL
// (memory-side, unbypassable), so it observes completed bypass stores and
// wbl2-released cached stores with no acquire-invalidate.
__device__ __forceinline__ float gld(const float* p) {
  unsigned int u = __hip_atomic_load((const unsigned int*)p, __ATOMIC_RELAXED, __HIP_MEMORY_SCOPE_AGENT);
  return __uint_as_float(u);
}
// Cross-WG WRITE: agent-scope bypass store (sc0 sc1) — write-through to MALL.
// vmcnt retirement (drained by __syncthreads before the barrier flag bump)
// means the value is at the MALL before any other WG can observe the flag.
__device__ __forceinline__ void gst(float* p, float v) {
  __hip_atomic_store((unsigned int*)p, __float_as_uint(v), __ATOMIC_RELAXED, __HIP_MEMORY_SCOPE_AGENT);
}

// ---------------- x = mu @ transfer_W + b ----------------
__global__ __launch_bounds__(256) void k_x(const float* __restrict__ mu,
                                           const float* __restrict__ tW,
                                           const float* __restrict__ tb,
                                           float* __restrict__ x) {
  const int k = blockIdx.x, n = blockIdx.y, tid = threadIdx.x;
  __shared__ float mus[384];
  const float* mub = mu + (size_t)(n*NK + k)*384;
  for (int i = tid; i < 384; i += 256) mus[i] = mub[i];
  __syncthreads();
  float* xb = x + (size_t)(n*NK + k)*NTDS;
  for (int oo = tid; oo < NTDS; oo += 256) {
    const int d = oo >> 8, i = oo & 255;
    float acc = tb[i];
    const float* mrow = &mus[d*128];
    for (int a = 0; a < 128; ++a) acc += mrow[a]*tW[a*256 + i];
    xb[oo] = acc;
  }
}

// ---------------- S[n][dd] = sum_k x[n][k][dd] ----------------
__global__ __launch_bounds__(256) void k_S(const float* __restrict__ x, float* __restrict__ S) {
  const int n = blockIdx.x, tid = threadIdx.x;
  for (int dd = tid; dd < NTDS; dd += 256) {
    float s = 0.f;
    for (int k = 0; k < NK; ++k) s += x[(size_t)(n*NK + k)*NTDS + dd];
    S[n*NTDS + dd] = s;
  }
}

// ---------------- diagonal blocks ----------------
__global__ __launch_bounds__(256) void k_diag(const float* __restrict__ x, const float* __restrict__ S,
                                              const float* __restrict__ Won, const float* __restrict__ bon,
                                              const float* __restrict__ hnew, const float* __restrict__ Foff,
                                              float* __restrict__ Fout, float* __restrict__ Acopy) {
  const int k = blockIdx.x, n = blockIdx.y, tid = threadIdx.x;
  __shared__ float q[NTDS];
  __shared__ float M[NMM];
  const float* xb = x + (size_t)(n*NK + k)*NTDS;
  const float* Sb = S + n*NTDS;
  for (int i = tid; i < NTDS; i += 256) q[i] = xb[i]*Sb[i];
  __syncthreads();
  for (int m = tid; m < NMM; m += 256) {
    float acc = 32.0f * bon[m];
    for (int dd = 0; dd < NTDS; ++dd) acc += q[dd]*Won[(size_t)dd*NMM + m];
    M[m] = acc;
  }
  __syncthreads();
  const float* hb = hnew + (size_t)n*NBB*NBB;
  float* Fb = Fout + (size_t)n*NBB*NBB;
  float* Ab = Acopy + (size_t)n*NBB*NBB;
  for (int m = tid; m < NMM; m += 256) {
    const int a = m/26, b = m - a*26;
    const float val = 0.5f*(M[m] + M[b*26 + a]);
    const int P = k*26 + a, Q = k*26 + b;
    const size_t idx = (size_t)P*NBB + Q;
    const float fo = Foff[idx];
    const float hv = hb[idx];
    const float Fv = (fabsf(hv) > 1e-7f) ? (val*FSCALE + fo) : fo;
    Fb[idx] = Fv; Ab[idx] = Fv;
  }
}

// ---------------- off-diagonal blocks: GEMM over pairs ----------------
__global__ __launch_bounds__(256) void k_off(const float* __restrict__ x,
                                             const float* __restrict__ Woff, const float* __restrict__ boff,
                                             const float* __restrict__ hnew, const float* __restrict__ Foff,
                                             float* __restrict__ Fout, float* __restrict__ Acopy) {
  const int ct = blockIdx.x, pt = blockIdx.y, n = blockIdx.z;
  const int tid = threadIdx.x;
  __shared__ __align__(16) float At[32*65];
  __shared__ __align__(16) float Bt[64*128];
  __shared__ int klk[32], kll[32];
  if (tid < 32) {
    int pr = pt*32 + tid, kk = 1, ll = 0;
    if (pr < NPAIR) pair_decode(pr, kk, ll);
    klk[tid] = kk; kll[tid] = ll;
  }
  __syncthreads();
  const int ty = tid >> 5, tx = tid & 31;
  const int r0 = ty*4, c0 = tx*4;
  float acc[4][4] = {};
  for (int dd0 = 0; dd0 < NTDS; dd0 += 64) {
    for (int idx = tid; idx < 2048; idx += 256) {
      const int r = idx >> 6, c = idx & 63;
      const int pr = pt*32 + r;
      float v = 0.f;
      if (pr < NPAIR) {
        const int kk = klk[r], ll = kll[r];
        v = x[(size_t)(n*NK + kk)*NTDS + dd0 + c] * x[(size_t)(n*NK + ll)*NTDS + dd0 + c];
      }
      At[r*65 + c] = v;
    }
    for (int idx = tid; idx < 8192; idx += 256) {
      const int r = idx >> 7, c = idx & 127;
      const int col = ct*128 + c;
      Bt[idx] = (col < NMM) ? Woff[(size_t)(dd0 + r)*NMM + col] : 0.f;
    }
    __syncthreads();
    for (int kk = 0; kk < 64; ++kk) {
      float av[4];
      av[0] = At[(r0+0)*65 + kk];
      av[1] = At[(r0+1)*65 + kk];
      av[2] = At[(r0+2)*65 + kk];
      av[3] = At[(r0+3)*65 + kk];
      const float4 b4 = *(const float4*)&Bt[kk*128 + c0];
      const float bb[4] = {b4.x, b4.y, b4.z, b4.w};
      #pragma unroll
      for (int qq = 0; qq < 4; ++qq)
        #pragma unroll
        for (int pp = 0; pp < 4; ++pp)
          acc[qq][pp] += av[qq]*bb[pp];
    }
    __syncthreads();
  }
  const float* hb = hnew + (size_t)n*NBB*NBB;
  float* Fb = Fout + (size_t)n*NBB*NBB;
  float* Ab = Acopy + (size_t)n*NBB*NBB;
  for (int qq = 0; qq < 4; ++qq) {
    const int pr = pt*32 + r0 + qq;
    if (pr >= NPAIR) continue;
    const int kk = klk[r0+qq], ll = kll[r0+qq];
    for (int pp = 0; pp < 4; ++pp) {
      const int m = ct*128 + c0 + pp;
      if (m >= NMM) continue;
      const float val = acc[qq][pp] + boff[m];
      const int a = m/26, b = m - a*26;
      const int P = kk*26 + a, Q = ll*26 + b;
      const size_t i1 = (size_t)P*NBB + Q;
      const float fo1 = Foff[i1], hv1 = hb[i1];
      const float Fv1 = (fabsf(hv1) > 1e-7f) ? (val*FSCALE + fo1) : fo1;
      Fb[i1] = Fv1; Ab[i1] = Fv1;
      const size_t i2 = (size_t)Q*NBB + P;
      const float fo2 = Foff[i2], hv2 = hb[i2];
      const float Fv2 = (fabsf(hv2) > 1e-7f) ? (val*FSCALE + fo2) : fo2;
      Fb[i2] = Fv2; Ab[i2] = Fv2;
    }
  }
}

// ================= blocked (latrd) multi-WG tridiagonalization =================
// R9: R7's proven full-square matvec + syr2k (R8 symmetric variant regressed:
// yp-exchange bypass traffic + LDS atomics cost more than the saved reads).
// NEW: 32 WGs/matrix, 8 matrices in flight, 2 sequential sets per WG group.
// In-flight trailing working set: 8 x 2.77 MB = 22 MB (2.77 MB/XCD) -> fits
// L2 at EVERY panel (R7's 16-concurrent = 5.5 MB/XCD thrashed early panels,
// FETCH 2.7 GB = 7x compulsory).
// Coherence protocol unchanged from R7 (proven): gst/gld bypass for ALL
// cross-WG data; relaxed rbar per column; release gbar per panel boundary.
__device__ __forceinline__ void rbar(int* cnt, int target) {
  __syncthreads();   // emits s_waitcnt vmcnt(0) before s_barrier: bypass stores MALL-complete
  if (threadIdx.x == 0) {
    asm volatile("" ::: "memory");
    __hip_atomic_fetch_add(cnt, 1, __ATOMIC_RELAXED, __HIP_MEMORY_SCOPE_AGENT);
    while (__hip_atomic_load(cnt, __ATOMIC_RELAXED, __HIP_MEMORY_SCOPE_AGENT) < target)
      __builtin_amdgcn_s_sleep(1);
    asm volatile("" ::: "memory");
  }
  __syncthreads();
}
__device__ __forceinline__ void gbar(int* cnt, int target) {
  __syncthreads();
  if (threadIdx.x == 0) {
    __hip_atomic_fetch_add(cnt, 1, __ATOMIC_RELEASE, __HIP_MEMORY_SCOPE_AGENT);  // wbl2
    while (__hip_atomic_load(cnt, __ATOMIC_RELAXED, __HIP_MEMORY_SCOPE_AGENT) < target)
      __builtin_amdgcn_s_sleep(1);
  }
  __syncthreads();
}

__device__ __forceinline__ float wg_reduce8(float v, volatile float* sred) {
  #pragma unroll
  for (int off = 32; off > 0; off >>= 1) v += __shfl_down(v, off);
  const int tid = threadIdx.x;
  if ((tid & 63) == 0) sred[tid >> 6] = v;
  __syncthreads();
  float r = 0.f;
  #pragma unroll
  for (int t = 0; t < 8; ++t) r += sred[t];
  __syncthreads();
  return r;
}

__global__ __launch_bounds__(TPW) void k_tridiag_panel(float* __restrict__ Acopy,
                                                       float* __restrict__ dA,
                                                       float* __restrict__ subA,
                                                       float* __restrict__ tauA,
                                                       float* __restrict__ Wpan,
                                                       float* __restrict__ cbufA,
                                                       float* __restrict__ slotA,
                                                       int* __restrict__ barA) {
  const int g = blockIdx.x;          // WG within matrix (0..31)
  const int ns = blockIdx.y;         // matrix-group (0..7)
  const int tid = threadIdx.x;
  const int lane = tid & 63, wv = tid >> 6;

  __shared__ float vsh[NBB];
  __shared__ float yloc[QMAX];
  __shared__ float Vloc[QMAX*33];
  __shared__ float Wloc[QMAX*33];
  __shared__ float Vt[64*33];
  __shared__ float Wt[64*33];
  __shared__ float d1s[PB], d2s[PB], Vk1s[PB], Wk1s[PB];
  __shared__ float sred[8];
  __shared__ float s_tau, s_scale, s_vav, s_ynext;

  for (int set = 0; set < NSET; ++set) {
    const int n = ns + 8*set;
    float* A    = Acopy + (size_t)n*NBB*NBB;
    float* Wbuf = Wpan  + (size_t)n*NBB*PB;
    float* cbuf = cbufA + (size_t)n*NBB;
    float* slot = slotA + (size_t)n*SLOTSTR;
    float* normp = slot;          // [32]
    float* vavp  = slot + 32;     // [32]
    float* alphaS= slot + 64;     // [1]
    float* ynextS= slot + 65;     // [1]
    float* d1pA  = slot + 128;    // [32][32]
    float* d2pA  = slot + 1152;   // [32][32]
    int*   cnt   = barA + n;
    int ep = 0;

    // ---- prologue: c = A[:,0], norm partials, alpha (all comms via gst) ----
    {
      const int q0p = (32 - g) >> 5;   // first q with 32q+g >= 1
      float np = 0.f;
      const int q = q0p + tid;
      if (q < QMAX) {
        const int j = 32*q + g;
        const float cv = A[(size_t)j*NBB];   // own row (prior kernel, dispatch-coherent)
        gst(&cbuf[j], cv);
        if (j >= 2) np = cv*cv;
        if (j == 1) gst(alphaS, cv);
      }
      const float s = wg_reduce8(np, sred);
      if (tid == 0) gst(&normp[g], s);
    }
    ++ep; gbar(cnt, ep*GW);

    for (int k0 = 0; k0 < NBB-2; k0 += PB) {
      const int ilim = (NBB-2-k0 < PB) ? (NBB-2-k0) : PB;
      for (int i = 0; i < ilim; ++i) {
        const int k = k0 + i;
        const int m = NBB-1-k;
        const int q0 = (k + 32 - g) >> 5;   // first q with 32q+g >= k+1

        // ================= Epoch X =================
        if (tid == 0) {
          float xn2 = 0.f;
          #pragma unroll
          for (int t = 0; t < GW; ++t) xn2 += gld(&normp[t]);
          const float alpha = gld(alphaS);
          float tau, scale, beta;
          if (xn2 < 1e-26f) {
            beta = alpha; tau = 0.f; scale = 0.f;
          } else {
            beta  = -copysignf(sqrtf(alpha*alpha + xn2), alpha);
            tau   = (beta - alpha) / beta;
            scale = 1.0f / (alpha - beta);
          }
          s_tau = tau; s_scale = scale;
          if (g == 0) { subA[n*NBB + k + 1] = beta; tauA[n*NBB + k] = tau; }
        }
        __syncthreads();
        const float tau = s_tau, scale = s_scale;
        // build full v in LDS (cbuf is cross-WG -> bypass loads)
        for (int idx = tid; idx < m; idx += TPW)
          vsh[idx] = (idx == 0) ? 1.0f : gld(&cbuf[k+1+idx])*scale;
        __syncthreads();
        // store v (own entries) into row k (transposed reflector, BYPASS) + Vloc
        {
          const int q = q0 + tid;
          if (q < QMAX) {
            const int j = 32*q + g;
            const float val = vsh[j-(k+1)];
            gst(&A[(size_t)k*NBB + j], val);
            Vloc[q*33 + i] = val;
          }
        }
        // d1/d2 partials over own rows (p < i)
        for (int p = wv; p < i; p += 8) {
          float a1 = 0.f, a2 = 0.f;
          const int q = q0 + lane;
          if (q < QMAX) {
            const int j = 32*q + g;
            const float vj = vsh[j-(k+1)];
            a1 = Vloc[q*33 + p]*vj;
            a2 = Wloc[q*33 + p]*vj;
          }
          #pragma unroll
          for (int off = 32; off > 0; off >>= 1) { a1 += __shfl_down(a1, off); a2 += __shfl_down(a2, off); }
          if (lane == 0) { gst(&d1pA[g*PB + p], a1); gst(&d2pA[g*PB + p], a2); }
        }
        // matvec y = A0 v over own rows (plain cached, L2-resident)
        float vavl = 0.f;
        for (int q = q0 + wv; q < QMAX; q += 8) {
          const int j = 32*q + g;
          const float* Ar = A + (size_t)j*NBB;
          float acc = 0.f;
          for (int c = k+1+lane; c < NBB; c += 64) acc += Ar[c]*vsh[c-(k+1)];
          #pragma unroll
          for (int off = 32; off > 0; off >>= 1) acc += __shfl_down(acc, off);
          if (lane == 0) {
            yloc[q] = acc;
            vavl += vsh[j-(k+1)]*acc;
            if (j == k+1) gst(ynextS, acc);
          }
        }
        const float vv = wg_reduce8(vavl, sred);
        if (tid == 0) gst(&vavp[g], vv);
        ++ep; rbar(cnt, ep*GW);

        // ================= Epoch Y =================
        if (tid < i) {
          float s1 = 0.f, s2 = 0.f;
          #pragma unroll
          for (int g2 = 0; g2 < GW; ++g2) { s1 += gld(&d1pA[g2*PB + tid]); s2 += gld(&d2pA[g2*PB + tid]); }
          d1s[tid] = s1; d2s[tid] = s2;
          Vk1s[tid] = gld(&A[(size_t)(k0+tid)*NBB + (k+1)]);
          Wk1s[tid] = gld(&Wbuf[(size_t)(k+1)*PB + tid]);
        }
        if (tid == TPW-1) {
          float sv = 0.f;
          #pragma unroll
          for (int t = 0; t < GW; ++t) sv += gld(&vavp[t]);
          s_vav = sv; s_ynext = gld(ynextS);
        }
        __syncthreads();
        // redundant scalars
        float s12 = 0.f, wk1acc = 0.f;
        for (int p = 0; p < i; ++p) { s12 += d1s[p]*d2s[p]; wk1acc += Vk1s[p]*d2s[p] + Wk1s[p]*d1s[p]; }
        const float corr = 0.5f*tau*tau*(s_vav - 2.f*s12);
        const float wk1 = tau*(s_ynext - wk1acc) - corr;
        // own-row w, then c' for column k+1
        {
          const int q = q0 + tid;
          float np = 0.f;
          if (q < QMAX) {
            const int j = 32*q + g;
            float wacc = 0.f;
            for (int p = 0; p < i; ++p) wacc += Vloc[q*33 + p]*d2s[p] + Wloc[q*33 + p]*d1s[p];
            const float vj = vsh[j-(k+1)];
            const float wj = tau*(yloc[q] - wacc) - corr*vj;
            Wloc[q*33 + i] = wj;
            gst(&Wbuf[(size_t)j*PB + i], wj);
            if (j >= k+2) {
              float cacc = 0.f;
              for (int p = 0; p < i; ++p) cacc += Vloc[q*33 + p]*Wk1s[p] + Wloc[q*33 + p]*Vk1s[p];
              cacc += vj*wk1 + wj;   // p = i term (V[k+1,i] = 1)
              const float cp = A[(size_t)j*NBB + (k+1)] - cacc;   // own row, clean cached
              gst(&cbuf[j], cp);
              if (j >= k+3) np = cp*cp;
              if (j == k+2) gst(alphaS, cp);
            }
          }
          const float ns2 = wg_reduce8(np, sred);
          if (tid == 0) gst(&normp[g], ns2);
        }
        // diagonal extraction d[k] (own row plain; cross-WG data via bypass)
        if (g == (k & 31) && tid == 0) {
          float dk = A[(size_t)k*NBB + k];
          for (int p = 0; p < i; ++p)
            dk -= 2.f * gld(&A[(size_t)(k0+p)*NBB + k]) * gld(&Wbuf[(size_t)k*PB + p]);
          dA[n*NBB + k] = dk;
        }
        ++ep; rbar(cnt, ep*GW);
      }

      // ================= syr2k: A22 -= V W^T + W V^T =================
      if (k0 + PB < NBB-2) {
        const int kp = k0 + PB;
        const int q0s = (kp + 31 - g) >> 5;   // first q with 32q+g >= kp
        for (int c0 = kp+1; c0 < NBB; c0 += 64) {
          const int nc = (NBB - c0 < 64) ? (NBB - c0) : 64;
          for (int r = 0; r < 4; ++r) {
            const int idx = r*TPW + tid;
            { const int p = idx >> 6, cc = idx & 63;
              Vt[cc*33 + p] = (cc < nc) ? gld(&A[(size_t)(k0+p)*NBB + c0 + cc]) : 0.f; }
            { const int p = idx & 31, cc = (idx >> 5) & 63;
              Wt[cc*33 + p] = (cc < nc) ? gld(&Wbuf[(size_t)(c0+cc)*PB + p]) : 0.f; }
          }
          __syncthreads();
          for (int q = q0s + wv; q < QMAX; q += 8) {
            const int j = 32*q + g;
            if (lane < nc) {
              const int c = c0 + lane;
              float acc = 0.f;
              #pragma unroll
              for (int p = 0; p < PB; ++p)
                acc += Vloc[q*33 + p]*Wt[lane*33 + p] + Wloc[q*33 + p]*Vt[lane*33 + p];
              A[(size_t)j*NBB + c] -= acc;   // own row, cached (cleaned below)
            }
          }
          __syncthreads();
        }
        // diagonal entry [kp][kp]
        if (g == (kp & 31) && tid == 0) {
          const int qd = kp >> 5;
          float acc = 0.f;
          #pragma unroll
          for (int p = 0; p < PB; ++p) acc += Vloc[qd*33 + p]*Wloc[qd*33 + p];
          A[(size_t)kp*NBB + kp] -= 2.f*acc;
        }
        ++ep; gbar(cnt, ep*GW);   // RELEASE: clean syr2k dirt before next panel's gst reflectors
      }
    }

    // ---- epilogue (cross-WG data via bypass loads) ----
    if (g == 0 && tid == 0) {
      const int k0l = ((NBB-3)/PB)*PB;       // 800
      const int np_ = NBB-2-k0l;             // 30
      float dm2 = gld(&A[(size_t)(NBB-2)*NBB + (NBB-2)]);
      float dm1 = gld(&A[(size_t)(NBB-1)*NBB + (NBB-1)]);
      for (int p = 0; p < np_; ++p) {
        dm2 -= 2.f * gld(&A[(size_t)(k0l+p)*NBB + (NBB-2)]) * gld(&Wbuf[(size_t)(NBB-2)*PB + p]);
        dm1 -= 2.f * gld(&A[(size_t)(k0l+p)*NBB + (NBB-1)]) * gld(&Wbuf[(size_t)(NBB-1)*PB + p]);
      }
      dA[n*NBB + NBB-2] = dm2;
      dA[n*NBB + NBB-1] = dm1;
      subA[n*NBB + NBB-1] = gld(alphaS);
      subA[n*NBB + 0] = 0.f;
      tauA[n*NBB + NBB-2] = 0.f;
      tauA[n*NBB + NBB-1] = 0.f;
    }
  }
}

// ---------------- all eigenvalues via bisection (Sturm counts) ----------------
__global__ __launch_bounds__(256) void k_bisect(const float* __restrict__ dA, const float* __restrict__ subA,
                                                float* __restrict__ eig, float* __restrict__ e_out) {
  const int n = blockIdx.y;
  const int i = blockIdx.x*256 + threadIdx.x;
  __shared__ float ds[NBB], ss[NBB];
  const float* dg = dA + n*NBB;
  const float* sg = subA + n*NBB;
  for (int j = threadIdx.x; j < NBB; j += 256) { ds[j] = dg[j]; ss[j] = sg[j]; }
  __syncthreads();
  if (i >= NBB) return;
  float lo = 1e30f, hi = -1e30f;
  for (int j = 0; j < NBB; ++j) {
    const float r = fabsf(ss[j]) + ((j+1 < NBB) ? fabsf(ss[j+1]) : 0.f);
    lo = fminf(lo, ds[j]-r); hi = fmaxf(hi, ds[j]+r);
  }
  const float pad = 1e-3f*(hi-lo) + 1e-3f;
  lo -= pad; hi += pad;
  for (int it = 0; it < 38; ++it) {
    const float mid = 0.5f*(lo+hi);
    int cnt = 0;
    float qv = ds[0]-mid;
    if (qv < 0.f) cnt++;
    for (int j = 1; j < NBB; ++j) {
      const float e = ss[j];
      if (fabsf(qv) < 1e-20f) qv = -1e-20f;
      qv = ds[j]-mid - e*e/qv;
      if (qv < 0.f) cnt++;
    }
    if (cnt > i) hi = mid; else lo = mid;
  }
  const float lam = 0.5f*(lo+hi);
  eig[n*NBB + i] = lam;
  e_out[n*NBB + i] = lam;
}

// ---------------- inverse iteration on T for the 128 lowest ----------------
__global__ __launch_bounds__(64) void k_invit(const float* __restrict__ dA, const float* __restrict__ subA,
                                              const float* __restrict__ eig, float* __restrict__ Utri) {
  const int i = blockIdx.x, n = blockIdx.y;
  const int lane = threadIdx.x;
  __shared__ float ds[NBB], ss[NBB], ud[NBB], u1[NBB], u2[NBB], yv[NBB], xv[NBB];
  const float* dg = dA + n*NBB;
  const float* sg = subA + n*NBB;
  for (int j = lane; j < NBB; j += 64) { ds[j] = dg[j]; ss[j] = sg[j]; }
  const float lam = eig[n*NBB + i];
  for (int j = lane; j < NBB; j += 64) {
    uint32_t s = (uint32_t)(j*2654435761u) ^ (uint32_t)(i*40503u + 977u) ^ (uint32_t)(n*9973u);
    s ^= s >> 16; s *= 0x7feb352dU; s ^= s >> 15; s *= 0x846ca68bU; s ^= s >> 16;
    yv[j] = 0.5f + (float)(s & 0xFFFF) * (1.0f/65536.0f);
  }
  __syncthreads();
  const float PIV = 3e-6f;
  for (int pass = 0; pass < 2; ++pass) {
    if (lane == 0) {
      float cd = ds[0] - lam;
      float cu = ss[1];
      float cy = yv[0];
      for (int j = 0; j < NBB-1; ++j) {
        const float bl = ss[j+1];
        const float bd = ds[j+1] - lam;
        const float bu = (j+2 < NBB) ? ss[j+2] : 0.f;
        const float yb = yv[j+1];
        float tud, tu1, tu2, tm, ncd, ncu, ny;
        if (fabsf(bl) > fabsf(cd)) {
          tud = bl; tu1 = bd; tu2 = bu;
          if (fabsf(tud) < PIV) tud = (tud < 0.f) ? -PIV : PIV;
          tm  = cd / tud;
          ncd = cu - tm*bd;
          ncu = -tm*bu;
          ny  = cy - tm*yb;
          yv[j] = yb;
        } else {
          tud = cd; tu1 = cu; tu2 = 0.f;
          if (fabsf(tud) < PIV) tud = (tud < 0.f) ? -PIV : PIV;
          tm  = bl / tud;
          ncd = bd - tm*cu;
          ncu = bu;
          ny  = yb - tm*cy;
          yv[j] = cy;
        }
        ud[j] = tud; u1[j] = tu1; u2[j] = tu2;
        cd = ncd; cu = ncu; cy = ny;
      }
      if (fabsf(cd) < PIV) cd = (cd < 0.f) ? -PIV : PIV;
      ud[NBB-1] = cd; u1[NBB-1] = 0.f; u2[NBB-1] = 0.f; yv[NBB-1] = cy;
      float x2 = yv[NBB-1]/ud[NBB-1];
      xv[NBB-1] = x2;
      float x1 = (yv[NBB-2] - u1[NBB-2]*x2)/ud[NBB-2];
      xv[NBB-2] = x1;
      for (int j = NBB-3; j >= 0; --j) {
        const float xj = (yv[j] - u1[j]*x1 - u2[j]*x2)/ud[j];
        xv[j] = xj;
        x2 = x1; x1 = xj;
      }
    }
    __syncthreads();
    float p2 = 0.f;
    for (int j = lane; j < NBB; j += 64) { const float t = xv[j]; p2 += t*t; }
    #pragma unroll
    for (int off = 32; off > 0; off >>= 1) p2 += __shfl_xor(p2, off);
    const float rin = rsqrtf(p2);
    if (pass == 0) {
      for (int j = lane; j < NBB; j += 64) yv[j] = xv[j]*rin;
      __syncthreads();
    } else {
      float* Ub = Utri + ((size_t)n*NOCC2 + i)*NBB;
      for (int j = lane; j < NBB; j += 64) Ub[j] = xv[j]*rin;
    }
  }
}

// ---------------- back-transform: Uocc = H0...H829 * Utri ----------------
#define RPT 104
__global__ __launch_bounds__(512, 2) void k_backxform(const float* __restrict__ Acopy,
                                                      const float* __restrict__ tauA,
                                                      const float* __restrict__ Utri,
                                                      float* __restrict__ Uocc) {
  const int cg = blockIdx.x;         // column half (0/1)
  const int n = blockIdx.y;
  const int tid = threadIdx.x;
  const int jc = tid & 63, g = tid >> 6;   // 8 row-groups x 104 rows
  const int col = cg*64 + jc;
  __shared__ float vlds[NBB];
  __shared__ float sred[8*64];
  const float* A = Acopy + (size_t)n*NBB*NBB;
  float U[RPT];
  const float* Ut = Utri + ((size_t)n*NOCC2 + col)*NBB + g*RPT;
  #pragma unroll
  for (int rr = 0; rr < RPT; ++rr) U[rr] = Ut[rr];
  const int rbase = g*RPT;
  for (int k = NBB-3; k >= 0; --k) {
    const float tau = tauA[n*NBB + k];
    if (tau == 0.f) continue;
    const int m = NBB-1-k;
    // transposed reflector storage: v lives in row k, cols k+1..
    for (int idx = tid; idx < m; idx += 512) vlds[idx] = A[(size_t)k*NBB + (k+1+idx)];
    __syncthreads();
    float part = 0.f;
    #pragma unroll
    for (int rr = 0; rr < RPT; ++rr) {
      const int r = rbase + rr;
      if (r > k) part += U[rr]*vlds[r-k-1];
    }
    sred[g*64 + jc] = part;
    __syncthreads();
    float ssum = 0.f;
    #pragma unroll
    for (int t = 0; t < 8; ++t) ssum += sred[t*64 + jc];
    const float s = tau*ssum;
    #pragma unroll
    for (int rr = 0; rr < RPT; ++rr) {
      const int r = rbase + rr;
      if (r > k) U[rr] -= s*vlds[r-k-1];
    }
    __syncthreads();
  }
  float* Ub = Uocc + (size_t)n*NBB*NOCC2;
  #pragma unroll
  for (int rr = 0; rr < RPT; ++rr) Ub[(size_t)(rbase+rr)*NOCC2 + col] = U[rr];
}

// ---------------- C = h_new * Uocc  (832x832 @ 832x128 per batch) ----------------
__global__ __launch_bounds__(256) void k_gemmC(const float* __restrict__ h,
                                               const float* __restrict__ Uocc,
                                               float* __restrict__ C) {
  const int rt = blockIdx.x, n = blockIdx.y;
  const int tid = threadIdx.x;
  __shared__ __align__(16) float hT[64*33];
  __shared__ __align__(16) float Ut[32*128];
  const int ty = tid >> 5, tx = tid & 31;
  float acc[8][4] = {};
  const float* hb = h + (size_t)n*NBB*NBB + (size_t)rt*64*NBB;
  const float* Ub = Uocc + (size_t)n*NBB*NOCC2;
  for (int k0 = 0; k0 < NBB; k0 += 32) {
    for (int idx = tid; idx < 64*32; idx += 256) {
      const int r = idx >> 5, c = idx & 31;
      hT[r*33 + c] = hb[(size_t)r*NBB + k0 + c];
    }
    for (int idx = tid; idx < 32*128; idx += 256) {
      const int r = idx >> 7, c = idx & 127;
      Ut[idx] = Ub[(size_t)(k0 + r)*NOCC2 + c];
    }
    __syncthreads();
    for (int kk = 0; kk < 32; ++kk) {
      const float4 b4 = *(const float4*)&Ut[kk*128 + tx*4];
      #pragma unroll
      for (int q = 0; q < 8; ++q) {
        const float a = hT[(ty*8 + q)*33 + kk];
        acc[q][0] += a*b4.x; acc[q][1] += a*b4.y; acc[q][2] += a*b4.z; acc[q][3] += a*b4.w;
      }
    }
    __syncthreads();
  }
  float* Cb = C + (size_t)n*NBB*NOCC2;
  #pragma unroll
  for (int q = 0; q < 8; ++q)
    #pragma unroll
    for (int p = 0; p < 4; ++p)
      Cb[(size_t)(rt*64 + ty*8 + q)*NOCC2 + tx*4 + p] = acc[q][p];
}

// ---------------- E = sum(e_occ) + Tr(Uocc^T h Uocc) + nuc ----------------
__global__ __launch_bounds__(256) void k_final(const float* __restrict__ eig,
                                               const float* __restrict__ Uocc, const float* __restrict__ C,
                                               const float* __restrict__ pos, const int* __restrict__ numbers,
                                               float* __restrict__ E_out) {
  const int n = blockIdx.x, tid = threadIdx.x;
  __shared__ float rb[256];
  float local = 0.f;
  for (int i = tid; i < NOCC2; i += 256) local += eig[n*NBB + i];
  const float* Ub = Uocc + (size_t)n*NBB*NOCC2;
  const float* Cb = C + (size_t)n*NBB*NOCC2;
  for (int idx = tid; idx < NBB*NOCC2; idx += 256) local += Ub[idx]*Cb[idx];
  float ln = 0.f;
  for (int t = tid; t < NPAIR; t += 256) {
    int kk, ll;
    pair_decode(t, kk, ll);
    const float dx = pos[(n*NK + kk)*3 + 0] - pos[(n*NK + ll)*3 + 0];
    const float dy = pos[(n*NK + kk)*3 + 1] - pos[(n*NK + ll)*3 + 1];
    const float dz = pos[(n*NK + kk)*3 + 2] - pos[(n*NK + ll)*3 + 2];
    const float d2 = dx*dx + dy*dy + dz*dz;
    const float Z = (float)(numbers[kk]*numbers[ll]);
    ln += Z / sqrtf(d2);
  }
  local += ln * A0C;
  rb[tid] = local;
  __syncthreads();
  for (int s = 128; s > 0; s >>= 1) {
    if (tid < s) rb[tid] += rb[tid + s];
    __syncthreads();
  }
  if (tid == 0) E_out[n] = rb[0];
}

extern "C" void kernel_launch(void* const* d_in, const int* in_sizes, int n_in,
                              void* d_out, int out_size, void* d_ws, size_t ws_size,
                              hipStream_t stream) {
  (void)in_sizes; (void)n_in; (void)out_size; (void)ws_size;
  const float* mu      = (const float*)d_in[0];
  const float* hnew    = (const float*)d_in[1];
  const float* pos     = (const float*)d_in[2];
  const float* Foff    = (const float*)d_in[3];
  const float* tW      = (const float*)d_in[4];
  const float* tb      = (const float*)d_in[5];
  const float* Won     = (const float*)d_in[6];
  const float* bon     = (const float*)d_in[7];
  const float* Woff    = (const float*)d_in[8];
  const float* boff    = (const float*)d_in[9];
  const int*   numbers = (const int*)d_in[10];

  float* out   = (float*)d_out;
  float* Fout  = out;                               // [16][832][832]
  float* e_out = out + (size_t)NBATCH*NBB*NBB;      // [16][832]
  float* E_out = e_out + (size_t)NBATCH*NBB;        // [16]

  float* ws    = (float*)d_ws;
  float* Acopy = ws + OFF_ACOPY;
  float* xbuf  = ws + OFF_X;
  float* Sbuf  = ws + OFF_S;
  float* dA    = ws + OFF_D;
  float* subA  = ws + OFF_SUB;
  float* tauA  = ws + OFF_TAU;
  float* eig   = ws + OFF_EIG;
  float* Utri  = ws + OFF_UTRI;
  float* Uocc  = ws + OFF_UOCC;
  float* Cbuf  = ws + OFF_C;     // overlays Utri
  float* Wpan  = ws + OFF_WPAN;  // overlays Utri (dead until k_invit)
  float* cbufA = ws + OFF_CBUF;
  float* slotA = ws + OFF_SLOT;
  int*   barA  = (int*)(ws + OFF_BARC);

  // zero the per-matrix barrier counters (graph-captured; runs every replay)
  hipMemsetAsync((void*)barA, 0, NBATCH*sizeof(int), stream);

  k_x<<<dim3(NK, NBATCH), dim3(256), 0, stream>>>(mu, tW, tb, xbuf);
  k_S<<<dim3(NBATCH), dim3(256), 0, stream>>>(xbuf, Sbuf);
  k_diag<<<dim3(NK, NBATCH), dim3(256), 0, stream>>>(xbuf, Sbuf, Won, bon, hnew, Foff, Fout, Acopy);
  k_off<<<dim3(6, 16, NBATCH), dim3(256), 0, stream>>>(xbuf, Woff, boff, hnew, Foff, Fout, Acopy);
  k_tridiag_panel<<<dim3(GW, NBATCH/NSET), dim3(TPW), 0, stream>>>(Acopy, dA, subA, tauA, Wpan, cbufA, slotA, barA);
  k_bisect<<<dim3(4, NBATCH), dim3(256), 0, stream>>>(dA, subA, eig, e_out);
  k_invit<<<dim3(NOCC2, NBATCH), dim3(64), 0, stream>>>(dA, subA, eig, Utri);
  k_backxform<<<dim3(2, NBATCH), dim3(512), 0, stream>>>(Acopy, tauA, Utri, Uocc);
  k_gemmC<<<dim3(13, NBATCH), dim3(256), 0, stream>>>(hnew, Uocc, Cbuf);
  k_final<<<dim3(NBATCH), dim3(256), 0, stream>>>(eig, Uocc, Cbuf, pos, numbers, E_out);
}

// Round 10
// 40938.208 us; speedup vs baseline: 1.9096x; 1.9096x over previous
//
#include <hip/hip_runtime.h>
#include <math.h>
#include <stdint.h>

// Problem constants
#define NBATCH 16
#define NK     32
#define NTDS   768      // 3*DS
#define NMM    676      // BM*BM
#define NBM    26
#define NBB    832      // B = K*BM
#define NOCC2  128
#define NPAIR  496      // K*(K-1)/2
#define FSCALE 1.0e-4f
#define A0C    0.5291772f

// ---------------- workspace layout (in floats) ----------------
#define OFF_ACOPY 0ull
#define SZ_ACOPY  (16ull*832*832)
#define OFF_X     (OFF_ACOPY + SZ_ACOPY)
#define SZ_X      (16ull*32*768)
#define OFF_S     (OFF_X + SZ_X)
#define SZ_S      (16ull*768)
#define OFF_D     (OFF_S + SZ_S)
#define OFF_SUB   (OFF_D   + 16ull*832)
#define OFF_TAU   (OFF_SUB + 16ull*832)
#define OFF_EIG   (OFF_TAU + 16ull*832)
#define OFF_UTRI  (OFF_EIG + 16ull*832)
#define SZ_UTRI   (16ull*128*832)
#define OFF_UOCC  (OFF_UTRI + SZ_UTRI)
#define OFF_C     OFF_UTRI   /* C overlays Utri (dead after backxform) */
// tridiag scratch overlays the Utri region (Utri written only later by k_invit)
#define PB   32   // panel width
#define GW   16   // workgroups per matrix (R7-proven config)
#define TPW  1024 // threads per workgroup (R10: was 512 — halves matvec work/wave)
#define NWV  16   // waves per WG
#define QMAX 52   // max own rows per WG (832/16)
#define SLOTSTR 1088
#define OFF_WPAN  OFF_UTRI                        /* 16*832*32 = 425,984 */
#define OFF_CBUF  (OFF_WPAN + 16ull*832*32)       /* 16*832 */
#define OFF_SLOT  (OFF_CBUF + 16ull*832)          /* 16*1088 */
#define OFF_BARC  (OFF_SLOT + 16ull*SLOTSTR)      /* 16 ints */

__device__ __forceinline__ void pair_decode(int t, int& k, int& l) {
  int kk = (int)((1.0f + sqrtf(1.0f + 8.0f*(float)t)) * 0.5f);
  while (kk*(kk-1)/2 > t) --kk;
  while ((kk+1)*kk/2 <= t) ++kk;
  k = kk; l = t - kk*(kk-1)/2;
}

// Cross-WG READ: agent-scope bypass load (sc0 sc1) — reads through to the MALL
// (memory-side, unbypassable), so it observes completed bypass stores and
// wbl2-released cached stores with no acquire-invalidate.
__device__ __forceinline__ float gld(const float* p) {
  unsigned int u = __hip_atomic_load((const unsigned int*)p, __ATOMIC_RELAXED, __HIP_MEMORY_SCOPE_AGENT);
  return __uint_as_float(u);
}
// Cross-WG WRITE: agent-scope bypass store (sc0 sc1) — write-through to MALL.
// vmcnt retirement (drained by __syncthreads before the barrier flag bump)
// means the value is at the MALL before any other WG can observe the flag.
__device__ __forceinline__ void gst(float* p, float v) {
  __hip_atomic_store((unsigned int*)p, __float_as_uint(v), __ATOMIC_RELAXED, __HIP_MEMORY_SCOPE_AGENT);
}

// ---------------- x = mu @ transfer_W + b ----------------
__global__ __launch_bounds__(256) void k_x(const float* __restrict__ mu,
                                           const float* __restrict__ tW,
                                           const float* __restrict__ tb,
                                           float* __restrict__ x) {
  const int k = blockIdx.x, n = blockIdx.y, tid = threadIdx.x;
  __shared__ float mus[384];
  const float* mub = mu + (size_t)(n*NK + k)*384;
  for (int i = tid; i < 384; i += 256) mus[i] = mub[i];
  __syncthreads();
  float* xb = x + (size_t)(n*NK + k)*NTDS;
  for (int oo = tid; oo < NTDS; oo += 256) {
    const int d = oo >> 8, i = oo & 255;
    float acc = tb[i];
    const float* mrow = &mus[d*128];
    for (int a = 0; a < 128; ++a) acc += mrow[a]*tW[a*256 + i];
    xb[oo] = acc;
  }
}

// ---------------- S[n][dd] = sum_k x[n][k][dd] ----------------
__global__ __launch_bounds__(256) void k_S(const float* __restrict__ x, float* __restrict__ S) {
  const int n = blockIdx.x, tid = threadIdx.x;
  for (int dd = tid; dd < NTDS; dd += 256) {
    float s = 0.f;
    for (int k = 0; k < NK; ++k) s += x[(size_t)(n*NK + k)*NTDS + dd];
    S[n*NTDS + dd] = s;
  }
}

// ---------------- diagonal blocks ----------------
__global__ __launch_bounds__(256) void k_diag(const float* __restrict__ x, const float* __restrict__ S,
                                              const float* __restrict__ Won, const float* __restrict__ bon,
                                              const float* __restrict__ hnew, const float* __restrict__ Foff,
                                              float* __restrict__ Fout, float* __restrict__ Acopy) {
  const int k = blockIdx.x, n = blockIdx.y, tid = threadIdx.x;
  __shared__ float q[NTDS];
  __shared__ float M[NMM];
  const float* xb = x + (size_t)(n*NK + k)*NTDS;
  const float* Sb = S + n*NTDS;
  for (int i = tid; i < NTDS; i += 256) q[i] = xb[i]*Sb[i];
  __syncthreads();
  for (int m = tid; m < NMM; m += 256) {
    float acc = 32.0f * bon[m];
    for (int dd = 0; dd < NTDS; ++dd) acc += q[dd]*Won[(size_t)dd*NMM + m];
    M[m] = acc;
  }
  __syncthreads();
  const float* hb = hnew + (size_t)n*NBB*NBB;
  float* Fb = Fout + (size_t)n*NBB*NBB;
  float* Ab = Acopy + (size_t)n*NBB*NBB;
  for (int m = tid; m < NMM; m += 256) {
    const int a = m/26, b = m - a*26;
    const float val = 0.5f*(M[m] + M[b*26 + a]);
    const int P = k*26 + a, Q = k*26 + b;
    const size_t idx = (size_t)P*NBB + Q;
    const float fo = Foff[idx];
    const float hv = hb[idx];
    const float Fv = (fabsf(hv) > 1e-7f) ? (val*FSCALE + fo) : fo;
    Fb[idx] = Fv; Ab[idx] = Fv;
  }
}

// ---------------- off-diagonal blocks: GEMM over pairs ----------------
__global__ __launch_bounds__(256) void k_off(const float* __restrict__ x,
                                             const float* __restrict__ Woff, const float* __restrict__ boff,
                                             const float* __restrict__ hnew, const float* __restrict__ Foff,
                                             float* __restrict__ Fout, float* __restrict__ Acopy) {
  const int ct = blockIdx.x, pt = blockIdx.y, n = blockIdx.z;
  const int tid = threadIdx.x;
  __shared__ __align__(16) float At[32*65];
  __shared__ __align__(16) float Bt[64*128];
  __shared__ int klk[32], kll[32];
  if (tid < 32) {
    int pr = pt*32 + tid, kk = 1, ll = 0;
    if (pr < NPAIR) pair_decode(pr, kk, ll);
    klk[tid] = kk; kll[tid] = ll;
  }
  __syncthreads();
  const int ty = tid >> 5, tx = tid & 31;
  const int r0 = ty*4, c0 = tx*4;
  float acc[4][4] = {};
  for (int dd0 = 0; dd0 < NTDS; dd0 += 64) {
    for (int idx = tid; idx < 2048; idx += 256) {
      const int r = idx >> 6, c = idx & 63;
      const int pr = pt*32 + r;
      float v = 0.f;
      if (pr < NPAIR) {
        const int kk = klk[r], ll = kll[r];
        v = x[(size_t)(n*NK + kk)*NTDS + dd0 + c] * x[(size_t)(n*NK + ll)*NTDS + dd0 + c];
      }
      At[r*65 + c] = v;
    }
    for (int idx = tid; idx < 8192; idx += 256) {
      const int r = idx >> 7, c = idx & 127;
      const int col = ct*128 + c;
      Bt[idx] = (col < NMM) ? Woff[(size_t)(dd0 + r)*NMM + col] : 0.f;
    }
    __syncthreads();
    for (int kk = 0; kk < 64; ++kk) {
      float av[4];
      av[0] = At[(r0+0)*65 + kk];
      av[1] = At[(r0+1)*65 + kk];
      av[2] = At[(r0+2)*65 + kk];
      av[3] = At[(r0+3)*65 + kk];
      const float4 b4 = *(const float4*)&Bt[kk*128 + c0];
      const float bb[4] = {b4.x, b4.y, b4.z, b4.w};
      #pragma unroll
      for (int qq = 0; qq < 4; ++qq)
        #pragma unroll
        for (int pp = 0; pp < 4; ++pp)
          acc[qq][pp] += av[qq]*bb[pp];
    }
    __syncthreads();
  }
  const float* hb = hnew + (size_t)n*NBB*NBB;
  float* Fb = Fout + (size_t)n*NBB*NBB;
  float* Ab = Acopy + (size_t)n*NBB*NBB;
  for (int qq = 0; qq < 4; ++qq) {
    const int pr = pt*32 + r0 + qq;
    if (pr >= NPAIR) continue;
    const int kk = klk[r0+qq], ll = kll[r0+qq];
    for (int pp = 0; pp < 4; ++pp) {
      const int m = ct*128 + c0 + pp;
      if (m >= NMM) continue;
      const float val = acc[qq][pp] + boff[m];
      const int a = m/26, b = m - a*26;
      const int P = kk*26 + a, Q = ll*26 + b;
      const size_t i1 = (size_t)P*NBB + Q;
      const float fo1 = Foff[i1], hv1 = hb[i1];
      const float Fv1 = (fabsf(hv1) > 1e-7f) ? (val*FSCALE + fo1) : fo1;
      Fb[i1] = Fv1; Ab[i1] = Fv1;
      const size_t i2 = (size_t)Q*NBB + P;
      const float fo2 = Foff[i2], hv2 = hb[i2];
      const float Fv2 = (fabsf(hv2) > 1e-7f) ? (val*FSCALE + fo2) : fo2;
      Fb[i2] = Fv2; Ab[i2] = Fv2;
    }
  }
}

// ================= blocked (latrd) multi-WG tridiagonalization =================
// R10 = R7-proven structure (GW=16, all 16 matrices concurrent, full-square
// matvec + syr2k) with TPW 512->1024: halves matvec rows/wave and doubles
// outstanding loads. R9 lesson: fewer matrices in flight cut FETCH 3.2x but
// per-epoch time is work+chain-latency, so epoch COUNT is what matters.
// Coherence protocol unchanged (proven R7): gst/gld bypass for ALL cross-WG
// data; relaxed rbar per column; release gbar per panel boundary.
__device__ __forceinline__ void rbar(int* cnt, int target) {
  __syncthreads();   // emits s_waitcnt vmcnt(0) before s_barrier: bypass stores MALL-complete
  if (threadIdx.x == 0) {
    asm volatile("" ::: "memory");
    __hip_atomic_fetch_add(cnt, 1, __ATOMIC_RELAXED, __HIP_MEMORY_SCOPE_AGENT);
    while (__hip_atomic_load(cnt, __ATOMIC_RELAXED, __HIP_MEMORY_SCOPE_AGENT) < target)
      __builtin_amdgcn_s_sleep(1);
    asm volatile("" ::: "memory");
  }
  __syncthreads();
}
__device__ __forceinline__ void gbar(int* cnt, int target) {
  __syncthreads();
  if (threadIdx.x == 0) {
    __hip_atomic_fetch_add(cnt, 1, __ATOMIC_RELEASE, __HIP_MEMORY_SCOPE_AGENT);  // wbl2
    while (__hip_atomic_load(cnt, __ATOMIC_RELAXED, __HIP_MEMORY_SCOPE_AGENT) < target)
      __builtin_amdgcn_s_sleep(1);
  }
  __syncthreads();
}

__device__ __forceinline__ float wg_reduce16(float v, volatile float* sred) {
  #pragma unroll
  for (int off = 32; off > 0; off >>= 1) v += __shfl_down(v, off);
  const int tid = threadIdx.x;
  if ((tid & 63) == 0) sred[tid >> 6] = v;
  __syncthreads();
  float r = 0.f;
  #pragma unroll
  for (int t = 0; t < NWV; ++t) r += sred[t];
  __syncthreads();
  return r;
}

__global__ __launch_bounds__(TPW) void k_tridiag_panel(float* __restrict__ Acopy,
                                                       float* __restrict__ dA,
                                                       float* __restrict__ subA,
                                                       float* __restrict__ tauA,
                                                       float* __restrict__ Wpan,
                                                       float* __restrict__ cbufA,
                                                       float* __restrict__ slotA,
                                                       int* __restrict__ barA) {
  const int g = blockIdx.x;          // WG within matrix
  const int n = blockIdx.y;          // matrix
  const int tid = threadIdx.x;
  const int lane = tid & 63, wv = tid >> 6;
  float* A    = Acopy + (size_t)n*NBB*NBB;
  float* Wbuf = Wpan  + (size_t)n*NBB*PB;
  float* cbuf = cbufA + (size_t)n*NBB;
  float* slot = slotA + (size_t)n*SLOTSTR;
  float* normp = slot;          // [16]
  float* vavp  = slot + 16;     // [16]
  float* alphaS= slot + 32;     // [1]
  float* ynextS= slot + 33;     // [1]
  float* d1pA  = slot + 64;     // [16][32]
  float* d2pA  = slot + 576;    // [16][32]
  int*   cnt   = barA + n;

  __shared__ float vsh[NBB];
  __shared__ float yloc[QMAX];
  __shared__ float Vloc[QMAX*33];
  __shared__ float Wloc[QMAX*33];
  __shared__ float Vt[64*33];
  __shared__ float Wt[64*33];
  __shared__ float d1s[PB], d2s[PB], Vk1s[PB], Wk1s[PB];
  __shared__ float sred[NWV];
  __shared__ float s_tau, s_scale, s_vav, s_ynext;
  int ep = 0;

  // ---- prologue: c = A[:,0], norm partials, alpha (all comms via gst) ----
  {
    const int q0p = (16 - g) >> 4;   // first q with 16q+g >= 1
    float np = 0.f;
    const int q = q0p + tid;
    if (q < QMAX) {
      const int j = 16*q + g;
      const float cv = A[(size_t)j*NBB];   // own row (prior kernel, dispatch-coherent)
      gst(&cbuf[j], cv);
      if (j >= 2) np = cv*cv;
      if (j == 1) gst(alphaS, cv);
    }
    const float s = wg_reduce16(np, sred);
    if (tid == 0) gst(&normp[g], s);
  }
  ++ep; gbar(cnt, ep*GW);

  for (int k0 = 0; k0 < NBB-2; k0 += PB) {
    const int ilim = (NBB-2-k0 < PB) ? (NBB-2-k0) : PB;
    for (int i = 0; i < ilim; ++i) {
      const int k = k0 + i;
      const int m = NBB-1-k;
      const int q0 = (k + 16 - g) >> 4;   // first q with 16q+g >= k+1

      // ================= Epoch X =================
      if (tid == 0) {
        float xn2 = 0.f;
        #pragma unroll
        for (int t = 0; t < GW; ++t) xn2 += gld(&normp[t]);
        const float alpha = gld(alphaS);
        float tau, scale, beta;
        if (xn2 < 1e-26f) {
          beta = alpha; tau = 0.f; scale = 0.f;
        } else {
          beta  = -copysignf(sqrtf(alpha*alpha + xn2), alpha);
          tau   = (beta - alpha) / beta;
          scale = 1.0f / (alpha - beta);
        }
        s_tau = tau; s_scale = scale;
        if (g == 0) { subA[n*NBB + k + 1] = beta; tauA[n*NBB + k] = tau; }
      }
      __syncthreads();
      const float tau = s_tau, scale = s_scale;
      // build full v in LDS (cbuf is cross-WG -> bypass loads)
      for (int idx = tid; idx < m; idx += TPW)
        vsh[idx] = (idx == 0) ? 1.0f : gld(&cbuf[k+1+idx])*scale;
      __syncthreads();
      // store v (own entries) into row k (transposed reflector, BYPASS) + Vloc
      {
        const int q = q0 + tid;
        if (q < QMAX) {
          const int j = 16*q + g;
          const float val = vsh[j-(k+1)];
          gst(&A[(size_t)k*NBB + j], val);
          Vloc[q*33 + i] = val;
        }
      }
      // d1/d2 partials over own rows (p < i)
      for (int p = wv; p < i; p += NWV) {
        float a1 = 0.f, a2 = 0.f;
        const int q = q0 + lane;
        if (q < QMAX) {
          const int j = 16*q + g;
          const float vj = vsh[j-(k+1)];
          a1 = Vloc[q*33 + p]*vj;
          a2 = Wloc[q*33 + p]*vj;
        }
        #pragma unroll
        for (int off = 32; off > 0; off >>= 1) { a1 += __shfl_down(a1, off); a2 += __shfl_down(a2, off); }
        if (lane == 0) { gst(&d1pA[g*PB + p], a1); gst(&d2pA[g*PB + p], a2); }
      }
      // matvec y = A0 v over own rows (plain cached, L2-resident)
      float vavl = 0.f;
      for (int q = q0 + wv; q < QMAX; q += NWV) {
        const int j = 16*q + g;
        const float* Ar = A + (size_t)j*NBB;
        float acc = 0.f;
        for (int c = k+1+lane; c < NBB; c += 64) acc += Ar[c]*vsh[c-(k+1)];
        #pragma unroll
        for (int off = 32; off > 0; off >>= 1) acc += __shfl_down(acc, off);
        if (lane == 0) {
          yloc[q] = acc;
          vavl += vsh[j-(k+1)]*acc;
          if (j == k+1) gst(ynextS, acc);
        }
      }
      const float vv = wg_reduce16(vavl, sred);
      if (tid == 0) gst(&vavp[g], vv);
      ++ep; rbar(cnt, ep*GW);

      // ================= Epoch Y =================
      if (tid < i) {
        float s1 = 0.f, s2 = 0.f;
        #pragma unroll
        for (int g2 = 0; g2 < GW; ++g2) { s1 += gld(&d1pA[g2*PB + tid]); s2 += gld(&d2pA[g2*PB + tid]); }
        d1s[tid] = s1; d2s[tid] = s2;
        Vk1s[tid] = gld(&A[(size_t)(k0+tid)*NBB + (k+1)]);
        Wk1s[tid] = gld(&Wbuf[(size_t)(k+1)*PB + tid]);
      }
      if (tid == TPW-1) {
        float sv = 0.f;
        #pragma unroll
        for (int t = 0; t < GW; ++t) sv += gld(&vavp[t]);
        s_vav = sv; s_ynext = gld(ynextS);
      }
      __syncthreads();
      // redundant scalars
      float s12 = 0.f, wk1acc = 0.f;
      for (int p = 0; p < i; ++p) { s12 += d1s[p]*d2s[p]; wk1acc += Vk1s[p]*d2s[p] + Wk1s[p]*d1s[p]; }
      const float corr = 0.5f*tau*tau*(s_vav - 2.f*s12);
      const float wk1 = tau*(s_ynext - wk1acc) - corr;
      // own-row w, then c' for column k+1
      {
        const int q = q0 + tid;
        float np = 0.f;
        if (q < QMAX) {
          const int j = 16*q + g;
          float wacc = 0.f;
          for (int p = 0; p < i; ++p) wacc += Vloc[q*33 + p]*d2s[p] + Wloc[q*33 + p]*d1s[p];
          const float vj = vsh[j-(k+1)];
          const float wj = tau*(yloc[q] - wacc) - corr*vj;
          Wloc[q*33 + i] = wj;
          gst(&Wbuf[(size_t)j*PB + i], wj);
          if (j >= k+2) {
            float cacc = 0.f;
            for (int p = 0; p < i; ++p) cacc += Vloc[q*33 + p]*Wk1s[p] + Wloc[q*33 + p]*Vk1s[p];
            cacc += vj*wk1 + wj;   // p = i term (V[k+1,i] = 1)
            const float cp = A[(size_t)j*NBB + (k+1)] - cacc;   // own row, clean cached
            gst(&cbuf[j], cp);
            if (j >= k+3) np = cp*cp;
            if (j == k+2) gst(alphaS, cp);
          }
        }
        const float ns = wg_reduce16(np, sred);
        if (tid == 0) gst(&normp[g], ns);
      }
      // diagonal extraction d[k] (own row plain; cross-WG data via bypass)
      if (g == (k & 15) && tid == 0) {
        float dk = A[(size_t)k*NBB + k];
        for (int p = 0; p < i; ++p)
          dk -= 2.f * gld(&A[(size_t)(k0+p)*NBB + k]) * gld(&Wbuf[(size_t)k*PB + p]);
        dA[n*NBB + k] = dk;
      }
      ++ep; rbar(cnt, ep*GW);
    }

    // ================= syr2k: A22 -= V W^T + W V^T =================
    if (k0 + PB < NBB-2) {
      const int kp = k0 + PB;
      const int q0s = (kp + 15 - g) >> 4;   // first q with 16q+g >= kp
      for (int c0 = kp+1; c0 < NBB; c0 += 64) {
        const int nc = (NBB - c0 < 64) ? (NBB - c0) : 64;
        for (int idx = tid; idx < 2048; idx += TPW) {
          const int p = idx >> 6, cc = idx & 63;
          Vt[cc*33 + p] = (cc < nc) ? gld(&A[(size_t)(k0+p)*NBB + c0 + cc]) : 0.f;
        }
        for (int idx = tid; idx < 2048; idx += TPW) {
          const int p = idx & 31, cc = idx >> 5;
          Wt[cc*33 + p] = (cc < nc) ? gld(&Wbuf[(size_t)(c0+cc)*PB + p]) : 0.f;
        }
        __syncthreads();
        for (int q = q0s + wv; q < QMAX; q += NWV) {
          const int j = 16*q + g;
          if (lane < nc) {
            const int c = c0 + lane;
            float acc = 0.f;
            #pragma unroll
            for (int p = 0; p < PB; ++p)
              acc += Vloc[q*33 + p]*Wt[lane*33 + p] + Wloc[q*33 + p]*Vt[lane*33 + p];
            A[(size_t)j*NBB + c] -= acc;   // own row, cached (cleaned below)
          }
        }
        __syncthreads();
      }
      // diagonal entry [kp][kp]
      if (g == (kp & 15) && tid == 0) {
        const int qd = kp >> 4;
        float acc = 0.f;
        #pragma unroll
        for (int p = 0; p < PB; ++p) acc += Vloc[qd*33 + p]*Wloc[qd*33 + p];
        A[(size_t)kp*NBB + kp] -= 2.f*acc;
      }
      ++ep; gbar(cnt, ep*GW);   // RELEASE: clean syr2k dirt before next panel's gst reflectors
    }
  }

  // ---- epilogue (cross-WG data via bypass loads) ----
  if (g == 0 && tid == 0) {
    const int k0l = ((NBB-3)/PB)*PB;       // 800
    const int np_ = NBB-2-k0l;             // 30
    float dm2 = gld(&A[(size_t)(NBB-2)*NBB + (NBB-2)]);
    float dm1 = gld(&A[(size_t)(NBB-1)*NBB + (NBB-1)]);
    for (int p = 0; p < np_; ++p) {
      dm2 -= 2.f * gld(&A[(size_t)(k0l+p)*NBB + (NBB-2)]) * gld(&Wbuf[(size_t)(NBB-2)*PB + p]);
      dm1 -= 2.f * gld(&A[(size_t)(k0l+p)*NBB + (NBB-1)]) * gld(&Wbuf[(size_t)(NBB-1)*PB + p]);
    }
    dA[n*NBB + NBB-2] = dm2;
    dA[n*NBB + NBB-1] = dm1;
    subA[n*NBB + NBB-1] = gld(alphaS);
    subA[n*NBB + 0] = 0.f;
    tauA[n*NBB + NBB-2] = 0.f;
    tauA[n*NBB + NBB-1] = 0.f;
  }
}

// ---------------- all eigenvalues via bisection (Sturm counts) ----------------
__global__ __launch_bounds__(256) void k_bisect(const float* __restrict__ dA, const float* __restrict__ subA,
                                                float* __restrict__ eig, float* __restrict__ e_out) {
  const int n = blockIdx.y;
  const int i = blockIdx.x*256 + threadIdx.x;
  __shared__ float ds[NBB], ss[NBB];
  const float* dg = dA + n*NBB;
  const float* sg = subA + n*NBB;
  for (int j = threadIdx.x; j < NBB; j += 256) { ds[j] = dg[j]; ss[j] = sg[j]; }
  __syncthreads();
  if (i >= NBB) return;
  float lo = 1e30f, hi = -1e30f;
  for (int j = 0; j < NBB; ++j) {
    const float r = fabsf(ss[j]) + ((j+1 < NBB) ? fabsf(ss[j+1]) : 0.f);
    lo = fminf(lo, ds[j]-r); hi = fmaxf(hi, ds[j]+r);
  }
  const float pad = 1e-3f*(hi-lo) + 1e-3f;
  lo -= pad; hi += pad;
  for (int it = 0; it < 38; ++it) {
    const float mid = 0.5f*(lo+hi);
    int cnt = 0;
    float qv = ds[0]-mid;
    if (qv < 0.f) cnt++;
    for (int j = 1; j < NBB; ++j) {
      const float e = ss[j];
      if (fabsf(qv) < 1e-20f) qv = -1e-20f;
      qv = ds[j]-mid - e*e/qv;
      if (qv < 0.f) cnt++;
    }
    if (cnt > i) hi = mid; else lo = mid;
  }
  const float lam = 0.5f*(lo+hi);
  eig[n*NBB + i] = lam;
  e_out[n*NBB + i] = lam;
}

// ---------------- inverse iteration on T for the 128 lowest ----------------
__global__ __launch_bounds__(64) void k_invit(const float* __restrict__ dA, const float* __restrict__ subA,
                                              const float* __restrict__ eig, float* __restrict__ Utri) {
  const int i = blockIdx.x, n = blockIdx.y;
  const int lane = threadIdx.x;
  __shared__ float ds[NBB], ss[NBB], ud[NBB], u1[NBB], u2[NBB], yv[NBB], xv[NBB];
  const float* dg = dA + n*NBB;
  const float* sg = subA + n*NBB;
  for (int j = lane; j < NBB; j += 64) { ds[j] = dg[j]; ss[j] = sg[j]; }
  const float lam = eig[n*NBB + i];
  for (int j = lane; j < NBB; j += 64) {
    uint32_t s = (uint32_t)(j*2654435761u) ^ (uint32_t)(i*40503u + 977u) ^ (uint32_t)(n*9973u);
    s ^= s >> 16; s *= 0x7feb352dU; s ^= s >> 15; s *= 0x846ca68bU; s ^= s >> 16;
    yv[j] = 0.5f + (float)(s & 0xFFFF) * (1.0f/65536.0f);
  }
  __syncthreads();
  const float PIV = 3e-6f;
  for (int pass = 0; pass < 2; ++pass) {
    if (lane == 0) {
      float cd = ds[0] - lam;
      float cu = ss[1];
      float cy = yv[0];
      for (int j = 0; j < NBB-1; ++j) {
        const float bl = ss[j+1];
        const float bd = ds[j+1] - lam;
        const float bu = (j+2 < NBB) ? ss[j+2] : 0.f;
        const float yb = yv[j+1];
        float tud, tu1, tu2, tm, ncd, ncu, ny;
        if (fabsf(bl) > fabsf(cd)) {
          tud = bl; tu1 = bd; tu2 = bu;
          if (fabsf(tud) < PIV) tud = (tud < 0.f) ? -PIV : PIV;
          tm  = cd / tud;
          ncd = cu - tm*bd;
          ncu = -tm*bu;
          ny  = cy - tm*yb;
          yv[j] = yb;
        } else {
          tud = cd; tu1 = cu; tu2 = 0.f;
          if (fabsf(tud) < PIV) tud = (tud < 0.f) ? -PIV : PIV;
          tm  = bl / tud;
          ncd = bd - tm*cu;
          ncu = bu;
          ny  = yb - tm*cy;
          yv[j] = cy;
        }
        ud[j] = tud; u1[j] = tu1; u2[j] = tu2;
        cd = ncd; cu = ncu; cy = ny;
      }
      if (fabsf(cd) < PIV) cd = (cd < 0.f) ? -PIV : PIV;
      ud[NBB-1] = cd; u1[NBB-1] = 0.f; u2[NBB-1] = 0.f; yv[NBB-1] = cy;
      float x2 = yv[NBB-1]/ud[NBB-1];
      xv[NBB-1] = x2;
      float x1 = (yv[NBB-2] - u1[NBB-2]*x2)/ud[NBB-2];
      xv[NBB-2] = x1;
      for (int j = NBB-3; j >= 0; --j) {
        const float xj = (yv[j] - u1[j]*x1 - u2[j]*x2)/ud[j];
        xv[j] = xj;
        x2 = x1; x1 = xj;
      }
    }
    __syncthreads();
    float p2 = 0.f;
    for (int j = lane; j < NBB; j += 64) { const float t = xv[j]; p2 += t*t; }
    #pragma unroll
    for (int off = 32; off > 0; off >>= 1) p2 += __shfl_xor(p2, off);
    const float rin = rsqrtf(p2);
    if (pass == 0) {
      for (int j = lane; j < NBB; j += 64) yv[j] = xv[j]*rin;
      __syncthreads();
    } else {
      float* Ub = Utri + ((size_t)n*NOCC2 + i)*NBB;
      for (int j = lane; j < NBB; j += 64) Ub[j] = xv[j]*rin;
    }
  }
}

// ---------------- back-transform: Uocc = H0...H829 * Utri ----------------
#define RPT 104
__global__ __launch_bounds__(512, 2) void k_backxform(const float* __restrict__ Acopy,
                                                      const float* __restrict__ tauA,
                                                      const float* __restrict__ Utri,
                                                      float* __restrict__ Uocc) {
  const int cg = blockIdx.x;         // column half (0/1)
  const int n = blockIdx.y;
  const int tid = threadIdx.x;
  const int jc = tid & 63, g = tid >> 6;   // 8 row-groups x 104 rows
  const int col = cg*64 + jc;
  __shared__ float vlds[NBB];
  __shared__ float sred[8*64];
  const float* A = Acopy + (size_t)n*NBB*NBB;
  float U[RPT];
  const float* Ut = Utri + ((size_t)n*NOCC2 + col)*NBB + g*RPT;
  #pragma unroll
  for (int rr = 0; rr < RPT; ++rr) U[rr] = Ut[rr];
  const int rbase = g*RPT;
  for (int k = NBB-3; k >= 0; --k) {
    const float tau = tauA[n*NBB + k];
    if (tau == 0.f) continue;
    const int m = NBB-1-k;
    // transposed reflector storage: v lives in row k, cols k+1..
    for (int idx = tid; idx < m; idx += 512) vlds[idx] = A[(size_t)k*NBB + (k+1+idx)];
    __syncthreads();
    float part = 0.f;
    #pragma unroll
    for (int rr = 0; rr < RPT; ++rr) {
      const int r = rbase + rr;
      if (r > k) part += U[rr]*vlds[r-k-1];
    }
    sred[g*64 + jc] = part;
    __syncthreads();
    float ssum = 0.f;
    #pragma unroll
    for (int t = 0; t < 8; ++t) ssum += sred[t*64 + jc];
    const float s = tau*ssum;
    #pragma unroll
    for (int rr = 0; rr < RPT; ++rr) {
      const int r = rbase + rr;
      if (r > k) U[rr] -= s*vlds[r-k-1];
    }
    __syncthreads();
  }
  float* Ub = Uocc + (size_t)n*NBB*NOCC2;
  #pragma unroll
  for (int rr = 0; rr < RPT; ++rr) Ub[(size_t)(rbase+rr)*NOCC2 + col] = U[rr];
}

// ---------------- C = h_new * Uocc  (832x832 @ 832x128 per batch) ----------------
__global__ __launch_bounds__(256) void k_gemmC(const float* __restrict__ h,
                                               const float* __restrict__ Uocc,
                                               float* __restrict__ C) {
  const int rt = blockIdx.x, n = blockIdx.y;
  const int tid = threadIdx.x;
  __shared__ __align__(16) float hT[64*33];
  __shared__ __align__(16) float Ut[32*128];
  const int ty = tid >> 5, tx = tid & 31;
  float acc[8][4] = {};
  const float* hb = h + (size_t)n*NBB*NBB + (size_t)rt*64*NBB;
  const float* Ub = Uocc + (size_t)n*NBB*NOCC2;
  for (int k0 = 0; k0 < NBB; k0 += 32) {
    for (int idx = tid; idx < 64*32; idx += 256) {
      const int r = idx >> 5, c = idx & 31;
      hT[r*33 + c] = hb[(size_t)r*NBB + k0 + c];
    }
    for (int idx = tid; idx < 32*128; idx += 256) {
      const int r = idx >> 7, c = idx & 127;
      Ut[idx] = Ub[(size_t)(k0 + r)*NOCC2 + c];
    }
    __syncthreads();
    for (int kk = 0; kk < 32; ++kk) {
      const float4 b4 = *(const float4*)&Ut[kk*128 + tx*4];
      #pragma unroll
      for (int q = 0; q < 8; ++q) {
        const float a = hT[(ty*8 + q)*33 + kk];
        acc[q][0] += a*b4.x; acc[q][1] += a*b4.y; acc[q][2] += a*b4.z; acc[q][3] += a*b4.w;
      }
    }
    __syncthreads();
  }
  float* Cb = C + (size_t)n*NBB*NOCC2;
  #pragma unroll
  for (int q = 0; q < 8; ++q)
    #pragma unroll
    for (int p = 0; p < 4; ++p)
      Cb[(size_t)(rt*64 + ty*8 + q)*NOCC2 + tx*4 + p] = acc[q][p];
}

// ---------------- E = sum(e_occ) + Tr(Uocc^T h Uocc) + nuc ----------------
__global__ __launch_bounds__(256) void k_final(const float* __restrict__ eig,
                                               const float* __restrict__ Uocc, const float* __restrict__ C,
                                               const float* __restrict__ pos, const int* __restrict__ numbers,
                                               float* __restrict__ E_out) {
  const int n = blockIdx.x, tid = threadIdx.x;
  __shared__ float rb[256];
  float local = 0.f;
  for (int i = tid; i < NOCC2; i += 256) local += eig[n*NBB + i];
  const float* Ub = Uocc + (size_t)n*NBB*NOCC2;
  const float* Cb = C + (size_t)n*NBB*NOCC2;
  for (int idx = tid; idx < NBB*NOCC2; idx += 256) local += Ub[idx]*Cb[idx];
  float ln = 0.f;
  for (int t = tid; t < NPAIR; t += 256) {
    int kk, ll;
    pair_decode(t, kk, ll);
    const float dx = pos[(n*NK + kk)*3 + 0] - pos[(n*NK + ll)*3 + 0];
    const float dy = pos[(n*NK + kk)*3 + 1] - pos[(n*NK + ll)*3 + 1];
    const float dz = pos[(n*NK + kk)*3 + 2] - pos[(n*NK + ll)*3 + 2];
    const float d2 = dx*dx + dy*dy + dz*dz;
    const float Z = (float)(numbers[kk]*numbers[ll]);
    ln += Z / sqrtf(d2);
  }
  local += ln * A0C;
  rb[tid] = local;
  __syncthreads();
  for (int s = 128; s > 0; s >>= 1) {
    if (tid < s) rb[tid] += rb[tid + s];
    __syncthreads();
  }
  if (tid == 0) E_out[n] = rb[0];
}

extern "C" void kernel_launch(void* const* d_in, const int* in_sizes, int n_in,
                              void* d_out, int out_size, void* d_ws, size_t ws_size,
                              hipStream_t stream) {
  (void)in_sizes; (void)n_in; (void)out_size; (void)ws_size;
  const float* mu      = (const float*)d_in[0];
  const float* hnew    = (const float*)d_in[1];
  const float* pos     = (const float*)d_in[2];
  const float* Foff    = (const float*)d_in[3];
  const float* tW      = (const float*)d_in[4];
  const float* tb      = (const float*)d_in[5];
  const float* Won     = (const float*)d_in[6];
  const float* bon     = (const float*)d_in[7];
  const float* Woff    = (const float*)d_in[8];
  const float* boff    = (const float*)d_in[9];
  const int*   numbers = (const int*)d_in[10];

  float* out   = (float*)d_out;
  float* Fout  = out;                               // [16][832][832]
  float* e_out = out + (size_t)NBATCH*NBB*NBB;      // [16][832]
  float* E_out = e_out + (size_t)NBATCH*NBB;        // [16]

  float* ws    = (float*)d_ws;
  float* Acopy = ws + OFF_ACOPY;
  float* xbuf  = ws + OFF_X;
  float* Sbuf  = ws + OFF_S;
  float* dA    = ws + OFF_D;
  float* subA  = ws + OFF_SUB;
  float* tauA  = ws + OFF_TAU;
  float* eig   = ws + OFF_EIG;
  float* Utri  = ws + OFF_UTRI;
  float* Uocc  = ws + OFF_UOCC;
  float* Cbuf  = ws + OFF_C;     // overlays Utri
  float* Wpan  = ws + OFF_WPAN;  // overlays Utri (dead until k_invit)
  float* cbufA = ws + OFF_CBUF;
  float* slotA = ws + OFF_SLOT;
  int*   barA  = (int*)(ws + OFF_BARC);

  // zero the per-matrix barrier counters (graph-captured; runs every replay)
  hipMemsetAsync((void*)barA, 0, NBATCH*sizeof(int), stream);

  k_x<<<dim3(NK, NBATCH), dim3(256), 0, stream>>>(mu, tW, tb, xbuf);
  k_S<<<dim3(NBATCH), dim3(256), 0, stream>>>(xbuf, Sbuf);
  k_diag<<<dim3(NK, NBATCH), dim3(256), 0, stream>>>(xbuf, Sbuf, Won, bon, hnew, Foff, Fout, Acopy);
  k_off<<<dim3(6, 16, NBATCH), dim3(256), 0, stream>>>(xbuf, Woff, boff, hnew, Foff, Fout, Acopy);
  k_tridiag_panel<<<dim3(GW, NBATCH), dim3(TPW), 0, stream>>>(Acopy, dA, subA, tauA, Wpan, cbufA, slotA, barA);
  k_bisect<<<dim3(4, NBATCH), dim3(256), 0, stream>>>(dA, subA, eig, e_out);
  k_invit<<<dim3(NOCC2, NBATCH), dim3(64), 0, stream>>>(dA, subA, eig, Utri);
  k_backxform<<<dim3(2, NBATCH), dim3(512), 0, stream>>>(Acopy, tauA, Utri, Uocc);
  k_gemmC<<<dim3(13, NBATCH), dim3(256), 0, stream>>>(hnew, Uocc, Cbuf);
  k_final<<<dim3(NBATCH), dim3(256), 0, stream>>>(eig, Uocc, Cbuf, pos, numbers, E_out);
}

// Round 11
// 36051.230 us; speedup vs baseline: 2.1684x; 1.1356x over previous
//
#include <hip/hip_runtime.h>
#include <math.h>
#include <stdint.h>

// Problem constants
#define NBATCH 16
#define NK     32
#define NTDS   768      // 3*DS
#define NMM    676      // BM*BM
#define NBM    26
#define NBB    832      // B = K*BM
#define NOCC2  128
#define NPAIR  496      // K*(K-1)/2
#define FSCALE 1.0e-4f
#define A0C    0.5291772f

// ---------------- workspace layout (in floats) ----------------
#define OFF_ACOPY 0ull
#define SZ_ACOPY  (16ull*832*832)
#define OFF_X     (OFF_ACOPY + SZ_ACOPY)
#define SZ_X      (16ull*32*768)
#define OFF_S     (OFF_X + SZ_X)
#define SZ_S      (16ull*768)
#define OFF_D     (OFF_S + SZ_S)
#define OFF_SUB   (OFF_D   + 16ull*832)
#define OFF_TAU   (OFF_SUB + 16ull*832)
#define OFF_EIG   (OFF_TAU + 16ull*832)
#define OFF_UTRI  (OFF_EIG + 16ull*832)
#define SZ_UTRI   (16ull*128*832)
#define OFF_UOCC  (OFF_UTRI + SZ_UTRI)
#define OFF_C     OFF_UTRI   /* C overlays Utri (dead after backxform) */
// tridiag scratch overlays the Utri region (Utri written only later by k_invit)
#define PB   32   // panel width
#define GW   16   // workgroups per matrix (R7-proven config)
#define TPW  1024 // threads per workgroup
#define NWV  16   // waves per WG
#define QMAX 52   // max own rows per WG (832/16)
#define SLOTSTR 1088
#define OFF_WPAN  OFF_UTRI                        /* 16*832*32 = 425,984 */
#define OFF_CBUF  (OFF_WPAN + 16ull*832*32)       /* 16*832 */
#define OFF_SLOT  (OFF_CBUF + 16ull*832)          /* 16*1088 */
#define OFF_BARC  (OFF_SLOT + 16ull*SLOTSTR)      /* 16 ints */

__device__ __forceinline__ void pair_decode(int t, int& k, int& l) {
  int kk = (int)((1.0f + sqrtf(1.0f + 8.0f*(float)t)) * 0.5f);
  while (kk*(kk-1)/2 > t) --kk;
  while ((kk+1)*kk/2 <= t) ++kk;
  k = kk; l = t - kk*(kk-1)/2;
}

// Cross-WG READ: agent-scope bypass load (sc0 sc1) — reads through to the MALL
// (memory-side, unbypassable), so it observes completed bypass stores and
// wbl2-released cached stores with no acquire-invalidate.
__device__ __forceinline__ float gld(const float* p) {
  unsigned int u = __hip_atomic_load((const unsigned int*)p, __ATOMIC_RELAXED, __HIP_MEMORY_SCOPE_AGENT);
  return __uint_as_float(u);
}
// Cross-WG WRITE: agent-scope bypass store (sc0 sc1) — write-through to MALL.
// vmcnt retirement (drained by __syncthreads before the barrier flag bump)
// means the value is at the MALL before any other WG can observe the flag.
__device__ __forceinline__ void gst(float* p, float v) {
  __hip_atomic_store((unsigned int*)p, __float_as_uint(v), __ATOMIC_RELAXED, __HIP_MEMORY_SCOPE_AGENT);
}

// ---------------- x = mu @ transfer_W + b ----------------
__global__ __launch_bounds__(256) void k_x(const float* __restrict__ mu,
                                           const float* __restrict__ tW,
                                           const float* __restrict__ tb,
                                           float* __restrict__ x) {
  const int k = blockIdx.x, n = blockIdx.y, tid = threadIdx.x;
  __shared__ float mus[384];
  const float* mub = mu + (size_t)(n*NK + k)*384;
  for (int i = tid; i < 384; i += 256) mus[i] = mub[i];
  __syncthreads();
  float* xb = x + (size_t)(n*NK + k)*NTDS;
  for (int oo = tid; oo < NTDS; oo += 256) {
    const int d = oo >> 8, i = oo & 255;
    float acc = tb[i];
    const float* mrow = &mus[d*128];
    for (int a = 0; a < 128; ++a) acc += mrow[a]*tW[a*256 + i];
    xb[oo] = acc;
  }
}

// ---------------- S[n][dd] = sum_k x[n][k][dd] ----------------
__global__ __launch_bounds__(256) void k_S(const float* __restrict__ x, float* __restrict__ S) {
  const int n = blockIdx.x, tid = threadIdx.x;
  for (int dd = tid; dd < NTDS; dd += 256) {
    float s = 0.f;
    for (int k = 0; k < NK; ++k) s += x[(size_t)(n*NK + k)*NTDS + dd];
    S[n*NTDS + dd] = s;
  }
}

// ---------------- diagonal blocks ----------------
__global__ __launch_bounds__(256) void k_diag(const float* __restrict__ x, const float* __restrict__ S,
                                              const float* __restrict__ Won, const float* __restrict__ bon,
                                              const float* __restrict__ hnew, const float* __restrict__ Foff,
                                              float* __restrict__ Fout, float* __restrict__ Acopy) {
  const int k = blockIdx.x, n = blockIdx.y, tid = threadIdx.x;
  __shared__ float q[NTDS];
  __shared__ float M[NMM];
  const float* xb = x + (size_t)(n*NK + k)*NTDS;
  const float* Sb = S + n*NTDS;
  for (int i = tid; i < NTDS; i += 256) q[i] = xb[i]*Sb[i];
  __syncthreads();
  for (int m = tid; m < NMM; m += 256) {
    float acc = 32.0f * bon[m];
    for (int dd = 0; dd < NTDS; ++dd) acc += q[dd]*Won[(size_t)dd*NMM + m];
    M[m] = acc;
  }
  __syncthreads();
  const float* hb = hnew + (size_t)n*NBB*NBB;
  float* Fb = Fout + (size_t)n*NBB*NBB;
  float* Ab = Acopy + (size_t)n*NBB*NBB;
  for (int m = tid; m < NMM; m += 256) {
    const int a = m/26, b = m - a*26;
    const float val = 0.5f*(M[m] + M[b*26 + a]);
    const int P = k*26 + a, Q = k*26 + b;
    const size_t idx = (size_t)P*NBB + Q;
    const float fo = Foff[idx];
    const float hv = hb[idx];
    const float Fv = (fabsf(hv) > 1e-7f) ? (val*FSCALE + fo) : fo;
    Fb[idx] = Fv; Ab[idx] = Fv;
  }
}

// ---------------- off-diagonal blocks: GEMM over pairs ----------------
__global__ __launch_bounds__(256) void k_off(const float* __restrict__ x,
                                             const float* __restrict__ Woff, const float* __restrict__ boff,
                                             const float* __restrict__ hnew, const float* __restrict__ Foff,
                                             float* __restrict__ Fout, float* __restrict__ Acopy) {
  const int ct = blockIdx.x, pt = blockIdx.y, n = blockIdx.z;
  const int tid = threadIdx.x;
  __shared__ __align__(16) float At[32*65];
  __shared__ __align__(16) float Bt[64*128];
  __shared__ int klk[32], kll[32];
  if (tid < 32) {
    int pr = pt*32 + tid, kk = 1, ll = 0;
    if (pr < NPAIR) pair_decode(pr, kk, ll);
    klk[tid] = kk; kll[tid] = ll;
  }
  __syncthreads();
  const int ty = tid >> 5, tx = tid & 31;
  const int r0 = ty*4, c0 = tx*4;
  float acc[4][4] = {};
  for (int dd0 = 0; dd0 < NTDS; dd0 += 64) {
    for (int idx = tid; idx < 2048; idx += 256) {
      const int r = idx >> 6, c = idx & 63;
      const int pr = pt*32 + r;
      float v = 0.f;
      if (pr < NPAIR) {
        const int kk = klk[r], ll = kll[r];
        v = x[(size_t)(n*NK + kk)*NTDS + dd0 + c] * x[(size_t)(n*NK + ll)*NTDS + dd0 + c];
      }
      At[r*65 + c] = v;
    }
    for (int idx = tid; idx < 8192; idx += 256) {
      const int r = idx >> 7, c = idx & 127;
      const int col = ct*128 + c;
      Bt[idx] = (col < NMM) ? Woff[(size_t)(dd0 + r)*NMM + col] : 0.f;
    }
    __syncthreads();
    for (int kk = 0; kk < 64; ++kk) {
      float av[4];
      av[0] = At[(r0+0)*65 + kk];
      av[1] = At[(r0+1)*65 + kk];
      av[2] = At[(r0+2)*65 + kk];
      av[3] = At[(r0+3)*65 + kk];
      const float4 b4 = *(const float4*)&Bt[kk*128 + c0];
      const float bb[4] = {b4.x, b4.y, b4.z, b4.w};
      #pragma unroll
      for (int qq = 0; qq < 4; ++qq)
        #pragma unroll
        for (int pp = 0; pp < 4; ++pp)
          acc[qq][pp] += av[qq]*bb[pp];
    }
    __syncthreads();
  }
  const float* hb = hnew + (size_t)n*NBB*NBB;
  float* Fb = Fout + (size_t)n*NBB*NBB;
  float* Ab = Acopy + (size_t)n*NBB*NBB;
  for (int qq = 0; qq < 4; ++qq) {
    const int pr = pt*32 + r0 + qq;
    if (pr >= NPAIR) continue;
    const int kk = klk[r0+qq], ll = kll[r0+qq];
    for (int pp = 0; pp < 4; ++pp) {
      const int m = ct*128 + c0 + pp;
      if (m >= NMM) continue;
      const float val = acc[qq][pp] + boff[m];
      const int a = m/26, b = m - a*26;
      const int P = kk*26 + a, Q = ll*26 + b;
      const size_t i1 = (size_t)P*NBB + Q;
      const float fo1 = Foff[i1], hv1 = hb[i1];
      const float Fv1 = (fabsf(hv1) > 1e-7f) ? (val*FSCALE + fo1) : fo1;
      Fb[i1] = Fv1; Ab[i1] = Fv1;
      const size_t i2 = (size_t)Q*NBB + P;
      const float fo2 = Foff[i2], hv2 = hb[i2];
      const float Fv2 = (fabsf(hv2) > 1e-7f) ? (val*FSCALE + fo2) : fo2;
      Fb[i2] = Fv2; Ab[i2] = Fv2;
    }
  }
}

// ================= blocked (latrd) multi-WG tridiagonalization =================
// R11: R10 structure with float4 matvec (4x fewer load issues, 4x MLP per
// issue on the hot path). Epoch model from R7-R10: ~17.6us/epoch invariant to
// work-halving/footprint/wave-count -> attack instruction/latency depth.
// Coherence protocol unchanged (proven R7): gst/gld bypass for ALL cross-WG
// data; relaxed rbar per column; release gbar per panel boundary.
__device__ __forceinline__ void rbar(int* cnt, int target) {
  __syncthreads();   // emits s_waitcnt vmcnt(0) before s_barrier: bypass stores MALL-complete
  if (threadIdx.x == 0) {
    asm volatile("" ::: "memory");
    __hip_atomic_fetch_add(cnt, 1, __ATOMIC_RELAXED, __HIP_MEMORY_SCOPE_AGENT);
    while (__hip_atomic_load(cnt, __ATOMIC_RELAXED, __HIP_MEMORY_SCOPE_AGENT) < target)
      __builtin_amdgcn_s_sleep(1);
    asm volatile("" ::: "memory");
  }
  __syncthreads();
}
__device__ __forceinline__ void gbar(int* cnt, int target) {
  __syncthreads();
  if (threadIdx.x == 0) {
    __hip_atomic_fetch_add(cnt, 1, __ATOMIC_RELEASE, __HIP_MEMORY_SCOPE_AGENT);  // wbl2
    while (__hip_atomic_load(cnt, __ATOMIC_RELAXED, __HIP_MEMORY_SCOPE_AGENT) < target)
      __builtin_amdgcn_s_sleep(1);
  }
  __syncthreads();
}

__device__ __forceinline__ float wg_reduce16(float v, volatile float* sred) {
  #pragma unroll
  for (int off = 32; off > 0; off >>= 1) v += __shfl_down(v, off);
  const int tid = threadIdx.x;
  if ((tid & 63) == 0) sred[tid >> 6] = v;
  __syncthreads();
  float r = 0.f;
  #pragma unroll
  for (int t = 0; t < NWV; ++t) r += sred[t];
  __syncthreads();
  return r;
}

__global__ __launch_bounds__(TPW) void k_tridiag_panel(float* __restrict__ Acopy,
                                                       float* __restrict__ dA,
                                                       float* __restrict__ subA,
                                                       float* __restrict__ tauA,
                                                       float* __restrict__ Wpan,
                                                       float* __restrict__ cbufA,
                                                       float* __restrict__ slotA,
                                                       int* __restrict__ barA) {
  const int g = blockIdx.x;          // WG within matrix
  const int n = blockIdx.y;          // matrix
  const int tid = threadIdx.x;
  const int lane = tid & 63, wv = tid >> 6;
  float* A    = Acopy + (size_t)n*NBB*NBB;
  float* Wbuf = Wpan  + (size_t)n*NBB*PB;
  float* cbuf = cbufA + (size_t)n*NBB;
  float* slot = slotA + (size_t)n*SLOTSTR;
  float* normp = slot;          // [16]
  float* vavp  = slot + 16;     // [16]
  float* alphaS= slot + 32;     // [1]
  float* ynextS= slot + 33;     // [1]
  float* d1pA  = slot + 64;     // [16][32]
  float* d2pA  = slot + 576;    // [16][32]
  int*   cnt   = barA + n;

  __shared__ float vsh[NBB];
  __shared__ float yloc[QMAX];
  __shared__ float Vloc[QMAX*33];
  __shared__ float Wloc[QMAX*33];
  __shared__ float Vt[64*33];
  __shared__ float Wt[64*33];
  __shared__ float d1s[PB], d2s[PB], Vk1s[PB], Wk1s[PB];
  __shared__ float sred[NWV];
  __shared__ float s_tau, s_scale, s_vav, s_ynext;
  int ep = 0;

  // ---- prologue: c = A[:,0], norm partials, alpha (all comms via gst) ----
  {
    const int q0p = (16 - g) >> 4;   // first q with 16q+g >= 1
    float np = 0.f;
    const int q = q0p + tid;
    if (q < QMAX) {
      const int j = 16*q + g;
      const float cv = A[(size_t)j*NBB];   // own row (prior kernel, dispatch-coherent)
      gst(&cbuf[j], cv);
      if (j >= 2) np = cv*cv;
      if (j == 1) gst(alphaS, cv);
    }
    const float s = wg_reduce16(np, sred);
    if (tid == 0) gst(&normp[g], s);
  }
  ++ep; gbar(cnt, ep*GW);

  for (int k0 = 0; k0 < NBB-2; k0 += PB) {
    const int ilim = (NBB-2-k0 < PB) ? (NBB-2-k0) : PB;
    for (int i = 0; i < ilim; ++i) {
      const int k = k0 + i;
      const int m = NBB-1-k;
      const int q0 = (k + 16 - g) >> 4;   // first q with 16q+g >= k+1

      // ================= Epoch X =================
      if (tid == 0) {
        float xn2 = 0.f;
        #pragma unroll
        for (int t = 0; t < GW; ++t) xn2 += gld(&normp[t]);
        const float alpha = gld(alphaS);
        float tau, scale, beta;
        if (xn2 < 1e-26f) {
          beta = alpha; tau = 0.f; scale = 0.f;
        } else {
          beta  = -copysignf(sqrtf(alpha*alpha + xn2), alpha);
          tau   = (beta - alpha) / beta;
          scale = 1.0f / (alpha - beta);
        }
        s_tau = tau; s_scale = scale;
        if (g == 0) { subA[n*NBB + k + 1] = beta; tauA[n*NBB + k] = tau; }
      }
      __syncthreads();
      const float tau = s_tau, scale = s_scale;
      // build full v in LDS (cbuf is cross-WG -> bypass loads)
      for (int idx = tid; idx < m; idx += TPW)
        vsh[idx] = (idx == 0) ? 1.0f : gld(&cbuf[k+1+idx])*scale;
      __syncthreads();
      // store v (own entries) into row k (transposed reflector, BYPASS) + Vloc
      {
        const int q = q0 + tid;
        if (q < QMAX) {
          const int j = 16*q + g;
          const float val = vsh[j-(k+1)];
          gst(&A[(size_t)k*NBB + j], val);
          Vloc[q*33 + i] = val;
        }
      }
      // d1/d2 partials over own rows (p < i)
      for (int p = wv; p < i; p += NWV) {
        float a1 = 0.f, a2 = 0.f;
        const int q = q0 + lane;
        if (q < QMAX) {
          const int j = 16*q + g;
          const float vj = vsh[j-(k+1)];
          a1 = Vloc[q*33 + p]*vj;
          a2 = Wloc[q*33 + p]*vj;
        }
        #pragma unroll
        for (int off = 32; off > 0; off >>= 1) { a1 += __shfl_down(a1, off); a2 += __shfl_down(a2, off); }
        if (lane == 0) { gst(&d1pA[g*PB + p], a1); gst(&d2pA[g*PB + p], a2); }
      }
      // matvec y = A0 v over own rows (plain cached; float4 body for 4x MLP)
      {
        const int cs = k+1;
        const int ca = (cs + 3) & ~3;          // 16B-aligned start (NBB%4==0 -> no tail)
        const int nh = ca - cs;                 // 0..3 head elems
        float vavl = 0.f;
        for (int q = q0 + wv; q < QMAX; q += NWV) {
          const int j = 16*q + g;
          const float* Ar = A + (size_t)j*NBB;
          float acc = 0.f;
          if (lane < nh) acc += Ar[cs+lane]*vsh[lane];
          for (int c = ca + 4*lane; c < NBB; c += 256) {
            const float4 a4 = *(const float4*)&Ar[c];
            const int vi = c - cs;
            acc += a4.x*vsh[vi] + a4.y*vsh[vi+1] + a4.z*vsh[vi+2] + a4.w*vsh[vi+3];
          }
          #pragma unroll
          for (int off = 32; off > 0; off >>= 1) acc += __shfl_down(acc, off);
          if (lane == 0) {
            yloc[q] = acc;
            vavl += vsh[j-(k+1)]*acc;
            if (j == k+1) gst(ynextS, acc);
          }
        }
        const float vv = wg_reduce16(vavl, sred);
        if (tid == 0) gst(&vavp[g], vv);
      }
      ++ep; rbar(cnt, ep*GW);

      // ================= Epoch Y =================
      if (tid < i) {
        float s1 = 0.f, s2 = 0.f;
        #pragma unroll
        for (int g2 = 0; g2 < GW; ++g2) { s1 += gld(&d1pA[g2*PB + tid]); s2 += gld(&d2pA[g2*PB + tid]); }
        d1s[tid] = s1; d2s[tid] = s2;
        Vk1s[tid] = gld(&A[(size_t)(k0+tid)*NBB + (k+1)]);
        Wk1s[tid] = gld(&Wbuf[(size_t)(k+1)*PB + tid]);
      }
      if (tid == TPW-1) {
        float sv = 0.f;
        #pragma unroll
        for (int t = 0; t < GW; ++t) sv += gld(&vavp[t]);
        s_vav = sv; s_ynext = gld(ynextS);
      }
      __syncthreads();
      // redundant scalars
      float s12 = 0.f, wk1acc = 0.f;
      for (int p = 0; p < i; ++p) { s12 += d1s[p]*d2s[p]; wk1acc += Vk1s[p]*d2s[p] + Wk1s[p]*d1s[p]; }
      const float corr = 0.5f*tau*tau*(s_vav - 2.f*s12);
      const float wk1 = tau*(s_ynext - wk1acc) - corr;
      // own-row w, then c' for column k+1
      {
        const int q = q0 + tid;
        float np = 0.f;
        if (q < QMAX) {
          const int j = 16*q + g;
          float wacc = 0.f;
          for (int p = 0; p < i; ++p) wacc += Vloc[q*33 + p]*d2s[p] + Wloc[q*33 + p]*d1s[p];
          const float vj = vsh[j-(k+1)];
          const float wj = tau*(yloc[q] - wacc) - corr*vj;
          Wloc[q*33 + i] = wj;
          gst(&Wbuf[(size_t)j*PB + i], wj);
          if (j >= k+2) {
            float cacc = 0.f;
            for (int p = 0; p < i; ++p) cacc += Vloc[q*33 + p]*Wk1s[p] + Wloc[q*33 + p]*Vk1s[p];
            cacc += vj*wk1 + wj;   // p = i term (V[k+1,i] = 1)
            const float cp = A[(size_t)j*NBB + (k+1)] - cacc;   // own row, clean cached
            gst(&cbuf[j], cp);
            if (j >= k+3) np = cp*cp;
            if (j == k+2) gst(alphaS, cp);
          }
        }
        const float ns = wg_reduce16(np, sred);
        if (tid == 0) gst(&normp[g], ns);
      }
      // diagonal extraction d[k] (own row plain; cross-WG data via bypass)
      if (g == (k & 15) && tid == 0) {
        float dk = A[(size_t)k*NBB + k];
        for (int p = 0; p < i; ++p)
          dk -= 2.f * gld(&A[(size_t)(k0+p)*NBB + k]) * gld(&Wbuf[(size_t)k*PB + p]);
        dA[n*NBB + k] = dk;
      }
      ++ep; rbar(cnt, ep*GW);
    }

    // ================= syr2k: A22 -= V W^T + W V^T =================
    if (k0 + PB < NBB-2) {
      const int kp = k0 + PB;
      const int q0s = (kp + 15 - g) >> 4;   // first q with 16q+g >= kp
      for (int c0 = kp+1; c0 < NBB; c0 += 64) {
        const int nc = (NBB - c0 < 64) ? (NBB - c0) : 64;
        for (int idx = tid; idx < 2048; idx += TPW) {
          const int p = idx >> 6, cc = idx & 63;
          Vt[cc*33 + p] = (cc < nc) ? gld(&A[(size_t)(k0+p)*NBB + c0 + cc]) : 0.f;
        }
        for (int idx = tid; idx < 2048; idx += TPW) {
          const int p = idx & 31, cc = idx >> 5;
          Wt[cc*33 + p] = (cc < nc) ? gld(&Wbuf[(size_t)(c0+cc)*PB + p]) : 0.f;
        }
        __syncthreads();
        for (int q = q0s + wv; q < QMAX; q += NWV) {
          const int j = 16*q + g;
          if (lane < nc) {
            const int c = c0 + lane;
            float acc = 0.f;
            #pragma unroll
            for (int p = 0; p < PB; ++p)
              acc += Vloc[q*33 + p]*Wt[lane*33 + p] + Wloc[q*33 + p]*Vt[lane*33 + p];
            A[(size_t)j*NBB + c] -= acc;   // own row, cached (cleaned below)
          }
        }
        __syncthreads();
      }
      // diagonal entry [kp][kp]
      if (g == (kp & 15) && tid == 0) {
        const int qd = kp >> 4;
        float acc = 0.f;
        #pragma unroll
        for (int p = 0; p < PB; ++p) acc += Vloc[qd*33 + p]*Wloc[qd*33 + p];
        A[(size_t)kp*NBB + kp] -= 2.f*acc;
      }
      ++ep; gbar(cnt, ep*GW);   // RELEASE: clean syr2k dirt before next panel's gst reflectors
    }
  }

  // ---- epilogue (cross-WG data via bypass loads) ----
  if (g == 0 && tid == 0) {
    const int k0l = ((NBB-3)/PB)*PB;       // 800
    const int np_ = NBB-2-k0l;             // 30
    float dm2 = gld(&A[(size_t)(NBB-2)*NBB + (NBB-2)]);
    float dm1 = gld(&A[(size_t)(NBB-1)*NBB + (NBB-1)]);
    for (int p = 0; p < np_; ++p) {
      dm2 -= 2.f * gld(&A[(size_t)(k0l+p)*NBB + (NBB-2)]) * gld(&Wbuf[(size_t)(NBB-2)*PB + p]);
      dm1 -= 2.f * gld(&A[(size_t)(k0l+p)*NBB + (NBB-1)]) * gld(&Wbuf[(size_t)(NBB-1)*PB + p]);
    }
    dA[n*NBB + NBB-2] = dm2;
    dA[n*NBB + NBB-1] = dm1;
    subA[n*NBB + NBB-1] = gld(alphaS);
    subA[n*NBB + 0] = 0.f;
    tauA[n*NBB + NBB-2] = 0.f;
    tauA[n*NBB + NBB-1] = 0.f;
  }
}

// ---------------- all eigenvalues via bisection (Sturm counts) ----------------
__global__ __launch_bounds__(256) void k_bisect(const float* __restrict__ dA, const float* __restrict__ subA,
                                                float* __restrict__ eig, float* __restrict__ e_out) {
  const int n = blockIdx.y;
  const int i = blockIdx.x*256 + threadIdx.x;
  __shared__ float ds[NBB], ss[NBB];
  const float* dg = dA + n*NBB;
  const float* sg = subA + n*NBB;
  for (int j = threadIdx.x; j < NBB; j += 256) { ds[j] = dg[j]; ss[j] = sg[j]; }
  __syncthreads();
  if (i >= NBB) return;
  float lo = 1e30f, hi = -1e30f;
  for (int j = 0; j < NBB; ++j) {
    const float r = fabsf(ss[j]) + ((j+1 < NBB) ? fabsf(ss[j+1]) : 0.f);
    lo = fminf(lo, ds[j]-r); hi = fmaxf(hi, ds[j]+r);
  }
  const float pad = 1e-3f*(hi-lo) + 1e-3f;
  lo -= pad; hi += pad;
  for (int it = 0; it < 38; ++it) {
    const float mid = 0.5f*(lo+hi);
    int cnt = 0;
    float qv = ds[0]-mid;
    if (qv < 0.f) cnt++;
    for (int j = 1; j < NBB; ++j) {
      const float e = ss[j];
      if (fabsf(qv) < 1e-20f) qv = -1e-20f;
      qv = ds[j]-mid - e*e/qv;
      if (qv < 0.f) cnt++;
    }
    if (cnt > i) hi = mid; else lo = mid;
  }
  const float lam = 0.5f*(lo+hi);
  eig[n*NBB + i] = lam;
  e_out[n*NBB + i] = lam;
}

// ---------------- inverse iteration on T for the 128 lowest ----------------
__global__ __launch_bounds__(64) void k_invit(const float* __restrict__ dA, const float* __restrict__ subA,
                                              const float* __restrict__ eig, float* __restrict__ Utri) {
  const int i = blockIdx.x, n = blockIdx.y;
  const int lane = threadIdx.x;
  __shared__ float ds[NBB], ss[NBB], ud[NBB], u1[NBB], u2[NBB], yv[NBB], xv[NBB];
  const float* dg = dA + n*NBB;
  const float* sg = subA + n*NBB;
  for (int j = lane; j < NBB; j += 64) { ds[j] = dg[j]; ss[j] = sg[j]; }
  const float lam = eig[n*NBB + i];
  for (int j = lane; j < NBB; j += 64) {
    uint32_t s = (uint32_t)(j*2654435761u) ^ (uint32_t)(i*40503u + 977u) ^ (uint32_t)(n*9973u);
    s ^= s >> 16; s *= 0x7feb352dU; s ^= s >> 15; s *= 0x846ca68bU; s ^= s >> 16;
    yv[j] = 0.5f + (float)(s & 0xFFFF) * (1.0f/65536.0f);
  }
  __syncthreads();
  const float PIV = 3e-6f;
  for (int pass = 0; pass < 2; ++pass) {
    if (lane == 0) {
      float cd = ds[0] - lam;
      float cu = ss[1];
      float cy = yv[0];
      for (int j = 0; j < NBB-1; ++j) {
        const float bl = ss[j+1];
        const float bd = ds[j+1] - lam;
        const float bu = (j+2 < NBB) ? ss[j+2] : 0.f;
        const float yb = yv[j+1];
        float tud, tu1, tu2, tm, ncd, ncu, ny;
        if (fabsf(bl) > fabsf(cd)) {
          tud = bl; tu1 = bd; tu2 = bu;
          if (fabsf(tud) < PIV) tud = (tud < 0.f) ? -PIV : PIV;
          tm  = cd / tud;
          ncd = cu - tm*bd;
          ncu = -tm*bu;
          ny  = cy - tm*yb;
          yv[j] = yb;
        } else {
          tud = cd; tu1 = cu; tu2 = 0.f;
          if (fabsf(tud) < PIV) tud = (tud < 0.f) ? -PIV : PIV;
          tm  = bl / tud;
          ncd = bd - tm*cu;
          ncu = bu;
          ny  = yb - tm*cy;
          yv[j] = cy;
        }
        ud[j] = tud; u1[j] = tu1; u2[j] = tu2;
        cd = ncd; cu = ncu; cy = ny;
      }
      if (fabsf(cd) < PIV) cd = (cd < 0.f) ? -PIV : PIV;
      ud[NBB-1] = cd; u1[NBB-1] = 0.f; u2[NBB-1] = 0.f; yv[NBB-1] = cy;
      float x2 = yv[NBB-1]/ud[NBB-1];
      xv[NBB-1] = x2;
      float x1 = (yv[NBB-2] - u1[NBB-2]*x2)/ud[NBB-2];
      xv[NBB-2] = x1;
      for (int j = NBB-3; j >= 0; --j) {
        const float xj = (yv[j] - u1[j]*x1 - u2[j]*x2)/ud[j];
        xv[j] = xj;
        x2 = x1; x1 = xj;
      }
    }
    __syncthreads();
    float p2 = 0.f;
    for (int j = lane; j < NBB; j += 64) { const float t = xv[j]; p2 += t*t; }
    #pragma unroll
    for (int off = 32; off > 0; off >>= 1) p2 += __shfl_xor(p2, off);
    const float rin = rsqrtf(p2);
    if (pass == 0) {
      for (int j = lane; j < NBB; j += 64) yv[j] = xv[j]*rin;
      __syncthreads();
    } else {
      float* Ub = Utri + ((size_t)n*NOCC2 + i)*NBB;
      for (int j = lane; j < NBB; j += 64) Ub[j] = xv[j]*rin;
    }
  }
}

// ---------------- back-transform: Uocc = H0...H829 * Utri ----------------
// R11: 4 WGs per matrix (32 columns each), 16 row-groups x 52 rows; halves
// per-step serial depth vs RPT=104 and doubles WG-level parallelism (64 WGs).
#define RPT 52
__global__ __launch_bounds__(512) void k_backxform(const float* __restrict__ Acopy,
                                                   const float* __restrict__ tauA,
                                                   const float* __restrict__ Utri,
                                                   float* __restrict__ Uocc) {
  const int cg = blockIdx.x;         // column quarter (0..3)
  const int n = blockIdx.y;
  const int tid = threadIdx.x;
  const int jc = tid & 31, g = tid >> 5;   // 16 row-groups x 52 rows
  const int col = cg*32 + jc;
  __shared__ float vlds[NBB];
  __shared__ float sred[16*32];
  const float* A = Acopy + (size_t)n*NBB*NBB;
  float U[RPT];
  const float* Ut = Utri + ((size_t)n*NOCC2 + col)*NBB + g*RPT;
  #pragma unroll
  for (int rr = 0; rr < RPT; ++rr) U[rr] = Ut[rr];
  const int rbase = g*RPT;
  for (int k = NBB-3; k >= 0; --k) {
    const float tau = tauA[n*NBB + k];
    if (tau == 0.f) continue;
    const int m = NBB-1-k;
    // transposed reflector storage: v lives in row k, cols k+1..
    for (int idx = tid; idx < m; idx += 512) vlds[idx] = A[(size_t)k*NBB + (k+1+idx)];
    __syncthreads();
    float part = 0.f;
    #pragma unroll
    for (int rr = 0; rr < RPT; ++rr) {
      const int r = rbase + rr;
      if (r > k) part += U[rr]*vlds[r-k-1];
    }
    sred[g*32 + jc] = part;
    __syncthreads();
    float ssum = 0.f;
    #pragma unroll
    for (int t = 0; t < 16; ++t) ssum += sred[t*32 + jc];
    const float s = tau*ssum;
    #pragma unroll
    for (int rr = 0; rr < RPT; ++rr) {
      const int r = rbase + rr;
      if (r > k) U[rr] -= s*vlds[r-k-1];
    }
    __syncthreads();
  }
  float* Ub = Uocc + (size_t)n*NBB*NOCC2;
  #pragma unroll
  for (int rr = 0; rr < RPT; ++rr) Ub[(size_t)(rbase+rr)*NOCC2 + col] = U[rr];
}

// ---------------- C = h_new * Uocc  (832x832 @ 832x128 per batch) ----------------
__global__ __launch_bounds__(256) void k_gemmC(const float* __restrict__ h,
                                               const float* __restrict__ Uocc,
                                               float* __restrict__ C) {
  const int rt = blockIdx.x, n = blockIdx.y;
  const int tid = threadIdx.x;
  __shared__ __align__(16) float hT[64*33];
  __shared__ __align__(16) float Ut[32*128];
  const int ty = tid >> 5, tx = tid & 31;
  float acc[8][4] = {};
  const float* hb = h + (size_t)n*NBB*NBB + (size_t)rt*64*NBB;
  const float* Ub = Uocc + (size_t)n*NBB*NOCC2;
  for (int k0 = 0; k0 < NBB; k0 += 32) {
    for (int idx = tid; idx < 64*32; idx += 256) {
      const int r = idx >> 5, c = idx & 31;
      hT[r*33 + c] = hb[(size_t)r*NBB + k0 + c];
    }
    for (int idx = tid; idx < 32*128; idx += 256) {
      const int r = idx >> 7, c = idx & 127;
      Ut[idx] = Ub[(size_t)(k0 + r)*NOCC2 + c];
    }
    __syncthreads();
    for (int kk = 0; kk < 32; ++kk) {
      const float4 b4 = *(const float4*)&Ut[kk*128 + tx*4];
      #pragma unroll
      for (int q = 0; q < 8; ++q) {
        const float a = hT[(ty*8 + q)*33 + kk];
        acc[q][0] += a*b4.x; acc[q][1] += a*b4.y; acc[q][2] += a*b4.z; acc[q][3] += a*b4.w;
      }
    }
    __syncthreads();
  }
  float* Cb = C + (size_t)n*NBB*NOCC2;
  #pragma unroll
  for (int q = 0; q < 8; ++q)
    #pragma unroll
    for (int p = 0; p < 4; ++p)
      Cb[(size_t)(rt*64 + ty*8 + q)*NOCC2 + tx*4 + p] = acc[q][p];
}

// ---------------- E = sum(e_occ) + Tr(Uocc^T h Uocc) + nuc ----------------
__global__ __launch_bounds__(256) void k_final(const float* __restrict__ eig,
                                               const float* __restrict__ Uocc, const float* __restrict__ C,
                                               const float* __restrict__ pos, const int* __restrict__ numbers,
                                               float* __restrict__ E_out) {
  const int n = blockIdx.x, tid = threadIdx.x;
  __shared__ float rb[256];
  float local = 0.f;
  for (int i = tid; i < NOCC2; i += 256) local += eig[n*NBB + i];
  const float* Ub = Uocc + (size_t)n*NBB*NOCC2;
  const float* Cb = C + (size_t)n*NBB*NOCC2;
  for (int idx = tid; idx < NBB*NOCC2; idx += 256) local += Ub[idx]*Cb[idx];
  float ln = 0.f;
  for (int t = tid; t < NPAIR; t += 256) {
    int kk, ll;
    pair_decode(t, kk, ll);
    const float dx = pos[(n*NK + kk)*3 + 0] - pos[(n*NK + ll)*3 + 0];
    const float dy = pos[(n*NK + kk)*3 + 1] - pos[(n*NK + ll)*3 + 1];
    const float dz = pos[(n*NK + kk)*3 + 2] - pos[(n*NK + ll)*3 + 2];
    const float d2 = dx*dx + dy*dy + dz*dz;
    const float Z = (float)(numbers[kk]*numbers[ll]);
    ln += Z / sqrtf(d2);
  }
  local += ln * A0C;
  rb[tid] = local;
  __syncthreads();
  for (int s = 128; s > 0; s >>= 1) {
    if (tid < s) rb[tid] += rb[tid + s];
    __syncthreads();
  }
  if (tid == 0) E_out[n] = rb[0];
}

extern "C" void kernel_launch(void* const* d_in, const int* in_sizes, int n_in,
                              void* d_out, int out_size, void* d_ws, size_t ws_size,
                              hipStream_t stream) {
  (void)in_sizes; (void)n_in; (void)out_size; (void)ws_size;
  const float* mu      = (const float*)d_in[0];
  const float* hnew    = (const float*)d_in[1];
  const float* pos     = (const float*)d_in[2];
  const float* Foff    = (const float*)d_in[3];
  const float* tW      = (const float*)d_in[4];
  const float* tb      = (const float*)d_in[5];
  const float* Won     = (const float*)d_in[6];
  const float* bon     = (const float*)d_in[7];
  const float* Woff    = (const float*)d_in[8];
  const float* boff    = (const float*)d_in[9];
  const int*   numbers = (const int*)d_in[10];

  float* out   = (float*)d_out;
  float* Fout  = out;                               // [16][832][832]
  float* e_out = out + (size_t)NBATCH*NBB*NBB;      // [16][832]
  float* E_out = e_out + (size_t)NBATCH*NBB;        // [16]

  float* ws    = (float*)d_ws;
  float* Acopy = ws + OFF_ACOPY;
  float* xbuf  = ws + OFF_X;
  float* Sbuf  = ws + OFF_S;
  float* dA    = ws + OFF_D;
  float* subA  = ws + OFF_SUB;
  float* tauA  = ws + OFF_TAU;
  float* eig   = ws + OFF_EIG;
  float* Utri  = ws + OFF_UTRI;
  float* Uocc  = ws + OFF_UOCC;
  float* Cbuf  = ws + OFF_C;     // overlays Utri
  float* Wpan  = ws + OFF_WPAN;  // overlays Utri (dead until k_invit)
  float* cbufA = ws + OFF_CBUF;
  float* slotA = ws + OFF_SLOT;
  int*   barA  = (int*)(ws + OFF_BARC);

  // zero the per-matrix barrier counters (graph-captured; runs every replay)
  hipMemsetAsync((void*)barA, 0, NBATCH*sizeof(int), stream);

  k_x<<<dim3(NK, NBATCH), dim3(256), 0, stream>>>(mu, tW, tb, xbuf);
  k_S<<<dim3(NBATCH), dim3(256), 0, stream>>>(xbuf, Sbuf);
  k_diag<<<dim3(NK, NBATCH), dim3(256), 0, stream>>>(xbuf, Sbuf, Won, bon, hnew, Foff, Fout, Acopy);
  k_off<<<dim3(6, 16, NBATCH), dim3(256), 0, stream>>>(xbuf, Woff, boff, hnew, Foff, Fout, Acopy);
  k_tridiag_panel<<<dim3(GW, NBATCH), dim3(TPW), 0, stream>>>(Acopy, dA, subA, tauA, Wpan, cbufA, slotA, barA);
  k_bisect<<<dim3(4, NBATCH), dim3(256), 0, stream>>>(dA, subA, eig, e_out);
  k_invit<<<dim3(NOCC2, NBATCH), dim3(64), 0, stream>>>(dA, subA, eig, Utri);
  k_backxform<<<dim3(4, NBATCH), dim3(512), 0, stream>>>(Acopy, tauA, Utri, Uocc);
  k_gemmC<<<dim3(13, NBATCH), dim3(256), 0, stream>>>(hnew, Uocc, Cbuf);
  k_final<<<dim3(NBATCH), dim3(256), 0, stream>>>(eig, Uocc, Cbuf, pos, numbers, E_out);
}

// Round 12
// 35139.069 us; speedup vs baseline: 2.2247x; 1.0260x over previous
//
#include <hip/hip_runtime.h>
#include <math.h>
#include <stdint.h>

// Problem constants
#define NBATCH 16
#define NK     32
#define NTDS   768      // 3*DS
#define NMM    676      // BM*BM
#define NBM    26
#define NBB    832      // B = K*BM
#define NOCC2  128
#define NPAIR  496      // K*(K-1)/2
#define FSCALE 1.0e-4f
#define A0C    0.5291772f

// ---------------- workspace layout (in floats) ----------------
#define OFF_ACOPY 0ull
#define SZ_ACOPY  (16ull*832*832)
#define OFF_X     (OFF_ACOPY + SZ_ACOPY)
#define SZ_X      (16ull*32*768)
#define OFF_S     (OFF_X + SZ_X)
#define SZ_S      (16ull*768)
#define OFF_D     (OFF_S + SZ_S)
#define OFF_SUB   (OFF_D   + 16ull*832)
#define OFF_TAU   (OFF_SUB + 16ull*832)
#define OFF_EIG   (OFF_TAU + 16ull*832)
#define OFF_UTRI  (OFF_EIG + 16ull*832)
#define SZ_UTRI   (16ull*128*832)
#define OFF_UOCC  (OFF_UTRI + SZ_UTRI)
#define OFF_C     OFF_UTRI   /* C overlays Utri (dead after backxform) */
// tridiag scratch overlays the Utri region (Utri written only later by k_invit)
#define PB   32   // panel width
#define GW   16   // workgroups per matrix (R7-proven config)
#define TPW  1024 // threads per workgroup
#define NWV  16   // waves per WG
#define QMAX 52   // max own rows per WG (832/16)
#define SLOTSTR 1088
#define OFF_WPAN  OFF_UTRI                        /* 16*832*32 = 425,984 */
#define OFF_CBUF  (OFF_WPAN + 16ull*832*32)       /* 16*832 */
#define OFF_SLOT  (OFF_CBUF + 16ull*832)          /* 16*1088 */
#define OFF_BARC  (OFF_SLOT + 16ull*SLOTSTR)      /* 16 ints */

__device__ __forceinline__ void pair_decode(int t, int& k, int& l) {
  int kk = (int)((1.0f + sqrtf(1.0f + 8.0f*(float)t)) * 0.5f);
  while (kk*(kk-1)/2 > t) --kk;
  while ((kk+1)*kk/2 <= t) ++kk;
  k = kk; l = t - kk*(kk-1)/2;
}

// Cross-WG READ: agent-scope bypass load (sc0 sc1) — reads through to the MALL
// (memory-side, unbypassable), so it observes completed bypass stores and
// wbl2-released cached stores with no acquire-invalidate.
__device__ __forceinline__ float gld(const float* p) {
  unsigned int u = __hip_atomic_load((const unsigned int*)p, __ATOMIC_RELAXED, __HIP_MEMORY_SCOPE_AGENT);
  return __uint_as_float(u);
}
// Cross-WG WRITE: agent-scope bypass store (sc0 sc1) — write-through to MALL.
// vmcnt retirement (drained by __syncthreads before the barrier flag bump)
// means the value is at the MALL before any other WG can observe the flag.
__device__ __forceinline__ void gst(float* p, float v) {
  __hip_atomic_store((unsigned int*)p, __float_as_uint(v), __ATOMIC_RELAXED, __HIP_MEMORY_SCOPE_AGENT);
}

// ---------------- x = mu @ transfer_W + b ----------------
__global__ __launch_bounds__(256) void k_x(const float* __restrict__ mu,
                                           const float* __restrict__ tW,
                                           const float* __restrict__ tb,
                                           float* __restrict__ x) {
  const int k = blockIdx.x, n = blockIdx.y, tid = threadIdx.x;
  __shared__ float mus[384];
  const float* mub = mu + (size_t)(n*NK + k)*384;
  for (int i = tid; i < 384; i += 256) mus[i] = mub[i];
  __syncthreads();
  float* xb = x + (size_t)(n*NK + k)*NTDS;
  for (int oo = tid; oo < NTDS; oo += 256) {
    const int d = oo >> 8, i = oo & 255;
    float acc = tb[i];
    const float* mrow = &mus[d*128];
    for (int a = 0; a < 128; ++a) acc += mrow[a]*tW[a*256 + i];
    xb[oo] = acc;
  }
}

// ---------------- S[n][dd] = sum_k x[n][k][dd] ----------------
__global__ __launch_bounds__(256) void k_S(const float* __restrict__ x, float* __restrict__ S) {
  const int n = blockIdx.x, tid = threadIdx.x;
  for (int dd = tid; dd < NTDS; dd += 256) {
    float s = 0.f;
    for (int k = 0; k < NK; ++k) s += x[(size_t)(n*NK + k)*NTDS + dd];
    S[n*NTDS + dd] = s;
  }
}

// ---------------- diagonal blocks ----------------
__global__ __launch_bounds__(256) void k_diag(const float* __restrict__ x, const float* __restrict__ S,
                                              const float* __restrict__ Won, const float* __restrict__ bon,
                                              const float* __restrict__ hnew, const float* __restrict__ Foff,
                                              float* __restrict__ Fout, float* __restrict__ Acopy) {
  const int k = blockIdx.x, n = blockIdx.y, tid = threadIdx.x;
  __shared__ float q[NTDS];
  __shared__ float M[NMM];
  const float* xb = x + (size_t)(n*NK + k)*NTDS;
  const float* Sb = S + n*NTDS;
  for (int i = tid; i < NTDS; i += 256) q[i] = xb[i]*Sb[i];
  __syncthreads();
  for (int m = tid; m < NMM; m += 256) {
    float acc = 32.0f * bon[m];
    for (int dd = 0; dd < NTDS; ++dd) acc += q[dd]*Won[(size_t)dd*NMM + m];
    M[m] = acc;
  }
  __syncthreads();
  const float* hb = hnew + (size_t)n*NBB*NBB;
  float* Fb = Fout + (size_t)n*NBB*NBB;
  float* Ab = Acopy + (size_t)n*NBB*NBB;
  for (int m = tid; m < NMM; m += 256) {
    const int a = m/26, b = m - a*26;
    const float val = 0.5f*(M[m] + M[b*26 + a]);
    const int P = k*26 + a, Q = k*26 + b;
    const size_t idx = (size_t)P*NBB + Q;
    const float fo = Foff[idx];
    const float hv = hb[idx];
    const float Fv = (fabsf(hv) > 1e-7f) ? (val*FSCALE + fo) : fo;
    Fb[idx] = Fv; Ab[idx] = Fv;
  }
}

// ---------------- off-diagonal blocks: GEMM over pairs ----------------
__global__ __launch_bounds__(256) void k_off(const float* __restrict__ x,
                                             const float* __restrict__ Woff, const float* __restrict__ boff,
                                             const float* __restrict__ hnew, const float* __restrict__ Foff,
                                             float* __restrict__ Fout, float* __restrict__ Acopy) {
  const int ct = blockIdx.x, pt = blockIdx.y, n = blockIdx.z;
  const int tid = threadIdx.x;
  __shared__ __align__(16) float At[32*65];
  __shared__ __align__(16) float Bt[64*128];
  __shared__ int klk[32], kll[32];
  if (tid < 32) {
    int pr = pt*32 + tid, kk = 1, ll = 0;
    if (pr < NPAIR) pair_decode(pr, kk, ll);
    klk[tid] = kk; kll[tid] = ll;
  }
  __syncthreads();
  const int ty = tid >> 5, tx = tid & 31;
  const int r0 = ty*4, c0 = tx*4;
  float acc[4][4] = {};
  for (int dd0 = 0; dd0 < NTDS; dd0 += 64) {
    for (int idx = tid; idx < 2048; idx += 256) {
      const int r = idx >> 6, c = idx & 63;
      const int pr = pt*32 + r;
      float v = 0.f;
      if (pr < NPAIR) {
        const int kk = klk[r], ll = kll[r];
        v = x[(size_t)(n*NK + kk)*NTDS + dd0 + c] * x[(size_t)(n*NK + ll)*NTDS + dd0 + c];
      }
      At[r*65 + c] = v;
    }
    for (int idx = tid; idx < 8192; idx += 256) {
      const int r = idx >> 7, c = idx & 127;
      const int col = ct*128 + c;
      Bt[idx] = (col < NMM) ? Woff[(size_t)(dd0 + r)*NMM + col] : 0.f;
    }
    __syncthreads();
    for (int kk = 0; kk < 64; ++kk) {
      float av[4];
      av[0] = At[(r0+0)*65 + kk];
      av[1] = At[(r0+1)*65 + kk];
      av[2] = At[(r0+2)*65 + kk];
      av[3] = At[(r0+3)*65 + kk];
      const float4 b4 = *(const float4*)&Bt[kk*128 + c0];
      const float bb[4] = {b4.x, b4.y, b4.z, b4.w};
      #pragma unroll
      for (int qq = 0; qq < 4; ++qq)
        #pragma unroll
        for (int pp = 0; pp < 4; ++pp)
          acc[qq][pp] += av[qq]*bb[pp];
    }
    __syncthreads();
  }
  const float* hb = hnew + (size_t)n*NBB*NBB;
  float* Fb = Fout + (size_t)n*NBB*NBB;
  float* Ab = Acopy + (size_t)n*NBB*NBB;
  for (int qq = 0; qq < 4; ++qq) {
    const int pr = pt*32 + r0 + qq;
    if (pr >= NPAIR) continue;
    const int kk = klk[r0+qq], ll = kll[r0+qq];
    for (int pp = 0; pp < 4; ++pp) {
      const int m = ct*128 + c0 + pp;
      if (m >= NMM) continue;
      const float val = acc[qq][pp] + boff[m];
      const int a = m/26, b = m - a*26;
      const int P = kk*26 + a, Q = ll*26 + b;
      const size_t i1 = (size_t)P*NBB + Q;
      const float fo1 = Foff[i1], hv1 = hb[i1];
      const float Fv1 = (fabsf(hv1) > 1e-7f) ? (val*FSCALE + fo1) : fo1;
      Fb[i1] = Fv1; Ab[i1] = Fv1;
      const size_t i2 = (size_t)Q*NBB + P;
      const float fo2 = Foff[i2], hv2 = hb[i2];
      const float Fv2 = (fabsf(hv2) > 1e-7f) ? (val*FSCALE + fo2) : fo2;
      Fb[i2] = Fv2; Ab[i2] = Fv2;
    }
  }
}

// ================= blocked (latrd) multi-WG tridiagonalization =================
// R12: float4 matvec with ALIGNED LDS v copy (vsh4, shifted so reads are one
// ds_read_b128/lane at 16B stride — conflict-free; R11's scalar vsh reads were
// 8-way conflicted, 3.3e8 conflict cycles). Vk1s/Wk1s prefetch moved into
// epoch X (their producers are >=1 barrier old).
// Coherence protocol unchanged (proven R7): gst/gld bypass for ALL cross-WG
// data; relaxed rbar per column; release gbar per panel boundary.
__device__ __forceinline__ void rbar(int* cnt, int target) {
  __syncthreads();   // emits s_waitcnt vmcnt(0) before s_barrier: bypass stores MALL-complete
  if (threadIdx.x == 0) {
    asm volatile("" ::: "memory");
    __hip_atomic_fetch_add(cnt, 1, __ATOMIC_RELAXED, __HIP_MEMORY_SCOPE_AGENT);
    while (__hip_atomic_load(cnt, __ATOMIC_RELAXED, __HIP_MEMORY_SCOPE_AGENT) < target)
      __builtin_amdgcn_s_sleep(1);
    asm volatile("" ::: "memory");
  }
  __syncthreads();
}
__device__ __forceinline__ void gbar(int* cnt, int target) {
  __syncthreads();
  if (threadIdx.x == 0) {
    __hip_atomic_fetch_add(cnt, 1, __ATOMIC_RELEASE, __HIP_MEMORY_SCOPE_AGENT);  // wbl2
    while (__hip_atomic_load(cnt, __ATOMIC_RELAXED, __HIP_MEMORY_SCOPE_AGENT) < target)
      __builtin_amdgcn_s_sleep(1);
  }
  __syncthreads();
}

__device__ __forceinline__ float wg_reduce16(float v, volatile float* sred) {
  #pragma unroll
  for (int off = 32; off > 0; off >>= 1) v += __shfl_down(v, off);
  const int tid = threadIdx.x;
  if ((tid & 63) == 0) sred[tid >> 6] = v;
  __syncthreads();
  float r = 0.f;
  #pragma unroll
  for (int t = 0; t < NWV; ++t) r += sred[t];
  __syncthreads();
  return r;
}

__global__ __launch_bounds__(TPW) void k_tridiag_panel(float* __restrict__ Acopy,
                                                       float* __restrict__ dA,
                                                       float* __restrict__ subA,
                                                       float* __restrict__ tauA,
                                                       float* __restrict__ Wpan,
                                                       float* __restrict__ cbufA,
                                                       float* __restrict__ slotA,
                                                       int* __restrict__ barA) {
  const int g = blockIdx.x;          // WG within matrix
  const int n = blockIdx.y;          // matrix
  const int tid = threadIdx.x;
  const int lane = tid & 63, wv = tid >> 6;
  float* A    = Acopy + (size_t)n*NBB*NBB;
  float* Wbuf = Wpan  + (size_t)n*NBB*PB;
  float* cbuf = cbufA + (size_t)n*NBB;
  float* slot = slotA + (size_t)n*SLOTSTR;
  float* normp = slot;          // [16]
  float* vavp  = slot + 16;     // [16]
  float* alphaS= slot + 32;     // [1]
  float* ynextS= slot + 33;     // [1]
  float* d1pA  = slot + 64;     // [16][32]
  float* d2pA  = slot + 576;    // [16][32]
  int*   cnt   = barA + n;

  __shared__ float vsh[NBB];
  __shared__ __align__(16) float vsh4[NBB+8];   // v shifted so matvec reads are 16B-aligned
  __shared__ float yloc[QMAX];
  __shared__ float Vloc[QMAX*33];
  __shared__ float Wloc[QMAX*33];
  __shared__ float Vt[64*33];
  __shared__ float Wt[64*33];
  __shared__ float d1s[PB], d2s[PB], Vk1s[PB], Wk1s[PB];
  __shared__ float sred[NWV];
  __shared__ float s_tau, s_scale, s_vav, s_ynext;
  int ep = 0;

  // ---- prologue: c = A[:,0], norm partials, alpha (all comms via gst) ----
  {
    const int q0p = (16 - g) >> 4;   // first q with 16q+g >= 1
    float np = 0.f;
    const int q = q0p + tid;
    if (q < QMAX) {
      const int j = 16*q + g;
      const float cv = A[(size_t)j*NBB];   // own row (prior kernel, dispatch-coherent)
      gst(&cbuf[j], cv);
      if (j >= 2) np = cv*cv;
      if (j == 1) gst(alphaS, cv);
    }
    const float s = wg_reduce16(np, sred);
    if (tid == 0) gst(&normp[g], s);
  }
  ++ep; gbar(cnt, ep*GW);

  for (int k0 = 0; k0 < NBB-2; k0 += PB) {
    const int ilim = (NBB-2-k0 < PB) ? (NBB-2-k0) : PB;
    for (int i = 0; i < ilim; ++i) {
      const int k = k0 + i;
      const int m = NBB-1-k;
      const int q0 = (k + 16 - g) >> 4;   // first q with 16q+g >= k+1
      const int cs = k+1;
      const int nh = (4 - (cs & 3)) & 3;  // head elems to 16B alignment
      const int ca = cs + nh;

      // ================= Epoch X =================
      if (tid == 0) {
        float xn2 = 0.f;
        #pragma unroll
        for (int t = 0; t < GW; ++t) xn2 += gld(&normp[t]);
        const float alpha = gld(alphaS);
        float tau, scale, beta;
        if (xn2 < 1e-26f) {
          beta = alpha; tau = 0.f; scale = 0.f;
        } else {
          beta  = -copysignf(sqrtf(alpha*alpha + xn2), alpha);
          tau   = (beta - alpha) / beta;
          scale = 1.0f / (alpha - beta);
        }
        s_tau = tau; s_scale = scale;
        if (g == 0) { subA[n*NBB + k + 1] = beta; tauA[n*NBB + k] = tau; }
      }
      __syncthreads();
      const float tau = s_tau, scale = s_scale;
      // build v in LDS (both copies; cbuf is cross-WG -> bypass loads)
      for (int idx = tid; idx < m; idx += TPW) {
        const float val = (idx == 0) ? 1.0f : gld(&cbuf[k+1+idx])*scale;
        vsh[idx] = val;
        vsh4[4 + idx - nh] = val;   // element for column cs+idx lands 16B-aligned at ca
      }
      __syncthreads();
      // store v (own entries) into row k (transposed reflector, BYPASS) + Vloc
      {
        const int q = q0 + tid;
        if (q < QMAX) {
          const int j = 16*q + g;
          const float val = vsh[j-(k+1)];
          gst(&A[(size_t)k*NBB + j], val);
          Vloc[q*33 + i] = val;
        }
      }
      // d1/d2 partials over own rows (p < i)
      for (int p = wv; p < i; p += NWV) {
        float a1 = 0.f, a2 = 0.f;
        const int q = q0 + lane;
        if (q < QMAX) {
          const int j = 16*q + g;
          const float vj = vsh[j-(k+1)];
          a1 = Vloc[q*33 + p]*vj;
          a2 = Wloc[q*33 + p]*vj;
        }
        #pragma unroll
        for (int off = 32; off > 0; off >>= 1) { a1 += __shfl_down(a1, off); a2 += __shfl_down(a2, off); }
        if (lane == 0) { gst(&d1pA[g*PB + p], a1); gst(&d2pA[g*PB + p], a2); }
      }
      // matvec y = A0 v over own rows (float4 A reads + float4 aligned v reads)
      {
        float vavl = 0.f;
        for (int q = q0 + wv; q < QMAX; q += NWV) {
          const int j = 16*q + g;
          const float* Ar = A + (size_t)j*NBB;
          float acc = 0.f;
          if (lane < nh) acc += Ar[cs+lane]*vsh[lane];
          for (int c = ca + 4*lane; c < NBB; c += 256) {
            const float4 a4 = *(const float4*)&Ar[c];
            const float4 v4 = *(const float4*)&vsh4[4 + c - ca];
            acc += a4.x*v4.x + a4.y*v4.y + a4.z*v4.z + a4.w*v4.w;
          }
          #pragma unroll
          for (int off = 32; off > 0; off >>= 1) acc += __shfl_down(acc, off);
          if (lane == 0) {
            yloc[q] = acc;
            vavl += vsh[j-(k+1)]*acc;
            if (j == k+1) gst(ynextS, acc);
          }
        }
        const float vv = wg_reduce16(vavl, sred);
        if (tid == 0) gst(&vavp[g], vv);
      }
      // prefetch Y-phase inputs that are >=1 barrier old (hide MALL latency)
      if (tid < i) {
        Vk1s[tid] = gld(&A[(size_t)(k0+tid)*NBB + (k+1)]);
        Wk1s[tid] = gld(&Wbuf[(size_t)(k+1)*PB + tid]);
      }
      ++ep; rbar(cnt, ep*GW);

      // ================= Epoch Y =================
      if (tid < i) {
        float s1 = 0.f, s2 = 0.f;
        #pragma unroll
        for (int g2 = 0; g2 < GW; ++g2) { s1 += gld(&d1pA[g2*PB + tid]); s2 += gld(&d2pA[g2*PB + tid]); }
        d1s[tid] = s1; d2s[tid] = s2;
      }
      if (tid == TPW-1) {
        float sv = 0.f;
        #pragma unroll
        for (int t = 0; t < GW; ++t) sv += gld(&vavp[t]);
        s_vav = sv; s_ynext = gld(ynextS);
      }
      __syncthreads();
      // redundant scalars
      float s12 = 0.f, wk1acc = 0.f;
      for (int p = 0; p < i; ++p) { s12 += d1s[p]*d2s[p]; wk1acc += Vk1s[p]*d2s[p] + Wk1s[p]*d1s[p]; }
      const float corr = 0.5f*tau*tau*(s_vav - 2.f*s12);
      const float wk1 = tau*(s_ynext - wk1acc) - corr;
      // own-row w, then c' for column k+1
      {
        const int q = q0 + tid;
        float np = 0.f;
        if (q < QMAX) {
          const int j = 16*q + g;
          float wacc = 0.f;
          for (int p = 0; p < i; ++p) wacc += Vloc[q*33 + p]*d2s[p] + Wloc[q*33 + p]*d1s[p];
          const float vj = vsh[j-(k+1)];
          const float wj = tau*(yloc[q] - wacc) - corr*vj;
          Wloc[q*33 + i] = wj;
          gst(&Wbuf[(size_t)j*PB + i], wj);
          if (j >= k+2) {
            float cacc = 0.f;
            for (int p = 0; p < i; ++p) cacc += Vloc[q*33 + p]*Wk1s[p] + Wloc[q*33 + p]*Vk1s[p];
            cacc += vj*wk1 + wj;   // p = i term (V[k+1,i] = 1)
            const float cp = A[(size_t)j*NBB + (k+1)] - cacc;   // own row, clean cached
            gst(&cbuf[j], cp);
            if (j >= k+3) np = cp*cp;
            if (j == k+2) gst(alphaS, cp);
          }
        }
        const float ns = wg_reduce16(np, sred);
        if (tid == 0) gst(&normp[g], ns);
      }
      // diagonal extraction d[k] (own row plain; cross-WG data via bypass)
      if (g == (k & 15) && tid == 0) {
        float dk = A[(size_t)k*NBB + k];
        for (int p = 0; p < i; ++p)
          dk -= 2.f * gld(&A[(size_t)(k0+p)*NBB + k]) * gld(&Wbuf[(size_t)k*PB + p]);
        dA[n*NBB + k] = dk;
      }
      ++ep; rbar(cnt, ep*GW);
    }

    // ================= syr2k: A22 -= V W^T + W V^T =================
    if (k0 + PB < NBB-2) {
      const int kp = k0 + PB;
      const int q0s = (kp + 15 - g) >> 4;   // first q with 16q+g >= kp
      for (int c0 = kp+1; c0 < NBB; c0 += 64) {
        const int nc = (NBB - c0 < 64) ? (NBB - c0) : 64;
        for (int idx = tid; idx < 2048; idx += TPW) {
          const int p = idx >> 6, cc = idx & 63;
          Vt[cc*33 + p] = (cc < nc) ? gld(&A[(size_t)(k0+p)*NBB + c0 + cc]) : 0.f;
        }
        for (int idx = tid; idx < 2048; idx += TPW) {
          const int p = idx & 31, cc = idx >> 5;
          Wt[cc*33 + p] = (cc < nc) ? gld(&Wbuf[(size_t)(c0+cc)*PB + p]) : 0.f;
        }
        __syncthreads();
        for (int q = q0s + wv; q < QMAX; q += NWV) {
          const int j = 16*q + g;
          if (lane < nc) {
            const int c = c0 + lane;
            float acc = 0.f;
            #pragma unroll
            for (int p = 0; p < PB; ++p)
              acc += Vloc[q*33 + p]*Wt[lane*33 + p] + Wloc[q*33 + p]*Vt[lane*33 + p];
            A[(size_t)j*NBB + c] -= acc;   // own row, cached (cleaned below)
          }
        }
        __syncthreads();
      }
      // diagonal entry [kp][kp]
      if (g == (kp & 15) && tid == 0) {
        const int qd = kp >> 4;
        float acc = 0.f;
        #pragma unroll
        for (int p = 0; p < PB; ++p) acc += Vloc[qd*33 + p]*Wloc[qd*33 + p];
        A[(size_t)kp*NBB + kp] -= 2.f*acc;
      }
      ++ep; gbar(cnt, ep*GW);   // RELEASE: clean syr2k dirt before next panel's gst reflectors
    }
  }

  // ---- epilogue (cross-WG data via bypass loads) ----
  if (g == 0 && tid == 0) {
    const int k0l = ((NBB-3)/PB)*PB;       // 800
    const int np_ = NBB-2-k0l;             // 30
    float dm2 = gld(&A[(size_t)(NBB-2)*NBB + (NBB-2)]);
    float dm1 = gld(&A[(size_t)(NBB-1)*NBB + (NBB-1)]);
    for (int p = 0; p < np_; ++p) {
      dm2 -= 2.f * gld(&A[(size_t)(k0l+p)*NBB + (NBB-2)]) * gld(&Wbuf[(size_t)(NBB-2)*PB + p]);
      dm1 -= 2.f * gld(&A[(size_t)(k0l+p)*NBB + (NBB-1)]) * gld(&Wbuf[(size_t)(NBB-1)*PB + p]);
    }
    dA[n*NBB + NBB-2] = dm2;
    dA[n*NBB + NBB-1] = dm1;
    subA[n*NBB + NBB-1] = gld(alphaS);
    subA[n*NBB + 0] = 0.f;
    tauA[n*NBB + NBB-2] = 0.f;
    tauA[n*NBB + NBB-1] = 0.f;
  }
}

// ---------------- all eigenvalues via bisection (Sturm counts) ----------------
__global__ __launch_bounds__(256) void k_bisect(const float* __restrict__ dA, const float* __restrict__ subA,
                                                float* __restrict__ eig, float* __restrict__ e_out) {
  const int n = blockIdx.y;
  const int i = blockIdx.x*256 + threadIdx.x;
  __shared__ float ds[NBB], ss[NBB];
  const float* dg = dA + n*NBB;
  const float* sg = subA + n*NBB;
  for (int j = threadIdx.x; j < NBB; j += 256) { ds[j] = dg[j]; ss[j] = sg[j]; }
  __syncthreads();
  if (i >= NBB) return;
  float lo = 1e30f, hi = -1e30f;
  for (int j = 0; j < NBB; ++j) {
    const float r = fabsf(ss[j]) + ((j+1 < NBB) ? fabsf(ss[j+1]) : 0.f);
    lo = fminf(lo, ds[j]-r); hi = fmaxf(hi, ds[j]+r);
  }
  const float pad = 1e-3f*(hi-lo) + 1e-3f;
  lo -= pad; hi += pad;
  for (int it = 0; it < 38; ++it) {
    const float mid = 0.5f*(lo+hi);
    int cnt = 0;
    float qv = ds[0]-mid;
    if (qv < 0.f) cnt++;
    for (int j = 1; j < NBB; ++j) {
      const float e = ss[j];
      if (fabsf(qv) < 1e-20f) qv = -1e-20f;
      qv = ds[j]-mid - e*e/qv;
      if (qv < 0.f) cnt++;
    }
    if (cnt > i) hi = mid; else lo = mid;
  }
  const float lam = 0.5f*(lo+hi);
  eig[n*NBB + i] = lam;
  e_out[n*NBB + i] = lam;
}

// ---------------- inverse iteration on T for the 128 lowest ----------------
__global__ __launch_bounds__(64) void k_invit(const float* __restrict__ dA, const float* __restrict__ subA,
                                              const float* __restrict__ eig, float* __restrict__ Utri) {
  const int i = blockIdx.x, n = blockIdx.y;
  const int lane = threadIdx.x;
  __shared__ float ds[NBB], ss[NBB], ud[NBB], u1[NBB], u2[NBB], yv[NBB], xv[NBB];
  const float* dg = dA + n*NBB;
  const float* sg = subA + n*NBB;
  for (int j = lane; j < NBB; j += 64) { ds[j] = dg[j]; ss[j] = sg[j]; }
  const float lam = eig[n*NBB + i];
  for (int j = lane; j < NBB; j += 64) {
    uint32_t s = (uint32_t)(j*2654435761u) ^ (uint32_t)(i*40503u + 977u) ^ (uint32_t)(n*9973u);
    s ^= s >> 16; s *= 0x7feb352dU; s ^= s >> 15; s *= 0x846ca68bU; s ^= s >> 16;
    yv[j] = 0.5f + (float)(s & 0xFFFF) * (1.0f/65536.0f);
  }
  __syncthreads();
  const float PIV = 3e-6f;
  for (int pass = 0; pass < 2; ++pass) {
    if (lane == 0) {
      float cd = ds[0] - lam;
      float cu = ss[1];
      float cy = yv[0];
      for (int j = 0; j < NBB-1; ++j) {
        const float bl = ss[j+1];
        const float bd = ds[j+1] - lam;
        const float bu = (j+2 < NBB) ? ss[j+2] : 0.f;
        const float yb = yv[j+1];
        float tud, tu1, tu2, tm, ncd, ncu, ny;
        if (fabsf(bl) > fabsf(cd)) {
          tud = bl; tu1 = bd; tu2 = bu;
          if (fabsf(tud) < PIV) tud = (tud < 0.f) ? -PIV : PIV;
          tm  = cd / tud;
          ncd = cu - tm*bd;
          ncu = -tm*bu;
          ny  = cy - tm*yb;
          yv[j] = yb;
        } else {
          tud = cd; tu1 = cu; tu2 = 0.f;
          if (fabsf(tud) < PIV) tud = (tud < 0.f) ? -PIV : PIV;
          tm  = bl / tud;
          ncd = bd - tm*cu;
          ncu = bu;
          ny  = yb - tm*cy;
          yv[j] = cy;
        }
        ud[j] = tud; u1[j] = tu1; u2[j] = tu2;
        cd = ncd; cu = ncu; cy = ny;
      }
      if (fabsf(cd) < PIV) cd = (cd < 0.f) ? -PIV : PIV;
      ud[NBB-1] = cd; u1[NBB-1] = 0.f; u2[NBB-1] = 0.f; yv[NBB-1] = cy;
      float x2 = yv[NBB-1]/ud[NBB-1];
      xv[NBB-1] = x2;
      float x1 = (yv[NBB-2] - u1[NBB-2]*x2)/ud[NBB-2];
      xv[NBB-2] = x1;
      for (int j = NBB-3; j >= 0; --j) {
        const float xj = (yv[j] - u1[j]*x1 - u2[j]*x2)/ud[j];
        xv[j] = xj;
        x2 = x1; x1 = xj;
      }
    }
    __syncthreads();
    float p2 = 0.f;
    for (int j = lane; j < NBB; j += 64) { const float t = xv[j]; p2 += t*t; }
    #pragma unroll
    for (int off = 32; off > 0; off >>= 1) p2 += __shfl_xor(p2, off);
    const float rin = rsqrtf(p2);
    if (pass == 0) {
      for (int j = lane; j < NBB; j += 64) yv[j] = xv[j]*rin;
      __syncthreads();
    } else {
      float* Ub = Utri + ((size_t)n*NOCC2 + i)*NBB;
      for (int j = lane; j < NBB; j += 64) Ub[j] = xv[j]*rin;
    }
  }
}

// ---------------- back-transform: Uocc = H0...H829 * Utri ----------------
// R12: register-staged double-buffered reflector rows (T14): issue global
// loads of row k-1 at loop top, write to alternate LDS buffer after compute.
// Hides the ~1us/step serial row-load latency of the 830-step chain.
#define RPT 52
__global__ __launch_bounds__(512) void k_backxform(const float* __restrict__ Acopy,
                                                   const float* __restrict__ tauA,
                                                   const float* __restrict__ Utri,
                                                   float* __restrict__ Uocc) {
  const int cg = blockIdx.x;         // column quarter (0..3)
  const int n = blockIdx.y;
  const int tid = threadIdx.x;
  const int jc = tid & 31, g = tid >> 5;   // 16 row-groups x 52 rows
  const int col = cg*32 + jc;
  __shared__ float vlds[2][NBB];
  __shared__ float sred[16*32];
  const float* A = Acopy + (size_t)n*NBB*NBB;
  float U[RPT];
  const float* Ut = Utri + ((size_t)n*NOCC2 + col)*NBB + g*RPT;
  #pragma unroll
  for (int rr = 0; rr < RPT; ++rr) U[rr] = Ut[rr];
  const int rbase = g*RPT;
  // preload reflector of k = NBB-3 into buffer 0
  {
    const int k = NBB-3, mm = NBB-1-k;
    for (int idx = tid; idx < mm; idx += 512) vlds[0][idx] = A[(size_t)k*NBB + (k+1+idx)];
  }
  __syncthreads();
  int buf = 0;
  for (int k = NBB-3; k >= 0; --k) {
    // register-stage prefetch of reflector k-1 (row k-1, cols k..NBB-1)
    float pf0 = 0.f, pf1 = 0.f;
    const int m2 = NBB - k;
    if (k > 0) {
      const float* Arow = A + (size_t)(k-1)*NBB + k;
      if (tid < m2) pf0 = Arow[tid];
      if (tid + 512 < m2) pf1 = Arow[tid + 512];
    }
    const float tau = tauA[n*NBB + k];   // block-uniform
    if (tau != 0.f) {
      float part = 0.f;
      #pragma unroll
      for (int rr = 0; rr < RPT; ++rr) {
        const int r = rbase + rr;
        if (r > k) part += U[rr]*vlds[buf][r-k-1];
      }
      sred[g*32 + jc] = part;
      __syncthreads();
      float ssum = 0.f;
      #pragma unroll
      for (int t = 0; t < 16; ++t) ssum += sred[t*32 + jc];
      const float s = tau*ssum;
      #pragma unroll
      for (int rr = 0; rr < RPT; ++rr) {
        const int r = rbase + rr;
        if (r > k) U[rr] -= s*vlds[buf][r-k-1];
      }
    }
    // write prefetched row into the other buffer (no conflict with vlds[buf] reads)
    if (k > 0) {
      if (tid < m2) vlds[buf^1][tid] = pf0;
      if (tid + 512 < m2) vlds[buf^1][tid + 512] = pf1;
    }
    __syncthreads();
    buf ^= 1;
  }
  float* Ub = Uocc + (size_t)n*NBB*NOCC2;
  #pragma unroll
  for (int rr = 0; rr < RPT; ++rr) Ub[(size_t)(rbase+rr)*NOCC2 + col] = U[rr];
}

// ---------------- C = h_new * Uocc  (832x832 @ 832x128 per batch) ----------------
__global__ __launch_bounds__(256) void k_gemmC(const float* __restrict__ h,
                                               const float* __restrict__ Uocc,
                                               float* __restrict__ C) {
  const int rt = blockIdx.x, n = blockIdx.y;
  const int tid = threadIdx.x;
  __shared__ __align__(16) float hT[64*33];
  __shared__ __align__(16) float Ut[32*128];
  const int ty = tid >> 5, tx = tid & 31;
  float acc[8][4] = {};
  const float* hb = h + (size_t)n*NBB*NBB + (size_t)rt*64*NBB;
  const float* Ub = Uocc + (size_t)n*NBB*NOCC2;
  for (int k0 = 0; k0 < NBB; k0 += 32) {
    for (int idx = tid; idx < 64*32; idx += 256) {
      const int r = idx >> 5, c = idx & 31;
      hT[r*33 + c] = hb[(size_t)r*NBB + k0 + c];
    }
    for (int idx = tid; idx < 32*128; idx += 256) {
      const int r = idx >> 7, c = idx & 127;
      Ut[idx] = Ub[(size_t)(k0 + r)*NOCC2 + c];
    }
    __syncthreads();
    for (int kk = 0; kk < 32; ++kk) {
      const float4 b4 = *(const float4*)&Ut[kk*128 + tx*4];
      #pragma unroll
      for (int q = 0; q < 8; ++q) {
        const float a = hT[(ty*8 + q)*33 + kk];
        acc[q][0] += a*b4.x; acc[q][1] += a*b4.y; acc[q][2] += a*b4.z; acc[q][3] += a*b4.w;
      }
    }
    __syncthreads();
  }
  float* Cb = C + (size_t)n*NBB*NOCC2;
  #pragma unroll
  for (int q = 0; q < 8; ++q)
    #pragma unroll
    for (int p = 0; p < 4; ++p)
      Cb[(size_t)(rt*64 + ty*8 + q)*NOCC2 + tx*4 + p] = acc[q][p];
}

// ---------------- E = sum(e_occ) + Tr(Uocc^T h Uocc) + nuc ----------------
__global__ __launch_bounds__(256) void k_final(const float* __restrict__ eig,
                                               const float* __restrict__ Uocc, const float* __restrict__ C,
                                               const float* __restrict__ pos, const int* __restrict__ numbers,
                                               float* __restrict__ E_out) {
  const int n = blockIdx.x, tid = threadIdx.x;
  __shared__ float rb[256];
  float local = 0.f;
  for (int i = tid; i < NOCC2; i += 256) local += eig[n*NBB + i];
  const float* Ub = Uocc + (size_t)n*NBB*NOCC2;
  const float* Cb = C + (size_t)n*NBB*NOCC2;
  for (int idx = tid; idx < NBB*NOCC2; idx += 256) local += Ub[idx]*Cb[idx];
  float ln = 0.f;
  for (int t = tid; t < NPAIR; t += 256) {
    int kk, ll;
    pair_decode(t, kk, ll);
    const float dx = pos[(n*NK + kk)*3 + 0] - pos[(n*NK + ll)*3 + 0];
    const float dy = pos[(n*NK + kk)*3 + 1] - pos[(n*NK + ll)*3 + 1];
    const float dz = pos[(n*NK + kk)*3 + 2] - pos[(n*NK + ll)*3 + 2];
    const float d2 = dx*dx + dy*dy + dz*dz;
    const float Z = (float)(numbers[kk]*numbers[ll]);
    ln += Z / sqrtf(d2);
  }
  local += ln * A0C;
  rb[tid] = local;
  __syncthreads();
  for (int s = 128; s > 0; s >>= 1) {
    if (tid < s) rb[tid] += rb[tid + s];
    __syncthreads();
  }
  if (tid == 0) E_out[n] = rb[0];
}

extern "C" void kernel_launch(void* const* d_in, const int* in_sizes, int n_in,
                              void* d_out, int out_size, void* d_ws, size_t ws_size,
                              hipStream_t stream) {
  (void)in_sizes; (void)n_in; (void)out_size; (void)ws_size;
  const float* mu      = (const float*)d_in[0];
  const float* hnew    = (const float*)d_in[1];
  const float* pos     = (const float*)d_in[2];
  const float* Foff    = (const float*)d_in[3];
  const float* tW      = (const float*)d_in[4];
  const float* tb      = (const float*)d_in[5];
  const float* Won     = (const float*)d_in[6];
  const float* bon     = (const float*)d_in[7];
  const float* Woff    = (const float*)d_in[8];
  const float* boff    = (const float*)d_in[9];
  const int*   numbers = (const int*)d_in[10];

  float* out   = (float*)d_out;
  float* Fout  = out;                               // [16][832][832]
  float* e_out = out + (size_t)NBATCH*NBB*NBB;      // [16][832]
  float* E_out = e_out + (size_t)NBATCH*NBB;        // [16]

  float* ws    = (float*)d_ws;
  float* Acopy = ws + OFF_ACOPY;
  float* xbuf  = ws + OFF_X;
  float* Sbuf  = ws + OFF_S;
  float* dA    = ws + OFF_D;
  float* subA  = ws + OFF_SUB;
  float* tauA  = ws + OFF_TAU;
  float* eig   = ws + OFF_EIG;
  float* Utri  = ws + OFF_UTRI;
  float* Uocc  = ws + OFF_UOCC;
  float* Cbuf  = ws + OFF_C;     // overlays Utri
  float* Wpan  = ws + OFF_WPAN;  // overlays Utri (dead until k_invit)
  float* cbufA = ws + OFF_CBUF;
  float* slotA = ws + OFF_SLOT;
  int*   barA  = (int*)(ws + OFF_BARC);

  // zero the per-matrix barrier counters (graph-captured; runs every replay)
  hipMemsetAsync((void*)barA, 0, NBATCH*sizeof(int), stream);

  k_x<<<dim3(NK, NBATCH), dim3(256), 0, stream>>>(mu, tW, tb, xbuf);
  k_S<<<dim3(NBATCH), dim3(256), 0, stream>>>(xbuf, Sbuf);
  k_diag<<<dim3(NK, NBATCH), dim3(256), 0, stream>>>(xbuf, Sbuf, Won, bon, hnew, Foff, Fout, Acopy);
  k_off<<<dim3(6, 16, NBATCH), dim3(256), 0, stream>>>(xbuf, Woff, boff, hnew, Foff, Fout, Acopy);
  k_tridiag_panel<<<dim3(GW, NBATCH), dim3(TPW), 0, stream>>>(Acopy, dA, subA, tauA, Wpan, cbufA, slotA, barA);
  k_bisect<<<dim3(4, NBATCH), dim3(256), 0, stream>>>(dA, subA, eig, e_out);
  k_invit<<<dim3(NOCC2, NBATCH), dim3(64), 0, stream>>>(dA, subA, eig, Utri);
  k_backxform<<<dim3(4, NBATCH), dim3(512), 0, stream>>>(Acopy, tauA, Utri, Uocc);
  k_gemmC<<<dim3(13, NBATCH), dim3(256), 0, stream>>>(hnew, Uocc, Cbuf);
  k_final<<<dim3(NBATCH), dim3(256), 0, stream>>>(eig, Uocc, Cbuf, pos, numbers, E_out);
}

// Round 13
// 28051.364 us; speedup vs baseline: 2.7868x; 1.2527x over previous
//
#include <hip/hip_runtime.h>
#include <math.h>
#include <stdint.h>

// Problem constants
#define NBATCH 16
#define NK     32
#define NTDS   768      // 3*DS
#define NMM    676      // BM*BM
#define NBM    26
#define NBB    832      // B = K*BM
#define NOCC2  128
#define NPAIR  496      // K*(K-1)/2
#define FSCALE 1.0e-4f
#define A0C    0.5291772f

// ---------------- workspace layout (in floats) ----------------
#define OFF_ACOPY 0ull
#define SZ_ACOPY  (16ull*832*832)
#define OFF_X     (OFF_ACOPY + SZ_ACOPY)
#define SZ_X      (16ull*32*768)
#define OFF_S     (OFF_X + SZ_X)
#define SZ_S      (16ull*768)
#define OFF_D     (OFF_S + SZ_S)
#define OFF_SUB   (OFF_D   + 16ull*832)
#define OFF_TAU   (OFF_SUB + 16ull*832)
#define OFF_EIG   (OFF_TAU + 16ull*832)
#define OFF_UTRI  (OFF_EIG + 16ull*832)
#define SZ_UTRI   (16ull*128*832)
#define OFF_UOCC  (OFF_UTRI + SZ_UTRI)
#define OFF_C     OFF_UTRI   /* C overlays Utri (dead after backxform) */
// tridiag scratch overlays the Utri region (Utri written only later by k_invit)
#define PB   32   // panel width
#define GW   8    // workgroups per matrix (R13: was 16 — barrier-participant probe)
#define GWL2 3
#define TPW  1024 // threads per workgroup
#define NWV  16   // waves per WG
#define QMAX 104  // max own rows per WG (832/8)
#define SLOTSTR 1088
#define OFF_WPAN  OFF_UTRI                        /* 16*832*32 = 425,984 */
#define OFF_CBUF  (OFF_WPAN + 16ull*832*32)       /* 16*832 */
#define OFF_SLOT  (OFF_CBUF + 16ull*832)          /* 16*1088 */
#define OFF_BARC  (OFF_SLOT + 16ull*SLOTSTR)      /* 16 ints */

__device__ __forceinline__ void pair_decode(int t, int& k, int& l) {
  int kk = (int)((1.0f + sqrtf(1.0f + 8.0f*(float)t)) * 0.5f);
  while (kk*(kk-1)/2 > t) --kk;
  while ((kk+1)*kk/2 <= t) ++kk;
  k = kk; l = t - kk*(kk-1)/2;
}

// Cross-WG READ: agent-scope bypass load (sc0 sc1) — reads through to the MALL
// (memory-side, unbypassable), so it observes completed bypass stores and
// wbl2-released cached stores with no acquire-invalidate.
__device__ __forceinline__ float gld(const float* p) {
  unsigned int u = __hip_atomic_load((const unsigned int*)p, __ATOMIC_RELAXED, __HIP_MEMORY_SCOPE_AGENT);
  return __uint_as_float(u);
}
// Cross-WG WRITE: agent-scope bypass store (sc0 sc1) — write-through to MALL.
// vmcnt retirement (drained by __syncthreads before the barrier flag bump)
// means the value is at the MALL before any other WG can observe the flag.
__device__ __forceinline__ void gst(float* p, float v) {
  __hip_atomic_store((unsigned int*)p, __float_as_uint(v), __ATOMIC_RELAXED, __HIP_MEMORY_SCOPE_AGENT);
}

// ---------------- x = mu @ transfer_W + b ----------------
__global__ __launch_bounds__(256) void k_x(const float* __restrict__ mu,
                                           const float* __restrict__ tW,
                                           const float* __restrict__ tb,
                                           float* __restrict__ x) {
  const int k = blockIdx.x, n = blockIdx.y, tid = threadIdx.x;
  __shared__ float mus[384];
  const float* mub = mu + (size_t)(n*NK + k)*384;
  for (int i = tid; i < 384; i += 256) mus[i] = mub[i];
  __syncthreads();
  float* xb = x + (size_t)(n*NK + k)*NTDS;
  for (int oo = tid; oo < NTDS; oo += 256) {
    const int d = oo >> 8, i = oo & 255;
    float acc = tb[i];
    const float* mrow = &mus[d*128];
    for (int a = 0; a < 128; ++a) acc += mrow[a]*tW[a*256 + i];
    xb[oo] = acc;
  }
}

// ---------------- S[n][dd] = sum_k x[n][k][dd] ----------------
__global__ __launch_bounds__(256) void k_S(const float* __restrict__ x, float* __restrict__ S) {
  const int n = blockIdx.x, tid = threadIdx.x;
  for (int dd = tid; dd < NTDS; dd += 256) {
    float s = 0.f;
    for (int k = 0; k < NK; ++k) s += x[(size_t)(n*NK + k)*NTDS + dd];
    S[n*NTDS + dd] = s;
  }
}

// ---------------- diagonal blocks ----------------
__global__ __launch_bounds__(256) void k_diag(const float* __restrict__ x, const float* __restrict__ S,
                                              const float* __restrict__ Won, const float* __restrict__ bon,
                                              const float* __restrict__ hnew, const float* __restrict__ Foff,
                                              float* __restrict__ Fout, float* __restrict__ Acopy) {
  const int k = blockIdx.x, n = blockIdx.y, tid = threadIdx.x;
  __shared__ float q[NTDS];
  __shared__ float M[NMM];
  const float* xb = x + (size_t)(n*NK + k)*NTDS;
  const float* Sb = S + n*NTDS;
  for (int i = tid; i < NTDS; i += 256) q[i] = xb[i]*Sb[i];
  __syncthreads();
  for (int m = tid; m < NMM; m += 256) {
    float acc = 32.0f * bon[m];
    for (int dd = 0; dd < NTDS; ++dd) acc += q[dd]*Won[(size_t)dd*NMM + m];
    M[m] = acc;
  }
  __syncthreads();
  const float* hb = hnew + (size_t)n*NBB*NBB;
  float* Fb = Fout + (size_t)n*NBB*NBB;
  float* Ab = Acopy + (size_t)n*NBB*NBB;
  for (int m = tid; m < NMM; m += 256) {
    const int a = m/26, b = m - a*26;
    const float val = 0.5f*(M[m] + M[b*26 + a]);
    const int P = k*26 + a, Q = k*26 + b;
    const size_t idx = (size_t)P*NBB + Q;
    const float fo = Foff[idx];
    const float hv = hb[idx];
    const float Fv = (fabsf(hv) > 1e-7f) ? (val*FSCALE + fo) : fo;
    Fb[idx] = Fv; Ab[idx] = Fv;
  }
}

// ---------------- off-diagonal blocks: GEMM over pairs ----------------
__global__ __launch_bounds__(256) void k_off(const float* __restrict__ x,
                                             const float* __restrict__ Woff, const float* __restrict__ boff,
                                             const float* __restrict__ hnew, const float* __restrict__ Foff,
                                             float* __restrict__ Fout, float* __restrict__ Acopy) {
  const int ct = blockIdx.x, pt = blockIdx.y, n = blockIdx.z;
  const int tid = threadIdx.x;
  __shared__ __align__(16) float At[32*65];
  __shared__ __align__(16) float Bt[64*128];
  __shared__ int klk[32], kll[32];
  if (tid < 32) {
    int pr = pt*32 + tid, kk = 1, ll = 0;
    if (pr < NPAIR) pair_decode(pr, kk, ll);
    klk[tid] = kk; kll[tid] = ll;
  }
  __syncthreads();
  const int ty = tid >> 5, tx = tid & 31;
  const int r0 = ty*4, c0 = tx*4;
  float acc[4][4] = {};
  for (int dd0 = 0; dd0 < NTDS; dd0 += 64) {
    for (int idx = tid; idx < 2048; idx += 256) {
      const int r = idx >> 6, c = idx & 63;
      const int pr = pt*32 + r;
      float v = 0.f;
      if (pr < NPAIR) {
        const int kk = klk[r], ll = kll[r];
        v = x[(size_t)(n*NK + kk)*NTDS + dd0 + c] * x[(size_t)(n*NK + ll)*NTDS + dd0 + c];
      }
      At[r*65 + c] = v;
    }
    for (int idx = tid; idx < 8192; idx += 256) {
      const int r = idx >> 7, c = idx & 127;
      const int col = ct*128 + c;
      Bt[idx] = (col < NMM) ? Woff[(size_t)(dd0 + r)*NMM + col] : 0.f;
    }
    __syncthreads();
    for (int kk = 0; kk < 64; ++kk) {
      float av[4];
      av[0] = At[(r0+0)*65 + kk];
      av[1] = At[(r0+1)*65 + kk];
      av[2] = At[(r0+2)*65 + kk];
      av[3] = At[(r0+3)*65 + kk];
      const float4 b4 = *(const float4*)&Bt[kk*128 + c0];
      const float bb[4] = {b4.x, b4.y, b4.z, b4.w};
      #pragma unroll
      for (int qq = 0; qq < 4; ++qq)
        #pragma unroll
        for (int pp = 0; pp < 4; ++pp)
          acc[qq][pp] += av[qq]*bb[pp];
    }
    __syncthreads();
  }
  const float* hb = hnew + (size_t)n*NBB*NBB;
  float* Fb = Fout + (size_t)n*NBB*NBB;
  float* Ab = Acopy + (size_t)n*NBB*NBB;
  for (int qq = 0; qq < 4; ++qq) {
    const int pr = pt*32 + r0 + qq;
    if (pr >= NPAIR) continue;
    const int kk = klk[r0+qq], ll = kll[r0+qq];
    for (int pp = 0; pp < 4; ++pp) {
      const int m = ct*128 + c0 + pp;
      if (m >= NMM) continue;
      const float val = acc[qq][pp] + boff[m];
      const int a = m/26, b = m - a*26;
      const int P = kk*26 + a, Q = ll*26 + b;
      const size_t i1 = (size_t)P*NBB + Q;
      const float fo1 = Foff[i1], hv1 = hb[i1];
      const float Fv1 = (fabsf(hv1) > 1e-7f) ? (val*FSCALE + fo1) : fo1;
      Fb[i1] = Fv1; Ab[i1] = Fv1;
      const size_t i2 = (size_t)Q*NBB + P;
      const float fo2 = Foff[i2], hv2 = hb[i2];
      const float Fv2 = (fabsf(hv2) > 1e-7f) ? (val*FSCALE + fo2) : fo2;
      Fb[i2] = Fv2; Ab[i2] = Fv2;
    }
  }
}

// ================= blocked (latrd) multi-WG tridiagonalization =================
// R13: GW 16->8 (barrier-participant probe). Half the arrivals per barrier,
// half the WGs polling MALL counters (128 vs 256); per-WG matvec work doubles
// (R10 showed work's epoch share is only ~1-2us). Row ownership: j = 8q+g.
// Coherence protocol unchanged (proven R7): gst/gld bypass for ALL cross-WG
// data; relaxed rbar per column; release gbar per panel boundary.
__device__ __forceinline__ void rbar(int* cnt, int target) {
  __syncthreads();   // emits s_waitcnt vmcnt(0) before s_barrier: bypass stores MALL-complete
  if (threadIdx.x == 0) {
    asm volatile("" ::: "memory");
    __hip_atomic_fetch_add(cnt, 1, __ATOMIC_RELAXED, __HIP_MEMORY_SCOPE_AGENT);
    while (__hip_atomic_load(cnt, __ATOMIC_RELAXED, __HIP_MEMORY_SCOPE_AGENT) < target)
      __builtin_amdgcn_s_sleep(1);
    asm volatile("" ::: "memory");
  }
  __syncthreads();
}
__device__ __forceinline__ void gbar(int* cnt, int target) {
  __syncthreads();
  if (threadIdx.x == 0) {
    __hip_atomic_fetch_add(cnt, 1, __ATOMIC_RELEASE, __HIP_MEMORY_SCOPE_AGENT);  // wbl2
    while (__hip_atomic_load(cnt, __ATOMIC_RELAXED, __HIP_MEMORY_SCOPE_AGENT) < target)
      __builtin_amdgcn_s_sleep(1);
  }
  __syncthreads();
}

__device__ __forceinline__ float wg_reduce16(float v, volatile float* sred) {
  #pragma unroll
  for (int off = 32; off > 0; off >>= 1) v += __shfl_down(v, off);
  const int tid = threadIdx.x;
  if ((tid & 63) == 0) sred[tid >> 6] = v;
  __syncthreads();
  float r = 0.f;
  #pragma unroll
  for (int t = 0; t < NWV; ++t) r += sred[t];
  __syncthreads();
  return r;
}

__global__ __launch_bounds__(TPW) void k_tridiag_panel(float* __restrict__ Acopy,
                                                       float* __restrict__ dA,
                                                       float* __restrict__ subA,
                                                       float* __restrict__ tauA,
                                                       float* __restrict__ Wpan,
                                                       float* __restrict__ cbufA,
                                                       float* __restrict__ slotA,
                                                       int* __restrict__ barA) {
  const int g = blockIdx.x;          // WG within matrix (0..GW-1)
  const int n = blockIdx.y;          // matrix
  const int tid = threadIdx.x;
  const int lane = tid & 63, wv = tid >> 6;
  float* A    = Acopy + (size_t)n*NBB*NBB;
  float* Wbuf = Wpan  + (size_t)n*NBB*PB;
  float* cbuf = cbufA + (size_t)n*NBB;
  float* slot = slotA + (size_t)n*SLOTSTR;
  float* normp = slot;          // [GW]
  float* vavp  = slot + 16;     // [GW]
  float* alphaS= slot + 32;     // [1]
  float* ynextS= slot + 33;     // [1]
  float* d1pA  = slot + 64;     // [GW][32]
  float* d2pA  = slot + 576;    // [GW][32]
  int*   cnt   = barA + n;

  __shared__ float vsh[NBB];
  __shared__ __align__(16) float vsh4[NBB+8];   // v shifted so matvec reads are 16B-aligned
  __shared__ float yloc[QMAX];
  __shared__ float Vloc[QMAX*33];
  __shared__ float Wloc[QMAX*33];
  __shared__ float Vt[64*33];
  __shared__ float Wt[64*33];
  __shared__ float d1s[PB], d2s[PB], Vk1s[PB], Wk1s[PB];
  __shared__ float sred[NWV];
  __shared__ float s_tau, s_scale, s_vav, s_ynext;
  int ep = 0;

  // ---- prologue: c = A[:,0], norm partials, alpha (all comms via gst) ----
  {
    const int q0p = (GW - g) >> GWL2;   // first q with GW*q+g >= 1
    float np = 0.f;
    const int q = q0p + tid;
    if (q < QMAX) {
      const int j = GW*q + g;
      const float cv = A[(size_t)j*NBB];   // own row (prior kernel, dispatch-coherent)
      gst(&cbuf[j], cv);
      if (j >= 2) np = cv*cv;
      if (j == 1) gst(alphaS, cv);
    }
    const float s = wg_reduce16(np, sred);
    if (tid == 0) gst(&normp[g], s);
  }
  ++ep; gbar(cnt, ep*GW);

  for (int k0 = 0; k0 < NBB-2; k0 += PB) {
    const int ilim = (NBB-2-k0 < PB) ? (NBB-2-k0) : PB;
    for (int i = 0; i < ilim; ++i) {
      const int k = k0 + i;
      const int m = NBB-1-k;
      const int q0 = (k + GW - g) >> GWL2;   // first q with GW*q+g >= k+1
      const int cs = k+1;
      const int nh = (4 - (cs & 3)) & 3;  // head elems to 16B alignment
      const int ca = cs + nh;

      // ================= Epoch X =================
      if (tid == 0) {
        float xn2 = 0.f;
        #pragma unroll
        for (int t = 0; t < GW; ++t) xn2 += gld(&normp[t]);
        const float alpha = gld(alphaS);
        float tau, scale, beta;
        if (xn2 < 1e-26f) {
          beta = alpha; tau = 0.f; scale = 0.f;
        } else {
          beta  = -copysignf(sqrtf(alpha*alpha + xn2), alpha);
          tau   = (beta - alpha) / beta;
          scale = 1.0f / (alpha - beta);
        }
        s_tau = tau; s_scale = scale;
        if (g == 0) { subA[n*NBB + k + 1] = beta; tauA[n*NBB + k] = tau; }
      }
      __syncthreads();
      const float tau = s_tau, scale = s_scale;
      // build v in LDS (both copies; cbuf is cross-WG -> bypass loads)
      for (int idx = tid; idx < m; idx += TPW) {
        const float val = (idx == 0) ? 1.0f : gld(&cbuf[k+1+idx])*scale;
        vsh[idx] = val;
        vsh4[4 + idx - nh] = val;
      }
      __syncthreads();
      // store v (own entries) into row k (transposed reflector, BYPASS) + Vloc
      {
        const int q = q0 + tid;
        if (q < QMAX) {
          const int j = GW*q + g;
          const float val = vsh[j-(k+1)];
          gst(&A[(size_t)k*NBB + j], val);
          Vloc[q*33 + i] = val;
        }
      }
      // d1/d2 partials over own rows (p < i); QMAX>64 -> chunked lane loop
      for (int p = wv; p < i; p += NWV) {
        float a1 = 0.f, a2 = 0.f;
        for (int q = q0 + lane; q < QMAX; q += 64) {
          const int j = GW*q + g;
          const float vj = vsh[j-(k+1)];
          a1 += Vloc[q*33 + p]*vj;
          a2 += Wloc[q*33 + p]*vj;
        }
        #pragma unroll
        for (int off = 32; off > 0; off >>= 1) { a1 += __shfl_down(a1, off); a2 += __shfl_down(a2, off); }
        if (lane == 0) { gst(&d1pA[g*PB + p], a1); gst(&d2pA[g*PB + p], a2); }
      }
      // matvec y = A0 v over own rows (float4 A reads + float4 aligned v reads)
      {
        float vavl = 0.f;
        for (int q = q0 + wv; q < QMAX; q += NWV) {
          const int j = GW*q + g;
          const float* Ar = A + (size_t)j*NBB;
          float acc = 0.f;
          if (lane < nh) acc += Ar[cs+lane]*vsh[lane];
          for (int c = ca + 4*lane; c < NBB; c += 256) {
            const float4 a4 = *(const float4*)&Ar[c];
            const float4 v4 = *(const float4*)&vsh4[4 + c - ca];
            acc += a4.x*v4.x + a4.y*v4.y + a4.z*v4.z + a4.w*v4.w;
          }
          #pragma unroll
          for (int off = 32; off > 0; off >>= 1) acc += __shfl_down(acc, off);
          if (lane == 0) {
            yloc[q] = acc;
            vavl += vsh[j-(k+1)]*acc;
            if (j == k+1) gst(ynextS, acc);
          }
        }
        const float vv = wg_reduce16(vavl, sred);
        if (tid == 0) gst(&vavp[g], vv);
      }
      // prefetch Y-phase inputs that are >=1 barrier old (hide MALL latency)
      if (tid < i) {
        Vk1s[tid] = gld(&A[(size_t)(k0+tid)*NBB + (k+1)]);
        Wk1s[tid] = gld(&Wbuf[(size_t)(k+1)*PB + tid]);
      }
      ++ep; rbar(cnt, ep*GW);

      // ================= Epoch Y =================
      if (tid < i) {
        float s1 = 0.f, s2 = 0.f;
        #pragma unroll
        for (int g2 = 0; g2 < GW; ++g2) { s1 += gld(&d1pA[g2*PB + tid]); s2 += gld(&d2pA[g2*PB + tid]); }
        d1s[tid] = s1; d2s[tid] = s2;
      }
      if (tid == TPW-1) {
        float sv = 0.f;
        #pragma unroll
        for (int t = 0; t < GW; ++t) sv += gld(&vavp[t]);
        s_vav = sv; s_ynext = gld(ynextS);
      }
      __syncthreads();
      // redundant scalars
      float s12 = 0.f, wk1acc = 0.f;
      for (int p = 0; p < i; ++p) { s12 += d1s[p]*d2s[p]; wk1acc += Vk1s[p]*d2s[p] + Wk1s[p]*d1s[p]; }
      const float corr = 0.5f*tau*tau*(s_vav - 2.f*s12);
      const float wk1 = tau*(s_ynext - wk1acc) - corr;
      // own-row w, then c' for column k+1
      {
        const int q = q0 + tid;
        float np = 0.f;
        if (q < QMAX) {
          const int j = GW*q + g;
          float wacc = 0.f;
          for (int p = 0; p < i; ++p) wacc += Vloc[q*33 + p]*d2s[p] + Wloc[q*33 + p]*d1s[p];
          const float vj = vsh[j-(k+1)];
          const float wj = tau*(yloc[q] - wacc) - corr*vj;
          Wloc[q*33 + i] = wj;
          gst(&Wbuf[(size_t)j*PB + i], wj);
          if (j >= k+2) {
            float cacc = 0.f;
            for (int p = 0; p < i; ++p) cacc += Vloc[q*33 + p]*Wk1s[p] + Wloc[q*33 + p]*Vk1s[p];
            cacc += vj*wk1 + wj;   // p = i term (V[k+1,i] = 1)
            const float cp = A[(size_t)j*NBB + (k+1)] - cacc;   // own row, clean cached
            gst(&cbuf[j], cp);
            if (j >= k+3) np = cp*cp;
            if (j == k+2) gst(alphaS, cp);
          }
        }
        const float ns = wg_reduce16(np, sred);
        if (tid == 0) gst(&normp[g], ns);
      }
      // diagonal extraction d[k] (own row plain; cross-WG data via bypass)
      if (g == (k & (GW-1)) && tid == 0) {
        float dk = A[(size_t)k*NBB + k];
        for (int p = 0; p < i; ++p)
          dk -= 2.f * gld(&A[(size_t)(k0+p)*NBB + k]) * gld(&Wbuf[(size_t)k*PB + p]);
        dA[n*NBB + k] = dk;
      }
      ++ep; rbar(cnt, ep*GW);
    }

    // ================= syr2k: A22 -= V W^T + W V^T =================
    if (k0 + PB < NBB-2) {
      const int kp = k0 + PB;
      const int q0s = (kp + GW-1 - g) >> GWL2;   // first q with GW*q+g >= kp
      for (int c0 = kp+1; c0 < NBB; c0 += 64) {
        const int nc = (NBB - c0 < 64) ? (NBB - c0) : 64;
        for (int idx = tid; idx < 2048; idx += TPW) {
          const int p = idx >> 6, cc = idx & 63;
          Vt[cc*33 + p] = (cc < nc) ? gld(&A[(size_t)(k0+p)*NBB + c0 + cc]) : 0.f;
        }
        for (int idx = tid; idx < 2048; idx += TPW) {
          const int p = idx & 31, cc = idx >> 5;
          Wt[cc*33 + p] = (cc < nc) ? gld(&Wbuf[(size_t)(c0+cc)*PB + p]) : 0.f;
        }
        __syncthreads();
        for (int q = q0s + wv; q < QMAX; q += NWV) {
          const int j = GW*q + g;
          if (lane < nc) {
            const int c = c0 + lane;
            float acc = 0.f;
            #pragma unroll
            for (int p = 0; p < PB; ++p)
              acc += Vloc[q*33 + p]*Wt[lane*33 + p] + Wloc[q*33 + p]*Vt[lane*33 + p];
            A[(size_t)j*NBB + c] -= acc;   // own row, cached (cleaned below)
          }
        }
        __syncthreads();
      }
      // diagonal entry [kp][kp]
      if (g == (kp & (GW-1)) && tid == 0) {
        const int qd = kp >> GWL2;
        float acc = 0.f;
        #pragma unroll
        for (int p = 0; p < PB; ++p) acc += Vloc[qd*33 + p]*Wloc[qd*33 + p];
        A[(size_t)kp*NBB + kp] -= 2.f*acc;
      }
      ++ep; gbar(cnt, ep*GW);   // RELEASE: clean syr2k dirt before next panel's gst reflectors
    }
  }

  // ---- epilogue (cross-WG data via bypass loads) ----
  if (g == 0 && tid == 0) {
    const int k0l = ((NBB-3)/PB)*PB;       // 800
    const int np_ = NBB-2-k0l;             // 30
    float dm2 = gld(&A[(size_t)(NBB-2)*NBB + (NBB-2)]);
    float dm1 = gld(&A[(size_t)(NBB-1)*NBB + (NBB-1)]);
    for (int p = 0; p < np_; ++p) {
      dm2 -= 2.f * gld(&A[(size_t)(k0l+p)*NBB + (NBB-2)]) * gld(&Wbuf[(size_t)(NBB-2)*PB + p]);
      dm1 -= 2.f * gld(&A[(size_t)(k0l+p)*NBB + (NBB-1)]) * gld(&Wbuf[(size_t)(NBB-1)*PB + p]);
    }
    dA[n*NBB + NBB-2] = dm2;
    dA[n*NBB + NBB-1] = dm1;
    subA[n*NBB + NBB-1] = gld(alphaS);
    subA[n*NBB + 0] = 0.f;
    tauA[n*NBB + NBB-2] = 0.f;
    tauA[n*NBB + NBB-1] = 0.f;
  }
}

// ---------------- all eigenvalues via bisection (Sturm counts) ----------------
__global__ __launch_bounds__(256) void k_bisect(const float* __restrict__ dA, const float* __restrict__ subA,
                                                float* __restrict__ eig, float* __restrict__ e_out) {
  const int n = blockIdx.y;
  const int i = blockIdx.x*256 + threadIdx.x;
  __shared__ float ds[NBB], ss[NBB];
  const float* dg = dA + n*NBB;
  const float* sg = subA + n*NBB;
  for (int j = threadIdx.x; j < NBB; j += 256) { ds[j] = dg[j]; ss[j] = sg[j]; }
  __syncthreads();
  if (i >= NBB) return;
  float lo = 1e30f, hi = -1e30f;
  for (int j = 0; j < NBB; ++j) {
    const float r = fabsf(ss[j]) + ((j+1 < NBB) ? fabsf(ss[j+1]) : 0.f);
    lo = fminf(lo, ds[j]-r); hi = fmaxf(hi, ds[j]+r);
  }
  const float pad = 1e-3f*(hi-lo) + 1e-3f;
  lo -= pad; hi += pad;
  for (int it = 0; it < 38; ++it) {
    const float mid = 0.5f*(lo+hi);
    int cnt = 0;
    float qv = ds[0]-mid;
    if (qv < 0.f) cnt++;
    for (int j = 1; j < NBB; ++j) {
      const float e = ss[j];
      if (fabsf(qv) < 1e-20f) qv = -1e-20f;
      qv = ds[j]-mid - e*e/qv;
      if (qv < 0.f) cnt++;
    }
    if (cnt > i) hi = mid; else lo = mid;
  }
  const float lam = 0.5f*(lo+hi);
  eig[n*NBB + i] = lam;
  e_out[n*NBB + i] = lam;
}

// ---------------- inverse iteration on T for the 128 lowest ----------------
__global__ __launch_bounds__(64) void k_invit(const float* __restrict__ dA, const float* __restrict__ subA,
                                              const float* __restrict__ eig, float* __restrict__ Utri) {
  const int i = blockIdx.x, n = blockIdx.y;
  const int lane = threadIdx.x;
  __shared__ float ds[NBB], ss[NBB], ud[NBB], u1[NBB], u2[NBB], yv[NBB], xv[NBB];
  const float* dg = dA + n*NBB;
  const float* sg = subA + n*NBB;
  for (int j = lane; j < NBB; j += 64) { ds[j] = dg[j]; ss[j] = sg[j]; }
  const float lam = eig[n*NBB + i];
  for (int j = lane; j < NBB; j += 64) {
    uint32_t s = (uint32_t)(j*2654435761u) ^ (uint32_t)(i*40503u + 977u) ^ (uint32_t)(n*9973u);
    s ^= s >> 16; s *= 0x7feb352dU; s ^= s >> 15; s *= 0x846ca68bU; s ^= s >> 16;
    yv[j] = 0.5f + (float)(s & 0xFFFF) * (1.0f/65536.0f);
  }
  __syncthreads();
  const float PIV = 3e-6f;
  for (int pass = 0; pass < 2; ++pass) {
    if (lane == 0) {
      float cd = ds[0] - lam;
      float cu = ss[1];
      float cy = yv[0];
      for (int j = 0; j < NBB-1; ++j) {
        const float bl = ss[j+1];
        const float bd = ds[j+1] - lam;
        const float bu = (j+2 < NBB) ? ss[j+2] : 0.f;
        const float yb = yv[j+1];
        float tud, tu1, tu2, tm, ncd, ncu, ny;
        if (fabsf(bl) > fabsf(cd)) {
          tud = bl; tu1 = bd; tu2 = bu;
          if (fabsf(tud) < PIV) tud = (tud < 0.f) ? -PIV : PIV;
          tm  = cd / tud;
          ncd = cu - tm*bd;
          ncu = -tm*bu;
          ny  = cy - tm*yb;
          yv[j] = yb;
        } else {
          tud = cd; tu1 = cu; tu2 = 0.f;
          if (fabsf(tud) < PIV) tud = (tud < 0.f) ? -PIV : PIV;
          tm  = bl / tud;
          ncd = bd - tm*cu;
          ncu = bu;
          ny  = yb - tm*cy;
          yv[j] = cy;
        }
        ud[j] = tud; u1[j] = tu1; u2[j] = tu2;
        cd = ncd; cu = ncu; cy = ny;
      }
      if (fabsf(cd) < PIV) cd = (cd < 0.f) ? -PIV : PIV;
      ud[NBB-1] = cd; u1[NBB-1] = 0.f; u2[NBB-1] = 0.f; yv[NBB-1] = cy;
      float x2 = yv[NBB-1]/ud[NBB-1];
      xv[NBB-1] = x2;
      float x1 = (yv[NBB-2] - u1[NBB-2]*x2)/ud[NBB-2];
      xv[NBB-2] = x1;
      for (int j = NBB-3; j >= 0; --j) {
        const float xj = (yv[j] - u1[j]*x1 - u2[j]*x2)/ud[j];
        xv[j] = xj;
        x2 = x1; x1 = xj;
      }
    }
    __syncthreads();
    float p2 = 0.f;
    for (int j = lane; j < NBB; j += 64) { const float t = xv[j]; p2 += t*t; }
    #pragma unroll
    for (int off = 32; off > 0; off >>= 1) p2 += __shfl_xor(p2, off);
    const float rin = rsqrtf(p2);
    if (pass == 0) {
      for (int j = lane; j < NBB; j += 64) yv[j] = xv[j]*rin;
      __syncthreads();
    } else {
      float* Ub = Utri + ((size_t)n*NOCC2 + i)*NBB;
      for (int j = lane; j < NBB; j += 64) Ub[j] = xv[j]*rin;
    }
  }
}

// ---------------- back-transform: Uocc = H0...H829 * Utri ----------------
#define RPT 52
__global__ __launch_bounds__(512) void k_backxform(const float* __restrict__ Acopy,
                                                   const float* __restrict__ tauA,
                                                   const float* __restrict__ Utri,
                                                   float* __restrict__ Uocc) {
  const int cg = blockIdx.x;         // column quarter (0..3)
  const int n = blockIdx.y;
  const int tid = threadIdx.x;
  const int jc = tid & 31, g = tid >> 5;   // 16 row-groups x 52 rows
  const int col = cg*32 + jc;
  __shared__ float vlds[2][NBB];
  __shared__ float sred[16*32];
  const float* A = Acopy + (size_t)n*NBB*NBB;
  float U[RPT];
  const float* Ut = Utri + ((size_t)n*NOCC2 + col)*NBB + g*RPT;
  #pragma unroll
  for (int rr = 0; rr < RPT; ++rr) U[rr] = Ut[rr];
  const int rbase = g*RPT;
  {
    const int k = NBB-3, mm = NBB-1-k;
    for (int idx = tid; idx < mm; idx += 512) vlds[0][idx] = A[(size_t)k*NBB + (k+1+idx)];
  }
  __syncthreads();
  int buf = 0;
  for (int k = NBB-3; k >= 0; --k) {
    float pf0 = 0.f, pf1 = 0.f;
    const int m2 = NBB - k;
    if (k > 0) {
      const float* Arow = A + (size_t)(k-1)*NBB + k;
      if (tid < m2) pf0 = Arow[tid];
      if (tid + 512 < m2) pf1 = Arow[tid + 512];
    }
    const float tau = tauA[n*NBB + k];
    if (tau != 0.f) {
      float part = 0.f;
      #pragma unroll
      for (int rr = 0; rr < RPT; ++rr) {
        const int r = rbase + rr;
        if (r > k) part += U[rr]*vlds[buf][r-k-1];
      }
      sred[g*32 + jc] = part;
      __syncthreads();
      float ssum = 0.f;
      #pragma unroll
      for (int t = 0; t < 16; ++t) ssum += sred[t*32 + jc];
      const float s = tau*ssum;
      #pragma unroll
      for (int rr = 0; rr < RPT; ++rr) {
        const int r = rbase + rr;
        if (r > k) U[rr] -= s*vlds[buf][r-k-1];
      }
    }
    if (k > 0) {
      if (tid < m2) vlds[buf^1][tid] = pf0;
      if (tid + 512 < m2) vlds[buf^1][tid + 512] = pf1;
    }
    __syncthreads();
    buf ^= 1;
  }
  float* Ub = Uocc + (size_t)n*NBB*NOCC2;
  #pragma unroll
  for (int rr = 0; rr < RPT; ++rr) Ub[(size_t)(rbase+rr)*NOCC2 + col] = U[rr];
}

// ---------------- C = h_new * Uocc  (832x832 @ 832x128 per batch) ----------------
__global__ __launch_bounds__(256) void k_gemmC(const float* __restrict__ h,
                                               const float* __restrict__ Uocc,
                                               float* __restrict__ C) {
  const int rt = blockIdx.x, n = blockIdx.y;
  const int tid = threadIdx.x;
  __shared__ __align__(16) float hT[64*33];
  __shared__ __align__(16) float Ut[32*128];
  const int ty = tid >> 5, tx = tid & 31;
  float acc[8][4] = {};
  const float* hb = h + (size_t)n*NBB*NBB + (size_t)rt*64*NBB;
  const float* Ub = Uocc + (size_t)n*NBB*NOCC2;
  for (int k0 = 0; k0 < NBB; k0 += 32) {
    for (int idx = tid; idx < 64*32; idx += 256) {
      const int r = idx >> 5, c = idx & 31;
      hT[r*33 + c] = hb[(size_t)r*NBB + k0 + c];
    }
    for (int idx = tid; idx < 32*128; idx += 256) {
      const int r = idx >> 7, c = idx & 127;
      Ut[idx] = Ub[(size_t)(k0 + r)*NOCC2 + c];
    }
    __syncthreads();
    for (int kk = 0; kk < 32; ++kk) {
      const float4 b4 = *(const float4*)&Ut[kk*128 + tx*4];
      #pragma unroll
      for (int q = 0; q < 8; ++q) {
        const float a = hT[(ty*8 + q)*33 + kk];
        acc[q][0] += a*b4.x; acc[q][1] += a*b4.y; acc[q][2] += a*b4.z; acc[q][3] += a*b4.w;
      }
    }
    __syncthreads();
  }
  float* Cb = C + (size_t)n*NBB*NOCC2;
  #pragma unroll
  for (int q = 0; q < 8; ++q)
    #pragma unroll
    for (int p = 0; p < 4; ++p)
      Cb[(size_t)(rt*64 + ty*8 + q)*NOCC2 + tx*4 + p] = acc[q][p];
}

// ---------------- E = sum(e_occ) + Tr(Uocc^T h Uocc) + nuc ----------------
__global__ __launch_bounds__(256) void k_final(const float* __restrict__ eig,
                                               const float* __restrict__ Uocc, const float* __restrict__ C,
                                               const float* __restrict__ pos, const int* __restrict__ numbers,
                                               float* __restrict__ E_out) {
  const int n = blockIdx.x, tid = threadIdx.x;
  __shared__ float rb[256];
  float local = 0.f;
  for (int i = tid; i < NOCC2; i += 256) local += eig[n*NBB + i];
  const float* Ub = Uocc + (size_t)n*NBB*NOCC2;
  const float* Cb = C + (size_t)n*NBB*NOCC2;
  for (int idx = tid; idx < NBB*NOCC2; idx += 256) local += Ub[idx]*Cb[idx];
  float ln = 0.f;
  for (int t = tid; t < NPAIR; t += 256) {
    int kk, ll;
    pair_decode(t, kk, ll);
    const float dx = pos[(n*NK + kk)*3 + 0] - pos[(n*NK + ll)*3 + 0];
    const float dy = pos[(n*NK + kk)*3 + 1] - pos[(n*NK + ll)*3 + 1];
    const float dz = pos[(n*NK + kk)*3 + 2] - pos[(n*NK + ll)*3 + 2];
    const float d2 = dx*dx + dy*dy + dz*dz;
    const float Z = (float)(numbers[kk]*numbers[ll]);
    ln += Z / sqrtf(d2);
  }
  local += ln * A0C;
  rb[tid] = local;
  __syncthreads();
  for (int s = 128; s > 0; s >>= 1) {
    if (tid < s) rb[tid] += rb[tid + s];
    __syncthreads();
  }
  if (tid == 0) E_out[n] = rb[0];
}

extern "C" void kernel_launch(void* const* d_in, const int* in_sizes, int n_in,
                              void* d_out, int out_size, void* d_ws, size_t ws_size,
                              hipStream_t stream) {
  (void)in_sizes; (void)n_in; (void)out_size; (void)ws_size;
  const float* mu      = (const float*)d_in[0];
  const float* hnew    = (const float*)d_in[1];
  const float* pos     = (const float*)d_in[2];
  const float* Foff    = (const float*)d_in[3];
  const float* tW      = (const float*)d_in[4];
  const float* tb      = (const float*)d_in[5];
  const float* Won     = (const float*)d_in[6];
  const float* bon     = (const float*)d_in[7];
  const float* Woff    = (const float*)d_in[8];
  const float* boff    = (const float*)d_in[9];
  const int*   numbers = (const int*)d_in[10];

  float* out   = (float*)d_out;
  float* Fout  = out;                               // [16][832][832]
  float* e_out = out + (size_t)NBATCH*NBB*NBB;      // [16][832]
  float* E_out = e_out + (size_t)NBATCH*NBB;        // [16]

  float* ws    = (float*)d_ws;
  float* Acopy = ws + OFF_ACOPY;
  float* xbuf  = ws + OFF_X;
  float* Sbuf  = ws + OFF_S;
  float* dA    = ws + OFF_D;
  float* subA  = ws + OFF_SUB;
  float* tauA  = ws + OFF_TAU;
  float* eig   = ws + OFF_EIG;
  float* Utri  = ws + OFF_UTRI;
  float* Uocc  = ws + OFF_UOCC;
  float* Cbuf  = ws + OFF_C;     // overlays Utri
  float* Wpan  = ws + OFF_WPAN;  // overlays Utri (dead until k_invit)
  float* cbufA = ws + OFF_CBUF;
  float* slotA = ws + OFF_SLOT;
  int*   barA  = (int*)(ws + OFF_BARC);

  // zero the per-matrix barrier counters (graph-captured; runs every replay)
  hipMemsetAsync((void*)barA, 0, NBATCH*sizeof(int), stream);

  k_x<<<dim3(NK, NBATCH), dim3(256), 0, stream>>>(mu, tW, tb, xbuf);
  k_S<<<dim3(NBATCH), dim3(256), 0, stream>>>(xbuf, Sbuf);
  k_diag<<<dim3(NK, NBATCH), dim3(256), 0, stream>>>(xbuf, Sbuf, Won, bon, hnew, Foff, Fout, Acopy);
  k_off<<<dim3(6, 16, NBATCH), dim3(256), 0, stream>>>(xbuf, Woff, boff, hnew, Foff, Fout, Acopy);
  k_tridiag_panel<<<dim3(GW, NBATCH), dim3(TPW), 0, stream>>>(Acopy, dA, subA, tauA, Wpan, cbufA, slotA, barA);
  k_bisect<<<dim3(4, NBATCH), dim3(256), 0, stream>>>(dA, subA, eig, e_out);
  k_invit<<<dim3(NOCC2, NBATCH), dim3(64), 0, stream>>>(dA, subA, eig, Utri);
  k_backxform<<<dim3(4, NBATCH), dim3(512), 0, stream>>>(Acopy, tauA, Utri, Uocc);
  k_gemmC<<<dim3(13, NBATCH), dim3(256), 0, stream>>>(hnew, Uocc, Cbuf);
  k_final<<<dim3(NBATCH), dim3(256), 0, stream>>>(eig, Uocc, Cbuf, pos, numbers, E_out);
}

// Round 14
// 27363.696 us; speedup vs baseline: 2.8568x; 1.0251x over previous
//
#include <hip/hip_runtime.h>
#include <math.h>
#include <stdint.h>

// Problem constants
#define NBATCH 16
#define NK     32
#define NTDS   768      // 3*DS
#define NMM    676      // BM*BM
#define NBM    26
#define NBB    832      // B = K*BM
#define NOCC2  128
#define NPAIR  496      // K*(K-1)/2
#define FSCALE 1.0e-4f
#define A0C    0.5291772f

// ---------------- workspace layout (in floats) ----------------
#define OFF_ACOPY 0ull
#define SZ_ACOPY  (16ull*832*832)
#define OFF_X     (OFF_ACOPY + SZ_ACOPY)
#define SZ_X      (16ull*32*768)
#define OFF_S     (OFF_X + SZ_X)
#define SZ_S      (16ull*768)
#define OFF_D     (OFF_S + SZ_S)
#define OFF_SUB   (OFF_D   + 16ull*832)
#define OFF_TAU   (OFF_SUB + 16ull*832)
#define OFF_EIG   (OFF_TAU + 16ull*832)
#define OFF_UTRI  (OFF_EIG + 16ull*832)
#define SZ_UTRI   (16ull*128*832)
#define OFF_UOCC  (OFF_UTRI + SZ_UTRI)
#define OFF_C     OFF_UTRI   /* C overlays Utri (dead after backxform) */
// tridiag scratch overlays the Utri region (Utri written only later by k_invit)
#define PB   32   // panel width
#define GW   4    // workgroups per matrix (R14: was 8 — participant-count gradient)
#define GWL2 2
#define TPW  1024 // threads per workgroup
#define NWV  16   // waves per WG
#define QMAX 208  // max own rows per WG (832/4)
#define SLOTSTR 1088
#define OFF_WPAN  OFF_UTRI                        /* 16*832*32 = 425,984 */
#define OFF_CBUF  (OFF_WPAN + 16ull*832*32)       /* 16*832 */
#define OFF_SLOT  (OFF_CBUF + 16ull*832)          /* 16*1088 */
#define OFF_BARC  (OFF_SLOT + 16ull*SLOTSTR)      /* 16 ints */

__device__ __forceinline__ void pair_decode(int t, int& k, int& l) {
  int kk = (int)((1.0f + sqrtf(1.0f + 8.0f*(float)t)) * 0.5f);
  while (kk*(kk-1)/2 > t) --kk;
  while ((kk+1)*kk/2 <= t) ++kk;
  k = kk; l = t - kk*(kk-1)/2;
}

// Cross-WG READ: agent-scope bypass load (sc0 sc1) — reads through to the MALL
// (memory-side, unbypassable), so it observes completed bypass stores and
// wbl2-released cached stores with no acquire-invalidate.
__device__ __forceinline__ float gld(const float* p) {
  unsigned int u = __hip_atomic_load((const unsigned int*)p, __ATOMIC_RELAXED, __HIP_MEMORY_SCOPE_AGENT);
  return __uint_as_float(u);
}
// Cross-WG WRITE: agent-scope bypass store (sc0 sc1) — write-through to MALL.
// vmcnt retirement (drained by __syncthreads before the barrier flag bump)
// means the value is at the MALL before any other WG can observe the flag.
__device__ __forceinline__ void gst(float* p, float v) {
  __hip_atomic_store((unsigned int*)p, __float_as_uint(v), __ATOMIC_RELAXED, __HIP_MEMORY_SCOPE_AGENT);
}

// ---------------- x = mu @ transfer_W + b ----------------
__global__ __launch_bounds__(256) void k_x(const float* __restrict__ mu,
                                           const float* __restrict__ tW,
                                           const float* __restrict__ tb,
                                           float* __restrict__ x) {
  const int k = blockIdx.x, n = blockIdx.y, tid = threadIdx.x;
  __shared__ float mus[384];
  const float* mub = mu + (size_t)(n*NK + k)*384;
  for (int i = tid; i < 384; i += 256) mus[i] = mub[i];
  __syncthreads();
  float* xb = x + (size_t)(n*NK + k)*NTDS;
  for (int oo = tid; oo < NTDS; oo += 256) {
    const int d = oo >> 8, i = oo & 255;
    float acc = tb[i];
    const float* mrow = &mus[d*128];
    for (int a = 0; a < 128; ++a) acc += mrow[a]*tW[a*256 + i];
    xb[oo] = acc;
  }
}

// ---------------- S[n][dd] = sum_k x[n][k][dd] ----------------
__global__ __launch_bounds__(256) void k_S(const float* __restrict__ x, float* __restrict__ S) {
  const int n = blockIdx.x, tid = threadIdx.x;
  for (int dd = tid; dd < NTDS; dd += 256) {
    float s = 0.f;
    for (int k = 0; k < NK; ++k) s += x[(size_t)(n*NK + k)*NTDS + dd];
    S[n*NTDS + dd] = s;
  }
}

// ---------------- diagonal blocks ----------------
__global__ __launch_bounds__(256) void k_diag(const float* __restrict__ x, const float* __restrict__ S,
                                              const float* __restrict__ Won, const float* __restrict__ bon,
                                              const float* __restrict__ hnew, const float* __restrict__ Foff,
                                              float* __restrict__ Fout, float* __restrict__ Acopy) {
  const int k = blockIdx.x, n = blockIdx.y, tid = threadIdx.x;
  __shared__ float q[NTDS];
  __shared__ float M[NMM];
  const float* xb = x + (size_t)(n*NK + k)*NTDS;
  const float* Sb = S + n*NTDS;
  for (int i = tid; i < NTDS; i += 256) q[i] = xb[i]*Sb[i];
  __syncthreads();
  for (int m = tid; m < NMM; m += 256) {
    float acc = 32.0f * bon[m];
    for (int dd = 0; dd < NTDS; ++dd) acc += q[dd]*Won[(size_t)dd*NMM + m];
    M[m] = acc;
  }
  __syncthreads();
  const float* hb = hnew + (size_t)n*NBB*NBB;
  float* Fb = Fout + (size_t)n*NBB*NBB;
  float* Ab = Acopy + (size_t)n*NBB*NBB;
  for (int m = tid; m < NMM; m += 256) {
    const int a = m/26, b = m - a*26;
    const float val = 0.5f*(M[m] + M[b*26 + a]);
    const int P = k*26 + a, Q = k*26 + b;
    const size_t idx = (size_t)P*NBB + Q;
    const float fo = Foff[idx];
    const float hv = hb[idx];
    const float Fv = (fabsf(hv) > 1e-7f) ? (val*FSCALE + fo) : fo;
    Fb[idx] = Fv; Ab[idx] = Fv;
  }
}

// ---------------- off-diagonal blocks: GEMM over pairs ----------------
__global__ __launch_bounds__(256) void k_off(const float* __restrict__ x,
                                             const float* __restrict__ Woff, const float* __restrict__ boff,
                                             const float* __restrict__ hnew, const float* __restrict__ Foff,
                                             float* __restrict__ Fout, float* __restrict__ Acopy) {
  const int ct = blockIdx.x, pt = blockIdx.y, n = blockIdx.z;
  const int tid = threadIdx.x;
  __shared__ __align__(16) float At[32*65];
  __shared__ __align__(16) float Bt[64*128];
  __shared__ int klk[32], kll[32];
  if (tid < 32) {
    int pr = pt*32 + tid, kk = 1, ll = 0;
    if (pr < NPAIR) pair_decode(pr, kk, ll);
    klk[tid] = kk; kll[tid] = ll;
  }
  __syncthreads();
  const int ty = tid >> 5, tx = tid & 31;
  const int r0 = ty*4, c0 = tx*4;
  float acc[4][4] = {};
  for (int dd0 = 0; dd0 < NTDS; dd0 += 64) {
    for (int idx = tid; idx < 2048; idx += 256) {
      const int r = idx >> 6, c = idx & 63;
      const int pr = pt*32 + r;
      float v = 0.f;
      if (pr < NPAIR) {
        const int kk = klk[r], ll = kll[r];
        v = x[(size_t)(n*NK + kk)*NTDS + dd0 + c] * x[(size_t)(n*NK + ll)*NTDS + dd0 + c];
      }
      At[r*65 + c] = v;
    }
    for (int idx = tid; idx < 8192; idx += 256) {
      const int r = idx >> 7, c = idx & 127;
      const int col = ct*128 + c;
      Bt[idx] = (col < NMM) ? Woff[(size_t)(dd0 + r)*NMM + col] : 0.f;
    }
    __syncthreads();
    for (int kk = 0; kk < 64; ++kk) {
      float av[4];
      av[0] = At[(r0+0)*65 + kk];
      av[1] = At[(r0+1)*65 + kk];
      av[2] = At[(r0+2)*65 + kk];
      av[3] = At[(r0+3)*65 + kk];
      const float4 b4 = *(const float4*)&Bt[kk*128 + c0];
      const float bb[4] = {b4.x, b4.y, b4.z, b4.w};
      #pragma unroll
      for (int qq = 0; qq < 4; ++qq)
        #pragma unroll
        for (int pp = 0; pp < 4; ++pp)
          acc[qq][pp] += av[qq]*bb[pp];
    }
    __syncthreads();
  }
  const float* hb = hnew + (size_t)n*NBB*NBB;
  float* Fb = Fout + (size_t)n*NBB*NBB;
  float* Ab = Acopy + (size_t)n*NBB*NBB;
  for (int qq = 0; qq < 4; ++qq) {
    const int pr = pt*32 + r0 + qq;
    if (pr >= NPAIR) continue;
    const int kk = klk[r0+qq], ll = kll[r0+qq];
    for (int pp = 0; pp < 4; ++pp) {
      const int m = ct*128 + c0 + pp;
      if (m >= NMM) continue;
      const float val = acc[qq][pp] + boff[m];
      const int a = m/26, b = m - a*26;
      const int P = kk*26 + a, Q = ll*26 + b;
      const size_t i1 = (size_t)P*NBB + Q;
      const float fo1 = Foff[i1], hv1 = hb[i1];
      const float Fv1 = (fabsf(hv1) > 1e-7f) ? (val*FSCALE + fo1) : fo1;
      Fb[i1] = Fv1; Ab[i1] = Fv1;
      const size_t i2 = (size_t)Q*NBB + P;
      const float fo2 = Foff[i2], hv2 = hb[i2];
      const float Fv2 = (fabsf(hv2) > 1e-7f) ? (val*FSCALE + fo2) : fo2;
      Fb[i2] = Fv2; Ab[i2] = Fv2;
    }
  }
}

// ================= blocked (latrd) multi-WG tridiagonalization =================
// R14: GW 8->4 (continuing the confirmed participant-count gradient:
// 16->8 gave 16.9->13.2 us/epoch). 4 arrivals/barrier, 64 WGs polling.
// Per-WG matvec work doubles (work term is only ~2-4us of the epoch).
// Coherence protocol unchanged (proven R7): gst/gld bypass for ALL cross-WG
// data; relaxed rbar per column; release gbar per panel boundary.
__device__ __forceinline__ void rbar(int* cnt, int target) {
  __syncthreads();   // emits s_waitcnt vmcnt(0) before s_barrier: bypass stores MALL-complete
  if (threadIdx.x == 0) {
    asm volatile("" ::: "memory");
    __hip_atomic_fetch_add(cnt, 1, __ATOMIC_RELAXED, __HIP_MEMORY_SCOPE_AGENT);
    while (__hip_atomic_load(cnt, __ATOMIC_RELAXED, __HIP_MEMORY_SCOPE_AGENT) < target)
      __builtin_amdgcn_s_sleep(1);
    asm volatile("" ::: "memory");
  }
  __syncthreads();
}
__device__ __forceinline__ void gbar(int* cnt, int target) {
  __syncthreads();
  if (threadIdx.x == 0) {
    __hip_atomic_fetch_add(cnt, 1, __ATOMIC_RELEASE, __HIP_MEMORY_SCOPE_AGENT);  // wbl2
    while (__hip_atomic_load(cnt, __ATOMIC_RELAXED, __HIP_MEMORY_SCOPE_AGENT) < target)
      __builtin_amdgcn_s_sleep(1);
  }
  __syncthreads();
}

__device__ __forceinline__ float wg_reduce16(float v, volatile float* sred) {
  #pragma unroll
  for (int off = 32; off > 0; off >>= 1) v += __shfl_down(v, off);
  const int tid = threadIdx.x;
  if ((tid & 63) == 0) sred[tid >> 6] = v;
  __syncthreads();
  float r = 0.f;
  #pragma unroll
  for (int t = 0; t < NWV; ++t) r += sred[t];
  __syncthreads();
  return r;
}

__global__ __launch_bounds__(TPW) void k_tridiag_panel(float* __restrict__ Acopy,
                                                       float* __restrict__ dA,
                                                       float* __restrict__ subA,
                                                       float* __restrict__ tauA,
                                                       float* __restrict__ Wpan,
                                                       float* __restrict__ cbufA,
                                                       float* __restrict__ slotA,
                                                       int* __restrict__ barA) {
  const int g = blockIdx.x;          // WG within matrix (0..GW-1)
  const int n = blockIdx.y;          // matrix
  const int tid = threadIdx.x;
  const int lane = tid & 63, wv = tid >> 6;
  float* A    = Acopy + (size_t)n*NBB*NBB;
  float* Wbuf = Wpan  + (size_t)n*NBB*PB;
  float* cbuf = cbufA + (size_t)n*NBB;
  float* slot = slotA + (size_t)n*SLOTSTR;
  float* normp = slot;          // [GW]
  float* vavp  = slot + 16;     // [GW]
  float* alphaS= slot + 32;     // [1]
  float* ynextS= slot + 33;     // [1]
  float* d1pA  = slot + 64;     // [GW][32]
  float* d2pA  = slot + 576;    // [GW][32]
  int*   cnt   = barA + n;

  __shared__ float vsh[NBB];
  __shared__ __align__(16) float vsh4[NBB+8];   // v shifted so matvec reads are 16B-aligned
  __shared__ float yloc[QMAX];
  __shared__ float Vloc[QMAX*33];
  __shared__ float Wloc[QMAX*33];
  __shared__ float Vt[64*33];
  __shared__ float Wt[64*33];
  __shared__ float d1s[PB], d2s[PB], Vk1s[PB], Wk1s[PB];
  __shared__ float sred[NWV];
  __shared__ float s_tau, s_scale, s_vav, s_ynext;
  int ep = 0;

  // ---- prologue: c = A[:,0], norm partials, alpha (all comms via gst) ----
  {
    const int q0p = (GW - g) >> GWL2;   // first q with GW*q+g >= 1
    float np = 0.f;
    const int q = q0p + tid;
    if (q < QMAX) {
      const int j = GW*q + g;
      const float cv = A[(size_t)j*NBB];   // own row (prior kernel, dispatch-coherent)
      gst(&cbuf[j], cv);
      if (j >= 2) np = cv*cv;
      if (j == 1) gst(alphaS, cv);
    }
    const float s = wg_reduce16(np, sred);
    if (tid == 0) gst(&normp[g], s);
  }
  ++ep; gbar(cnt, ep*GW);

  for (int k0 = 0; k0 < NBB-2; k0 += PB) {
    const int ilim = (NBB-2-k0 < PB) ? (NBB-2-k0) : PB;
    for (int i = 0; i < ilim; ++i) {
      const int k = k0 + i;
      const int m = NBB-1-k;
      const int q0 = (k + GW - g) >> GWL2;   // first q with GW*q+g >= k+1
      const int cs = k+1;
      const int nh = (4 - (cs & 3)) & 3;  // head elems to 16B alignment
      const int ca = cs + nh;

      // ================= Epoch X =================
      if (tid == 0) {
        float xn2 = 0.f;
        #pragma unroll
        for (int t = 0; t < GW; ++t) xn2 += gld(&normp[t]);
        const float alpha = gld(alphaS);
        float tau, scale, beta;
        if (xn2 < 1e-26f) {
          beta = alpha; tau = 0.f; scale = 0.f;
        } else {
          beta  = -copysignf(sqrtf(alpha*alpha + xn2), alpha);
          tau   = (beta - alpha) / beta;
          scale = 1.0f / (alpha - beta);
        }
        s_tau = tau; s_scale = scale;
        if (g == 0) { subA[n*NBB + k + 1] = beta; tauA[n*NBB + k] = tau; }
      }
      __syncthreads();
      const float tau = s_tau, scale = s_scale;
      // build v in LDS (both copies; cbuf is cross-WG -> bypass loads)
      for (int idx = tid; idx < m; idx += TPW) {
        const float val = (idx == 0) ? 1.0f : gld(&cbuf[k+1+idx])*scale;
        vsh[idx] = val;
        vsh4[4 + idx - nh] = val;
      }
      __syncthreads();
      // store v (own entries) into row k (transposed reflector, BYPASS) + Vloc
      {
        const int q = q0 + tid;
        if (q < QMAX) {
          const int j = GW*q + g;
          const float val = vsh[j-(k+1)];
          gst(&A[(size_t)k*NBB + j], val);
          Vloc[q*33 + i] = val;
        }
      }
      // d1/d2 partials over own rows (p < i); QMAX>64 -> chunked lane loop
      for (int p = wv; p < i; p += NWV) {
        float a1 = 0.f, a2 = 0.f;
        for (int q = q0 + lane; q < QMAX; q += 64) {
          const int j = GW*q + g;
          const float vj = vsh[j-(k+1)];
          a1 += Vloc[q*33 + p]*vj;
          a2 += Wloc[q*33 + p]*vj;
        }
        #pragma unroll
        for (int off = 32; off > 0; off >>= 1) { a1 += __shfl_down(a1, off); a2 += __shfl_down(a2, off); }
        if (lane == 0) { gst(&d1pA[g*PB + p], a1); gst(&d2pA[g*PB + p], a2); }
      }
      // matvec y = A0 v over own rows (float4 A reads + float4 aligned v reads)
      {
        float vavl = 0.f;
        for (int q = q0 + wv; q < QMAX; q += NWV) {
          const int j = GW*q + g;
          const float* Ar = A + (size_t)j*NBB;
          float acc = 0.f;
          if (lane < nh) acc += Ar[cs+lane]*vsh[lane];
          for (int c = ca + 4*lane; c < NBB; c += 256) {
            const float4 a4 = *(const float4*)&Ar[c];
            const float4 v4 = *(const float4*)&vsh4[4 + c - ca];
            acc += a4.x*v4.x + a4.y*v4.y + a4.z*v4.z + a4.w*v4.w;
          }
          #pragma unroll
          for (int off = 32; off > 0; off >>= 1) acc += __shfl_down(acc, off);
          if (lane == 0) {
            yloc[q] = acc;
            vavl += vsh[j-(k+1)]*acc;
            if (j == k+1) gst(ynextS, acc);
          }
        }
        const float vv = wg_reduce16(vavl, sred);
        if (tid == 0) gst(&vavp[g], vv);
      }
      // prefetch Y-phase inputs that are >=1 barrier old (hide MALL latency)
      if (tid < i) {
        Vk1s[tid] = gld(&A[(size_t)(k0+tid)*NBB + (k+1)]);
        Wk1s[tid] = gld(&Wbuf[(size_t)(k+1)*PB + tid]);
      }
      ++ep; rbar(cnt, ep*GW);

      // ================= Epoch Y =================
      if (tid < i) {
        float s1 = 0.f, s2 = 0.f;
        #pragma unroll
        for (int g2 = 0; g2 < GW; ++g2) { s1 += gld(&d1pA[g2*PB + tid]); s2 += gld(&d2pA[g2*PB + tid]); }
        d1s[tid] = s1; d2s[tid] = s2;
      }
      if (tid == TPW-1) {
        float sv = 0.f;
        #pragma unroll
        for (int t = 0; t < GW; ++t) sv += gld(&vavp[t]);
        s_vav = sv; s_ynext = gld(ynextS);
      }
      __syncthreads();
      // redundant scalars
      float s12 = 0.f, wk1acc = 0.f;
      for (int p = 0; p < i; ++p) { s12 += d1s[p]*d2s[p]; wk1acc += Vk1s[p]*d2s[p] + Wk1s[p]*d1s[p]; }
      const float corr = 0.5f*tau*tau*(s_vav - 2.f*s12);
      const float wk1 = tau*(s_ynext - wk1acc) - corr;
      // own-row w, then c' for column k+1
      {
        const int q = q0 + tid;
        float np = 0.f;
        if (q < QMAX) {
          const int j = GW*q + g;
          float wacc = 0.f;
          for (int p = 0; p < i; ++p) wacc += Vloc[q*33 + p]*d2s[p] + Wloc[q*33 + p]*d1s[p];
          const float vj = vsh[j-(k+1)];
          const float wj = tau*(yloc[q] - wacc) - corr*vj;
          Wloc[q*33 + i] = wj;
          gst(&Wbuf[(size_t)j*PB + i], wj);
          if (j >= k+2) {
            float cacc = 0.f;
            for (int p = 0; p < i; ++p) cacc += Vloc[q*33 + p]*Wk1s[p] + Wloc[q*33 + p]*Vk1s[p];
            cacc += vj*wk1 + wj;   // p = i term (V[k+1,i] = 1)
            const float cp = A[(size_t)j*NBB + (k+1)] - cacc;   // own row, clean cached
            gst(&cbuf[j], cp);
            if (j >= k+3) np = cp*cp;
            if (j == k+2) gst(alphaS, cp);
          }
        }
        const float ns = wg_reduce16(np, sred);
        if (tid == 0) gst(&normp[g], ns);
      }
      // diagonal extraction d[k] (own row plain; cross-WG data via bypass)
      if (g == (k & (GW-1)) && tid == 0) {
        float dk = A[(size_t)k*NBB + k];
        for (int p = 0; p < i; ++p)
          dk -= 2.f * gld(&A[(size_t)(k0+p)*NBB + k]) * gld(&Wbuf[(size_t)k*PB + p]);
        dA[n*NBB + k] = dk;
      }
      ++ep; rbar(cnt, ep*GW);
    }

    // ================= syr2k: A22 -= V W^T + W V^T =================
    if (k0 + PB < NBB-2) {
      const int kp = k0 + PB;
      const int q0s = (kp + GW-1 - g) >> GWL2;   // first q with GW*q+g >= kp
      for (int c0 = kp+1; c0 < NBB; c0 += 64) {
        const int nc = (NBB - c0 < 64) ? (NBB - c0) : 64;
        for (int idx = tid; idx < 2048; idx += TPW) {
          const int p = idx >> 6, cc = idx & 63;
          Vt[cc*33 + p] = (cc < nc) ? gld(&A[(size_t)(k0+p)*NBB + c0 + cc]) : 0.f;
        }
        for (int idx = tid; idx < 2048; idx += TPW) {
          const int p = idx & 31, cc = idx >> 5;
          Wt[cc*33 + p] = (cc < nc) ? gld(&Wbuf[(size_t)(c0+cc)*PB + p]) : 0.f;
        }
        __syncthreads();
        for (int q = q0s + wv; q < QMAX; q += NWV) {
          const int j = GW*q + g;
          if (lane < nc) {
            const int c = c0 + lane;
            float acc = 0.f;
            #pragma unroll
            for (int p = 0; p < PB; ++p)
              acc += Vloc[q*33 + p]*Wt[lane*33 + p] + Wloc[q*33 + p]*Vt[lane*33 + p];
            A[(size_t)j*NBB + c] -= acc;   // own row, cached (cleaned below)
          }
        }
        __syncthreads();
      }
      // diagonal entry [kp][kp]
      if (g == (kp & (GW-1)) && tid == 0) {
        const int qd = kp >> GWL2;
        float acc = 0.f;
        #pragma unroll
        for (int p = 0; p < PB; ++p) acc += Vloc[qd*33 + p]*Wloc[qd*33 + p];
        A[(size_t)kp*NBB + kp] -= 2.f*acc;
      }
      ++ep; gbar(cnt, ep*GW);   // RELEASE: clean syr2k dirt before next panel's gst reflectors
    }
  }

  // ---- epilogue (cross-WG data via bypass loads) ----
  if (g == 0 && tid == 0) {
    const int k0l = ((NBB-3)/PB)*PB;       // 800
    const int np_ = NBB-2-k0l;             // 30
    float dm2 = gld(&A[(size_t)(NBB-2)*NBB + (NBB-2)]);
    float dm1 = gld(&A[(size_t)(NBB-1)*NBB + (NBB-1)]);
    for (int p = 0; p < np_; ++p) {
      dm2 -= 2.f * gld(&A[(size_t)(k0l+p)*NBB + (NBB-2)]) * gld(&Wbuf[(size_t)(NBB-2)*PB + p]);
      dm1 -= 2.f * gld(&A[(size_t)(k0l+p)*NBB + (NBB-1)]) * gld(&Wbuf[(size_t)(NBB-1)*PB + p]);
    }
    dA[n*NBB + NBB-2] = dm2;
    dA[n*NBB + NBB-1] = dm1;
    subA[n*NBB + NBB-1] = gld(alphaS);
    subA[n*NBB + 0] = 0.f;
    tauA[n*NBB + NBB-2] = 0.f;
    tauA[n*NBB + NBB-1] = 0.f;
  }
}

// ---------------- all eigenvalues via bisection (Sturm counts) ----------------
__global__ __launch_bounds__(256) void k_bisect(const float* __restrict__ dA, const float* __restrict__ subA,
                                                float* __restrict__ eig, float* __restrict__ e_out) {
  const int n = blockIdx.y;
  const int i = blockIdx.x*256 + threadIdx.x;
  __shared__ float ds[NBB], ss[NBB];
  const float* dg = dA + n*NBB;
  const float* sg = subA + n*NBB;
  for (int j = threadIdx.x; j < NBB; j += 256) { ds[j] = dg[j]; ss[j] = sg[j]; }
  __syncthreads();
  if (i >= NBB) return;
  float lo = 1e30f, hi = -1e30f;
  for (int j = 0; j < NBB; ++j) {
    const float r = fabsf(ss[j]) + ((j+1 < NBB) ? fabsf(ss[j+1]) : 0.f);
    lo = fminf(lo, ds[j]-r); hi = fmaxf(hi, ds[j]+r);
  }
  const float pad = 1e-3f*(hi-lo) + 1e-3f;
  lo -= pad; hi += pad;
  for (int it = 0; it < 38; ++it) {
    const float mid = 0.5f*(lo+hi);
    int cnt = 0;
    float qv = ds[0]-mid;
    if (qv < 0.f) cnt++;
    for (int j = 1; j < NBB; ++j) {
      const float e = ss[j];
      if (fabsf(qv) < 1e-20f) qv = -1e-20f;
      qv = ds[j]-mid - e*e/qv;
      if (qv < 0.f) cnt++;
    }
    if (cnt > i) hi = mid; else lo = mid;
  }
  const float lam = 0.5f*(lo+hi);
  eig[n*NBB + i] = lam;
  e_out[n*NBB + i] = lam;
}

// ---------------- inverse iteration on T for the 128 lowest ----------------
__global__ __launch_bounds__(64) void k_invit(const float* __restrict__ dA, const float* __restrict__ subA,
                                              const float* __restrict__ eig, float* __restrict__ Utri) {
  const int i = blockIdx.x, n = blockIdx.y;
  const int lane = threadIdx.x;
  __shared__ float ds[NBB], ss[NBB], ud[NBB], u1[NBB], u2[NBB], yv[NBB], xv[NBB];
  const float* dg = dA + n*NBB;
  const float* sg = subA + n*NBB;
  for (int j = lane; j < NBB; j += 64) { ds[j] = dg[j]; ss[j] = sg[j]; }
  const float lam = eig[n*NBB + i];
  for (int j = lane; j < NBB; j += 64) {
    uint32_t s = (uint32_t)(j*2654435761u) ^ (uint32_t)(i*40503u + 977u) ^ (uint32_t)(n*9973u);
    s ^= s >> 16; s *= 0x7feb352dU; s ^= s >> 15; s *= 0x846ca68bU; s ^= s >> 16;
    yv[j] = 0.5f + (float)(s & 0xFFFF) * (1.0f/65536.0f);
  }
  __syncthreads();
  const float PIV = 3e-6f;
  for (int pass = 0; pass < 2; ++pass) {
    if (lane == 0) {
      float cd = ds[0] - lam;
      float cu = ss[1];
      float cy = yv[0];
      for (int j = 0; j < NBB-1; ++j) {
        const float bl = ss[j+1];
        const float bd = ds[j+1] - lam;
        const float bu = (j+2 < NBB) ? ss[j+2] : 0.f;
        const float yb = yv[j+1];
        float tud, tu1, tu2, tm, ncd, ncu, ny;
        if (fabsf(bl) > fabsf(cd)) {
          tud = bl; tu1 = bd; tu2 = bu;
          if (fabsf(tud) < PIV) tud = (tud < 0.f) ? -PIV : PIV;
          tm  = cd / tud;
          ncd = cu - tm*bd;
          ncu = -tm*bu;
          ny  = cy - tm*yb;
          yv[j] = yb;
        } else {
          tud = cd; tu1 = cu; tu2 = 0.f;
          if (fabsf(tud) < PIV) tud = (tud < 0.f) ? -PIV : PIV;
          tm  = bl / tud;
          ncd = bd - tm*cu;
          ncu = bu;
          ny  = yb - tm*cy;
          yv[j] = cy;
        }
        ud[j] = tud; u1[j] = tu1; u2[j] = tu2;
        cd = ncd; cu = ncu; cy = ny;
      }
      if (fabsf(cd) < PIV) cd = (cd < 0.f) ? -PIV : PIV;
      ud[NBB-1] = cd; u1[NBB-1] = 0.f; u2[NBB-1] = 0.f; yv[NBB-1] = cy;
      float x2 = yv[NBB-1]/ud[NBB-1];
      xv[NBB-1] = x2;
      float x1 = (yv[NBB-2] - u1[NBB-2]*x2)/ud[NBB-2];
      xv[NBB-2] = x1;
      for (int j = NBB-3; j >= 0; --j) {
        const float xj = (yv[j] - u1[j]*x1 - u2[j]*x2)/ud[j];
        xv[j] = xj;
        x2 = x1; x1 = xj;
      }
    }
    __syncthreads();
    float p2 = 0.f;
    for (int j = lane; j < NBB; j += 64) { const float t = xv[j]; p2 += t*t; }
    #pragma unroll
    for (int off = 32; off > 0; off >>= 1) p2 += __shfl_xor(p2, off);
    const float rin = rsqrtf(p2);
    if (pass == 0) {
      for (int j = lane; j < NBB; j += 64) yv[j] = xv[j]*rin;
      __syncthreads();
    } else {
      float* Ub = Utri + ((size_t)n*NOCC2 + i)*NBB;
      for (int j = lane; j < NBB; j += 64) Ub[j] = xv[j]*rin;
    }
  }
}

// ---------------- back-transform: Uocc = H0...H829 * Utri ----------------
#define RPT 52
__global__ __launch_bounds__(512) void k_backxform(const float* __restrict__ Acopy,
                                                   const float* __restrict__ tauA,
                                                   const float* __restrict__ Utri,
                                                   float* __restrict__ Uocc) {
  const int cg = blockIdx.x;         // column quarter (0..3)
  const int n = blockIdx.y;
  const int tid = threadIdx.x;
  const int jc = tid & 31, g = tid >> 5;   // 16 row-groups x 52 rows
  const int col = cg*32 + jc;
  __shared__ float vlds[2][NBB];
  __shared__ float sred[16*32];
  const float* A = Acopy + (size_t)n*NBB*NBB;
  float U[RPT];
  const float* Ut = Utri + ((size_t)n*NOCC2 + col)*NBB + g*RPT;
  #pragma unroll
  for (int rr = 0; rr < RPT; ++rr) U[rr] = Ut[rr];
  const int rbase = g*RPT;
  {
    const int k = NBB-3, mm = NBB-1-k;
    for (int idx = tid; idx < mm; idx += 512) vlds[0][idx] = A[(size_t)k*NBB + (k+1+idx)];
  }
  __syncthreads();
  int buf = 0;
  for (int k = NBB-3; k >= 0; --k) {
    float pf0 = 0.f, pf1 = 0.f;
    const int m2 = NBB - k;
    if (k > 0) {
      const float* Arow = A + (size_t)(k-1)*NBB + k;
      if (tid < m2) pf0 = Arow[tid];
      if (tid + 512 < m2) pf1 = Arow[tid + 512];
    }
    const float tau = tauA[n*NBB + k];
    if (tau != 0.f) {
      float part = 0.f;
      #pragma unroll
      for (int rr = 0; rr < RPT; ++rr) {
        const int r = rbase + rr;
        if (r > k) part += U[rr]*vlds[buf][r-k-1];
      }
      sred[g*32 + jc] = part;
      __syncthreads();
      float ssum = 0.f;
      #pragma unroll
      for (int t = 0; t < 16; ++t) ssum += sred[t*32 + jc];
      const float s = tau*ssum;
      #pragma unroll
      for (int rr = 0; rr < RPT; ++rr) {
        const int r = rbase + rr;
        if (r > k) U[rr] -= s*vlds[buf][r-k-1];
      }
    }
    if (k > 0) {
      if (tid < m2) vlds[buf^1][tid] = pf0;
      if (tid + 512 < m2) vlds[buf^1][tid + 512] = pf1;
    }
    __syncthreads();
    buf ^= 1;
  }
  float* Ub = Uocc + (size_t)n*NBB*NOCC2;
  #pragma unroll
  for (int rr = 0; rr < RPT; ++rr) Ub[(size_t)(rbase+rr)*NOCC2 + col] = U[rr];
}

// ---------------- C = h_new * Uocc  (832x832 @ 832x128 per batch) ----------------
__global__ __launch_bounds__(256) void k_gemmC(const float* __restrict__ h,
                                               const float* __restrict__ Uocc,
                                               float* __restrict__ C) {
  const int rt = blockIdx.x, n = blockIdx.y;
  const int tid = threadIdx.x;
  __shared__ __align__(16) float hT[64*33];
  __shared__ __align__(16) float Ut[32*128];
  const int ty = tid >> 5, tx = tid & 31;
  float acc[8][4] = {};
  const float* hb = h + (size_t)n*NBB*NBB + (size_t)rt*64*NBB;
  const float* Ub = Uocc + (size_t)n*NBB*NOCC2;
  for (int k0 = 0; k0 < NBB; k0 += 32) {
    for (int idx = tid; idx < 64*32; idx += 256) {
      const int r = idx >> 5, c = idx & 31;
      hT[r*33 + c] = hb[(size_t)r*NBB + k0 + c];
    }
    for (int idx = tid; idx < 32*128; idx += 256) {
      const int r = idx >> 7, c = idx & 127;
      Ut[idx] = Ub[(size_t)(k0 + r)*NOCC2 + c];
    }
    __syncthreads();
    for (int kk = 0; kk < 32; ++kk) {
      const float4 b4 = *(const float4*)&Ut[kk*128 + tx*4];
      #pragma unroll
      for (int q = 0; q < 8; ++q) {
        const float a = hT[(ty*8 + q)*33 + kk];
        acc[q][0] += a*b4.x; acc[q][1] += a*b4.y; acc[q][2] += a*b4.z; acc[q][3] += a*b4.w;
      }
    }
    __syncthreads();
  }
  float* Cb = C + (size_t)n*NBB*NOCC2;
  #pragma unroll
  for (int q = 0; q < 8; ++q)
    #pragma unroll
    for (int p = 0; p < 4; ++p)
      Cb[(size_t)(rt*64 + ty*8 + q)*NOCC2 + tx*4 + p] = acc[q][p];
}

// ---------------- E = sum(e_occ) + Tr(Uocc^T h Uocc) + nuc ----------------
__global__ __launch_bounds__(256) void k_final(const float* __restrict__ eig,
                                               const float* __restrict__ Uocc, const float* __restrict__ C,
                                               const float* __restrict__ pos, const int* __restrict__ numbers,
                                               float* __restrict__ E_out) {
  const int n = blockIdx.x, tid = threadIdx.x;
  __shared__ float rb[256];
  float local = 0.f;
  for (int i = tid; i < NOCC2; i += 256) local += eig[n*NBB + i];
  const float* Ub = Uocc + (size_t)n*NBB*NOCC2;
  const float* Cb = C + (size_t)n*NBB*NOCC2;
  for (int idx = tid; idx < NBB*NOCC2; idx += 256) local += Ub[idx]*Cb[idx];
  float ln = 0.f;
  for (int t = tid; t < NPAIR; t += 256) {
    int kk, ll;
    pair_decode(t, kk, ll);
    const float dx = pos[(n*NK + kk)*3 + 0] - pos[(n*NK + ll)*3 + 0];
    const float dy = pos[(n*NK + kk)*3 + 1] - pos[(n*NK + ll)*3 + 1];
    const float dz = pos[(n*NK + kk)*3 + 2] - pos[(n*NK + ll)*3 + 2];
    const float d2 = dx*dx + dy*dy + dz*dz;
    const float Z = (float)(numbers[kk]*numbers[ll]);
    ln += Z / sqrtf(d2);
  }
  local += ln * A0C;
  rb[tid] = local;
  __syncthreads();
  for (int s = 128; s > 0; s >>= 1) {
    if (tid < s) rb[tid] += rb[tid + s];
    __syncthreads();
  }
  if (tid == 0) E_out[n] = rb[0];
}

extern "C" void kernel_launch(void* const* d_in, const int* in_sizes, int n_in,
                              void* d_out, int out_size, void* d_ws, size_t ws_size,
                              hipStream_t stream) {
  (void)in_sizes; (void)n_in; (void)out_size; (void)ws_size;
  const float* mu      = (const float*)d_in[0];
  const float* hnew    = (const float*)d_in[1];
  const float* pos     = (const float*)d_in[2];
  const float* Foff    = (const float*)d_in[3];
  const float* tW      = (const float*)d_in[4];
  const float* tb      = (const float*)d_in[5];
  const float* Won     = (const float*)d_in[6];
  const float* bon     = (const float*)d_in[7];
  const float* Woff    = (const float*)d_in[8];
  const float* boff    = (const float*)d_in[9];
  const int*   numbers = (const int*)d_in[10];

  float* out   = (float*)d_out;
  float* Fout  = out;                               // [16][832][832]
  float* e_out = out + (size_t)NBATCH*NBB*NBB;      // [16][832]
  float* E_out = e_out + (size_t)NBATCH*NBB;        // [16]

  float* ws    = (float*)d_ws;
  float* Acopy = ws + OFF_ACOPY;
  float* xbuf  = ws + OFF_X;
  float* Sbuf  = ws + OFF_S;
  float* dA    = ws + OFF_D;
  float* subA  = ws + OFF_SUB;
  float* tauA  = ws + OFF_TAU;
  float* eig   = ws + OFF_EIG;
  float* Utri  = ws + OFF_UTRI;
  float* Uocc  = ws + OFF_UOCC;
  float* Cbuf  = ws + OFF_C;     // overlays Utri
  float* Wpan  = ws + OFF_WPAN;  // overlays Utri (dead until k_invit)
  float* cbufA = ws + OFF_CBUF;
  float* slotA = ws + OFF_SLOT;
  int*   barA  = (int*)(ws + OFF_BARC);

  // zero the per-matrix barrier counters (graph-captured; runs every replay)
  hipMemsetAsync((void*)barA, 0, NBATCH*sizeof(int), stream);

  k_x<<<dim3(NK, NBATCH), dim3(256), 0, stream>>>(mu, tW, tb, xbuf);
  k_S<<<dim3(NBATCH), dim3(256), 0, stream>>>(xbuf, Sbuf);
  k_diag<<<dim3(NK, NBATCH), dim3(256), 0, stream>>>(xbuf, Sbuf, Won, bon, hnew, Foff, Fout, Acopy);
  k_off<<<dim3(6, 16, NBATCH), dim3(256), 0, stream>>>(xbuf, Woff, boff, hnew, Foff, Fout, Acopy);
  k_tridiag_panel<<<dim3(GW, NBATCH), dim3(TPW), 0, stream>>>(Acopy, dA, subA, tauA, Wpan, cbufA, slotA, barA);
  k_bisect<<<dim3(4, NBATCH), dim3(256), 0, stream>>>(dA, subA, eig, e_out);
  k_invit<<<dim3(NOCC2, NBATCH), dim3(64), 0, stream>>>(dA, subA, eig, Utri);
  k_backxform<<<dim3(4, NBATCH), dim3(512), 0, stream>>>(Acopy, tauA, Utri, Uocc);
  k_gemmC<<<dim3(13, NBATCH), dim3(256), 0, stream>>>(hnew, Uocc, Cbuf);
  k_final<<<dim3(NBATCH), dim3(256), 0, stream>>>(eig, Uocc, Cbuf, pos, numbers, E_out);
}

// Round 15
// 26970.581 us; speedup vs baseline: 2.8985x; 1.0146x over previous
//
#include <hip/hip_runtime.h>
#include <math.h>
#include <stdint.h>

// Problem constants
#define NBATCH 16
#define NK     32
#define NTDS   768      // 3*DS
#define NMM    676      // BM*BM
#define NBM    26
#define NBB    832      // B = K*BM
#define NOCC2  128
#define NPAIR  496      // K*(K-1)/2
#define FSCALE 1.0e-4f
#define A0C    0.5291772f

// ---------------- workspace layout (in floats) ----------------
#define OFF_ACOPY 0ull
#define SZ_ACOPY  (16ull*832*832)
#define OFF_X     (OFF_ACOPY + SZ_ACOPY)
#define SZ_X      (16ull*32*768)
#define OFF_S     (OFF_X + SZ_X)
#define SZ_S      (16ull*768)
#define OFF_D     (OFF_S + SZ_S)
#define OFF_SUB   (OFF_D   + 16ull*832)
#define OFF_TAU   (OFF_SUB + 16ull*832)
#define OFF_EIG   (OFF_TAU + 16ull*832)
#define OFF_UTRI  (OFF_EIG + 16ull*832)
#define SZ_UTRI   (16ull*128*832)
#define OFF_UOCC  (OFF_UTRI + SZ_UTRI)
#define OFF_C     OFF_UTRI   /* C overlays Utri (dead after backxform) */
// tridiag scratch overlays the Utri region (Utri written only later by k_invit)
#define PB   16   // panel width (R15: full V/W panels LDS-resident in every WG)
#define GW   4    // workgroups per matrix
#define GWL2 2
#define TPW  1024 // threads per workgroup
#define NWV  16   // waves per WG
#define QMAX 208  // max own rows per WG (832/4)
#define OFF_YBUF  OFF_UTRI                        /* 16*832 floats (y exchange) */
#define OFF_BARC  (OFF_YBUF + 16ull*832)          /* 16 ints */

__device__ __forceinline__ void pair_decode(int t, int& k, int& l) {
  int kk = (int)((1.0f + sqrtf(1.0f + 8.0f*(float)t)) * 0.5f);
  while (kk*(kk-1)/2 > t) --kk;
  while ((kk+1)*kk/2 <= t) ++kk;
  k = kk; l = t - kk*(kk-1)/2;
}

// Cross-WG READ: agent-scope bypass load (sc0 sc1) — reads through to the MALL.
__device__ __forceinline__ float gld(const float* p) {
  unsigned int u = __hip_atomic_load((const unsigned int*)p, __ATOMIC_RELAXED, __HIP_MEMORY_SCOPE_AGENT);
  return __uint_as_float(u);
}
// Cross-WG WRITE: agent-scope bypass store (sc0 sc1) — write-through to MALL.
__device__ __forceinline__ void gst(float* p, float v) {
  __hip_atomic_store((unsigned int*)p, __float_as_uint(v), __ATOMIC_RELAXED, __HIP_MEMORY_SCOPE_AGENT);
}

// ---------------- x = mu @ transfer_W + b ----------------
__global__ __launch_bounds__(256) void k_x(const float* __restrict__ mu,
                                           const float* __restrict__ tW,
                                           const float* __restrict__ tb,
                                           float* __restrict__ x) {
  const int k = blockIdx.x, n = blockIdx.y, tid = threadIdx.x;
  __shared__ float mus[384];
  const float* mub = mu + (size_t)(n*NK + k)*384;
  for (int i = tid; i < 384; i += 256) mus[i] = mub[i];
  __syncthreads();
  float* xb = x + (size_t)(n*NK + k)*NTDS;
  for (int oo = tid; oo < NTDS; oo += 256) {
    const int d = oo >> 8, i = oo & 255;
    float acc = tb[i];
    const float* mrow = &mus[d*128];
    for (int a = 0; a < 128; ++a) acc += mrow[a]*tW[a*256 + i];
    xb[oo] = acc;
  }
}

// ---------------- S[n][dd] = sum_k x[n][k][dd] ----------------
__global__ __launch_bounds__(256) void k_S(const float* __restrict__ x, float* __restrict__ S) {
  const int n = blockIdx.x, tid = threadIdx.x;
  for (int dd = tid; dd < NTDS; dd += 256) {
    float s = 0.f;
    for (int k = 0; k < NK; ++k) s += x[(size_t)(n*NK + k)*NTDS + dd];
    S[n*NTDS + dd] = s;
  }
}

// ---------------- diagonal blocks ----------------
__global__ __launch_bounds__(256) void k_diag(const float* __restrict__ x, const float* __restrict__ S,
                                              const float* __restrict__ Won, const float* __restrict__ bon,
                                              const float* __restrict__ hnew, const float* __restrict__ Foff,
                                              float* __restrict__ Fout, float* __restrict__ Acopy) {
  const int k = blockIdx.x, n = blockIdx.y, tid = threadIdx.x;
  __shared__ float q[NTDS];
  __shared__ float M[NMM];
  const float* xb = x + (size_t)(n*NK + k)*NTDS;
  const float* Sb = S + n*NTDS;
  for (int i = tid; i < NTDS; i += 256) q[i] = xb[i]*Sb[i];
  __syncthreads();
  for (int m = tid; m < NMM; m += 256) {
    float acc = 32.0f * bon[m];
    for (int dd = 0; dd < NTDS; ++dd) acc += q[dd]*Won[(size_t)dd*NMM + m];
    M[m] = acc;
  }
  __syncthreads();
  const float* hb = hnew + (size_t)n*NBB*NBB;
  float* Fb = Fout + (size_t)n*NBB*NBB;
  float* Ab = Acopy + (size_t)n*NBB*NBB;
  for (int m = tid; m < NMM; m += 256) {
    const int a = m/26, b = m - a*26;
    const float val = 0.5f*(M[m] + M[b*26 + a]);
    const int P = k*26 + a, Q = k*26 + b;
    const size_t idx = (size_t)P*NBB + Q;
    const float fo = Foff[idx];
    const float hv = hb[idx];
    const float Fv = (fabsf(hv) > 1e-7f) ? (val*FSCALE + fo) : fo;
    Fb[idx] = Fv; Ab[idx] = Fv;
  }
}

// ---------------- off-diagonal blocks: GEMM over pairs ----------------
__global__ __launch_bounds__(256) void k_off(const float* __restrict__ x,
                                             const float* __restrict__ Woff, const float* __restrict__ boff,
                                             const float* __restrict__ hnew, const float* __restrict__ Foff,
                                             float* __restrict__ Fout, float* __restrict__ Acopy) {
  const int ct = blockIdx.x, pt = blockIdx.y, n = blockIdx.z;
  const int tid = threadIdx.x;
  __shared__ __align__(16) float At[32*65];
  __shared__ __align__(16) float Bt[64*128];
  __shared__ int klk[32], kll[32];
  if (tid < 32) {
    int pr = pt*32 + tid, kk = 1, ll = 0;
    if (pr < NPAIR) pair_decode(pr, kk, ll);
    klk[tid] = kk; kll[tid] = ll;
  }
  __syncthreads();
  const int ty = tid >> 5, tx = tid & 31;
  const int r0 = ty*4, c0 = tx*4;
  float acc[4][4] = {};
  for (int dd0 = 0; dd0 < NTDS; dd0 += 64) {
    for (int idx = tid; idx < 2048; idx += 256) {
      const int r = idx >> 6, c = idx & 63;
      const int pr = pt*32 + r;
      float v = 0.f;
      if (pr < NPAIR) {
        const int kk = klk[r], ll = kll[r];
        v = x[(size_t)(n*NK + kk)*NTDS + dd0 + c] * x[(size_t)(n*NK + ll)*NTDS + dd0 + c];
      }
      At[r*65 + c] = v;
    }
    for (int idx = tid; idx < 8192; idx += 256) {
      const int r = idx >> 7, c = idx & 127;
      const int col = ct*128 + c;
      Bt[idx] = (col < NMM) ? Woff[(size_t)(dd0 + r)*NMM + col] : 0.f;
    }
    __syncthreads();
    for (int kk = 0; kk < 64; ++kk) {
      float av[4];
      av[0] = At[(r0+0)*65 + kk];
      av[1] = At[(r0+1)*65 + kk];
      av[2] = At[(r0+2)*65 + kk];
      av[3] = At[(r0+3)*65 + kk];
      const float4 b4 = *(const float4*)&Bt[kk*128 + c0];
      const float bb[4] = {b4.x, b4.y, b4.z, b4.w};
      #pragma unroll
      for (int qq = 0; qq < 4; ++qq)
        #pragma unroll
        for (int pp = 0; pp < 4; ++pp)
          acc[qq][pp] += av[qq]*bb[pp];
    }
    __syncthreads();
  }
  const float* hb = hnew + (size_t)n*NBB*NBB;
  float* Fb = Fout + (size_t)n*NBB*NBB;
  float* Ab = Acopy + (size_t)n*NBB*NBB;
  for (int qq = 0; qq < 4; ++qq) {
    const int pr = pt*32 + r0 + qq;
    if (pr >= NPAIR) continue;
    const int kk = klk[r0+qq], ll = kll[r0+qq];
    for (int pp = 0; pp < 4; ++pp) {
      const int m = ct*128 + c0 + pp;
      if (m >= NMM) continue;
      const float val = acc[qq][pp] + boff[m];
      const int a = m/26, b = m - a*26;
      const int P = kk*26 + a, Q = ll*26 + b;
      const size_t i1 = (size_t)P*NBB + Q;
      const float fo1 = Foff[i1], hv1 = hb[i1];
      const float Fv1 = (fabsf(hv1) > 1e-7f) ? (val*FSCALE + fo1) : fo1;
      Fb[i1] = Fv1; Ab[i1] = Fv1;
      const size_t i2 = (size_t)Q*NBB + P;
      const float fo2 = Foff[i2], hv2 = hb[i2];
      const float Fv2 = (fabsf(hv2) > 1e-7f) ? (val*FSCALE + fo2) : fo2;
      Fb[i2] = Fv2; Ab[i2] = Fv2;
    }
  }
}

// ================= fused single-barrier latrd tridiagonalization =================
// R15: PB=16 -> FULL V/W panels LDS-resident in EVERY WG. All scalar/vector
// exchanges (d1/d2/vav/norm/alpha/c) computed REDUNDANTLY per WG (bitwise
// identical). Only cross-WG datum per column: matvec y (distributed rows,
// published via gst). => ONE barrier per column (830 rbars + 51 gbars).
// Coherence: R7-proven primitives. Math is a term-for-term port of R14.
__device__ __forceinline__ void rbar(int* cnt, int target) {
  __syncthreads();
  if (threadIdx.x == 0) {
    asm volatile("" ::: "memory");
    __hip_atomic_fetch_add(cnt, 1, __ATOMIC_RELAXED, __HIP_MEMORY_SCOPE_AGENT);
    while (__hip_atomic_load(cnt, __ATOMIC_RELAXED, __HIP_MEMORY_SCOPE_AGENT) < target)
      __builtin_amdgcn_s_sleep(1);
    asm volatile("" ::: "memory");
  }
  __syncthreads();
}
__device__ __forceinline__ void gbar(int* cnt, int target) {
  __syncthreads();
  if (threadIdx.x == 0) {
    __hip_atomic_fetch_add(cnt, 1, __ATOMIC_RELEASE, __HIP_MEMORY_SCOPE_AGENT);  // wbl2
    while (__hip_atomic_load(cnt, __ATOMIC_RELAXED, __HIP_MEMORY_SCOPE_AGENT) < target)
      __builtin_amdgcn_s_sleep(1);
  }
  __syncthreads();
}

__device__ __forceinline__ float wg_reduce16(float v, volatile float* sred) {
  #pragma unroll
  for (int off = 32; off > 0; off >>= 1) v += __shfl_down(v, off);
  const int tid = threadIdx.x;
  if ((tid & 63) == 0) sred[tid >> 6] = v;
  __syncthreads();
  float r = 0.f;
  #pragma unroll
  for (int t = 0; t < NWV; ++t) r += sred[t];
  __syncthreads();
  return r;
}

__global__ __launch_bounds__(TPW) void k_tridiag_fused(float* __restrict__ Acopy,
                                                       float* __restrict__ dA,
                                                       float* __restrict__ subA,
                                                       float* __restrict__ tauA,
                                                       float* __restrict__ ybufA,
                                                       int* __restrict__ barA) {
  const int g = blockIdx.x;          // WG within matrix (0..GW-1)
  const int n = blockIdx.y;          // matrix
  const int tid = threadIdx.x;
  const int lane = tid & 63, wv = tid >> 6;
  float* A    = Acopy + (size_t)n*NBB*NBB;
  float* ybuf = ybufA + (size_t)n*NBB;
  int*   cnt  = barA + n;

  __shared__ float Vf[NBB*(PB+1)];   // [j][p], stride 17 (full panel, redundant)
  __shared__ float Wf[NBB*(PB+1)];
  __shared__ float vsh[NBB];
  __shared__ __align__(16) float vsh4[NBB];
  __shared__ float csh[NBB];
  __shared__ float ysh[NBB];
  __shared__ float spart[NWV*32];    // per-wave dot partials (31 slots used)
  __shared__ float dsum[32];         // [0]=vav, [1+p]=d1[p], [16+p]=d2[p]
  __shared__ float sred[NWV];
  __shared__ float taus[PB];
  int ep = 0;

  // complete column kprev (compute w(kprev), store into Vf/Wf col iprev)
  auto complete_prev = [&](int kprev, int iprev) {
    { int j = kprev+1+tid; if (j < NBB) ysh[j] = gld(&ybuf[j]); }
    __syncthreads();
    // per-thread products for vav + d1/d2 dots
    float pv = 0.f;
    float p1[PB-1], p2[PB-1];
    #pragma unroll
    for (int p = 0; p < PB-1; ++p) { p1[p] = 0.f; p2[p] = 0.f; }
    { int j = kprev+1+tid;
      if (j < NBB) {
        const float vj = vsh[j];
        pv = vj*ysh[j];
        #pragma unroll
        for (int p = 0; p < PB-1; ++p) if (p < iprev) {
          p1[p] = Vf[j*(PB+1)+p]*vj;
          p2[p] = Wf[j*(PB+1)+p]*vj;
        }
      }
    }
    #pragma unroll
    for (int off = 32; off > 0; off >>= 1) {
      pv += __shfl_down(pv, off);
      #pragma unroll
      for (int p = 0; p < PB-1; ++p) { p1[p] += __shfl_down(p1[p], off); p2[p] += __shfl_down(p2[p], off); }
    }
    if (lane == 0) {
      spart[wv*32 + 0] = pv;
      #pragma unroll
      for (int p = 0; p < PB-1; ++p) { spart[wv*32 + 1 + p] = p1[p]; spart[wv*32 + 16 + p] = p2[p]; }
    }
    __syncthreads();
    if (tid < 31) {
      float s = 0.f;
      #pragma unroll
      for (int w = 0; w < NWV; ++w) s += spart[w*32 + tid];
      dsum[tid] = s;
    }
    __syncthreads();
    const float tau = taus[iprev];
    float s12 = 0.f;
    for (int p = 0; p < iprev; ++p) s12 += dsum[1+p]*dsum[16+p];
    const float corr = 0.5f*tau*tau*(dsum[0] - 2.f*s12);
    { int j = kprev+1+tid;
      if (j < NBB) {
        float wacc = 0.f;
        #pragma unroll
        for (int p = 0; p < PB-1; ++p) if (p < iprev)
          wacc += Vf[j*(PB+1)+p]*dsum[16+p] + Wf[j*(PB+1)+p]*dsum[1+p];
        const float wj = tau*(ysh[j] - wacc) - corr*vsh[j];
        Wf[j*(PB+1)+iprev] = wj;
        Vf[j*(PB+1)+iprev] = vsh[j];
      }
    }
    __syncthreads();
  };

  for (int k0 = 0; k0 < NBB-2; k0 += PB) {
    const int ilim = (NBB-2-k0 < PB) ? (NBB-2-k0) : PB;
    for (int i = 0; i < ilim; ++i) {
      const int k = k0 + i;
      if (i > 0) complete_prev(k-1, i-1);

      // ---- c(k) = A0[:,k] - panel corrections (redundant, rows j >= k) ----
      { int j = k+tid; if (j < NBB) csh[j] = gld(&A[(size_t)j*NBB + k]); }
      __syncthreads();
      { int j = k+tid;
        if (j < NBB) {
          float cacc = 0.f;
          #pragma unroll
          for (int p = 0; p < PB; ++p) if (p < i)
            cacc += Vf[j*(PB+1)+p]*Wf[k*(PB+1)+p] + Wf[j*(PB+1)+p]*Vf[k*(PB+1)+p];
          csh[j] -= cacc;
        }
      }
      __syncthreads();
      // ---- norm/alpha/tau (redundant; bitwise identical across WGs) ----
      float np2 = 0.f;
      { int j2 = k+2+tid; if (j2 < NBB) { const float c = csh[j2]; np2 = c*c; } }
      const float nrm = wg_reduce16(np2, sred);
      const float alpha = csh[k+1];
      float tau, scale, beta;
      if (nrm < 1e-26f) { beta = alpha; tau = 0.f; scale = 0.f; }
      else {
        beta  = -copysignf(sqrtf(alpha*alpha + nrm), alpha);
        tau   = (beta - alpha) / beta;
        scale = 1.0f / (alpha - beta);
      }
      if (tid == 0) taus[i] = tau;
      if (g == 0 && tid == 0) {
        subA[n*NBB + k + 1] = beta;
        tauA[n*NBB + k] = tau;
        dA[n*NBB + k] = csh[k];
      }
      // ---- v(k) ----
      { int j3 = k+1+tid;
        if (j3 < NBB) {
          const float val = (j3 == k+1) ? 1.0f : csh[j3]*scale;
          vsh[j3] = val; vsh4[j3] = val;
        }
      }
      __syncthreads();
      // reflector publish (row k, BYPASS) by owner WG
      if (g == (k & (GW-1))) {
        int j4 = k+1+tid;
        if (j4 < NBB) gst(&A[(size_t)k*NBB + j4], vsh[j4]);
      }
      // ---- distributed matvec y(k) over OWN rows; publish via gst ----
      {
        const int cs = k+1;
        const int nh = (4 - (cs & 3)) & 3;
        const int ca = cs + nh;
        const int q0 = (k + GW - g) >> GWL2;
        for (int q = q0 + wv; q < QMAX; q += NWV) {
          const int jr = GW*q + g;
          const float* Ar = A + (size_t)jr*NBB;
          float acc = 0.f;
          if (lane < nh) acc += Ar[cs+lane]*vsh[cs+lane];
          for (int c = ca + 4*lane; c < NBB; c += 256) {
            const float4 a4 = *(const float4*)&Ar[c];
            const float4 v4 = *(const float4*)&vsh4[c];
            acc += a4.x*v4.x + a4.y*v4.y + a4.z*v4.z + a4.w*v4.w;
          }
          #pragma unroll
          for (int off = 32; off > 0; off >>= 1) acc += __shfl_down(acc, off);
          if (lane == 0) gst(&ybuf[jr], acc);
        }
      }
      ++ep; rbar(cnt, ep*GW);
    }

    // ---- panel boundary: finish last w, then syr2k (own rows, cached) ----
    if (k0 + PB < NBB-2) {
      const int kp = k0 + PB;
      complete_prev(kp-1, PB-1);
      const int q0s = (kp + GW-1 - g) >> GWL2;
      for (int q = q0s + wv; q < QMAX; q += NWV) {
        const int jr = GW*q + g;
        float vr[PB], wr[PB];
        #pragma unroll
        for (int p = 0; p < PB; ++p) { vr[p] = Vf[jr*(PB+1)+p]; wr[p] = Wf[jr*(PB+1)+p]; }
        for (int c = kp + lane; c < NBB; c += 64) {
          float acc = 0.f;
          #pragma unroll
          for (int p = 0; p < PB; ++p)
            acc += vr[p]*Wf[c*(PB+1)+p] + wr[p]*Vf[c*(PB+1)+p];
          A[(size_t)jr*NBB + c] -= acc;   // own row, cached (cleaned by gbar)
        }
      }
      ++ep; gbar(cnt, ep*GW);   // RELEASE: clean syr2k dirt before next panel's glds
    }
  }

  // ---- final: complete w(NBB-3), epilogue diagonals ----
  {
    const int k0l = ((NBB-3)/PB)*PB;
    const int npl = NBB-2-k0l;           // last-panel column count
    complete_prev(NBB-3, npl-1);
    if (g == 0 && tid == 0) {
      const int r2 = NBB-2, r1 = NBB-1;
      float dm2 = gld(&A[(size_t)r2*NBB + r2]);
      float dm1 = gld(&A[(size_t)r1*NBB + r1]);
      float sb  = gld(&A[(size_t)r1*NBB + r2]);
      for (int p = 0; p < npl; ++p) {
        dm2 -= 2.f*Vf[r2*(PB+1)+p]*Wf[r2*(PB+1)+p];
        dm1 -= 2.f*Vf[r1*(PB+1)+p]*Wf[r1*(PB+1)+p];
        sb  -= Vf[r1*(PB+1)+p]*Wf[r2*(PB+1)+p] + Wf[r1*(PB+1)+p]*Vf[r2*(PB+1)+p];
      }
      dA[n*NBB + r2] = dm2;
      dA[n*NBB + r1] = dm1;
      subA[n*NBB + r1] = sb;
      subA[n*NBB + 0] = 0.f;
      tauA[n*NBB + r2] = 0.f;
      tauA[n*NBB + r1] = 0.f;
    }
  }
}

// ---------------- all eigenvalues via bisection (Sturm counts) ----------------
__global__ __launch_bounds__(256) void k_bisect(const float* __restrict__ dA, const float* __restrict__ subA,
                                                float* __restrict__ eig, float* __restrict__ e_out) {
  const int n = blockIdx.y;
  const int i = blockIdx.x*256 + threadIdx.x;
  __shared__ float ds[NBB], ss[NBB];
  const float* dg = dA + n*NBB;
  const float* sg = subA + n*NBB;
  for (int j = threadIdx.x; j < NBB; j += 256) { ds[j] = dg[j]; ss[j] = sg[j]; }
  __syncthreads();
  if (i >= NBB) return;
  float lo = 1e30f, hi = -1e30f;
  for (int j = 0; j < NBB; ++j) {
    const float r = fabsf(ss[j]) + ((j+1 < NBB) ? fabsf(ss[j+1]) : 0.f);
    lo = fminf(lo, ds[j]-r); hi = fmaxf(hi, ds[j]+r);
  }
  const float pad = 1e-3f*(hi-lo) + 1e-3f;
  lo -= pad; hi += pad;
  for (int it = 0; it < 30; ++it) {
    const float mid = 0.5f*(lo+hi);
    int cnt = 0;
    float qv = ds[0]-mid;
    if (qv < 0.f) cnt++;
    for (int j = 1; j < NBB; ++j) {
      const float e = ss[j];
      if (fabsf(qv) < 1e-20f) qv = -1e-20f;
      qv = ds[j]-mid - e*e/qv;
      if (qv < 0.f) cnt++;
    }
    if (cnt > i) hi = mid; else lo = mid;
  }
  const float lam = 0.5f*(lo+hi);
  eig[n*NBB + i] = lam;
  e_out[n*NBB + i] = lam;
}

// ---------------- inverse iteration on T for the 128 lowest ----------------
__global__ __launch_bounds__(64) void k_invit(const float* __restrict__ dA, const float* __restrict__ subA,
                                              const float* __restrict__ eig, float* __restrict__ Utri) {
  const int i = blockIdx.x, n = blockIdx.y;
  const int lane = threadIdx.x;
  __shared__ float ds[NBB], ss[NBB], ud[NBB], u1[NBB], u2[NBB], yv[NBB], xv[NBB];
  const float* dg = dA + n*NBB;
  const float* sg = subA + n*NBB;
  for (int j = lane; j < NBB; j += 64) { ds[j] = dg[j]; ss[j] = sg[j]; }
  const float lam = eig[n*NBB + i];
  for (int j = lane; j < NBB; j += 64) {
    uint32_t s = (uint32_t)(j*2654435761u) ^ (uint32_t)(i*40503u + 977u) ^ (uint32_t)(n*9973u);
    s ^= s >> 16; s *= 0x7feb352dU; s ^= s >> 15; s *= 0x846ca68bU; s ^= s >> 16;
    yv[j] = 0.5f + (float)(s & 0xFFFF) * (1.0f/65536.0f);
  }
  __syncthreads();
  const float PIV = 3e-6f;
  for (int pass = 0; pass < 2; ++pass) {
    if (lane == 0) {
      float cd = ds[0] - lam;
      float cu = ss[1];
      float cy = yv[0];
      for (int j = 0; j < NBB-1; ++j) {
        const float bl = ss[j+1];
        const float bd = ds[j+1] - lam;
        const float bu = (j+2 < NBB) ? ss[j+2] : 0.f;
        const float yb = yv[j+1];
        float tud, tu1, tu2, tm, ncd, ncu, ny;
        if (fabsf(bl) > fabsf(cd)) {
          tud = bl; tu1 = bd; tu2 = bu;
          if (fabsf(tud) < PIV) tud = (tud < 0.f) ? -PIV : PIV;
          tm  = cd / tud;
          ncd = cu - tm*bd;
          ncu = -tm*bu;
          ny  = cy - tm*yb;
          yv[j] = yb;
        } else {
          tud = cd; tu1 = cu; tu2 = 0.f;
          if (fabsf(tud) < PIV) tud = (tud < 0.f) ? -PIV : PIV;
          tm  = bl / tud;
          ncd = bd - tm*cu;
          ncu = bu;
          ny  = yb - tm*cy;
          yv[j] = cy;
        }
        ud[j] = tud; u1[j] = tu1; u2[j] = tu2;
        cd = ncd; cu = ncu; cy = ny;
      }
      if (fabsf(cd) < PIV) cd = (cd < 0.f) ? -PIV : PIV;
      ud[NBB-1] = cd; u1[NBB-1] = 0.f; u2[NBB-1] = 0.f; yv[NBB-1] = cy;
      float x2 = yv[NBB-1]/ud[NBB-1];
      xv[NBB-1] = x2;
      float x1 = (yv[NBB-2] - u1[NBB-2]*x2)/ud[NBB-2];
      xv[NBB-2] = x1;
      for (int j = NBB-3; j >= 0; --j) {
        const float xj = (yv[j] - u1[j]*x1 - u2[j]*x2)/ud[j];
        xv[j] = xj;
        x2 = x1; x1 = xj;
      }
    }
    __syncthreads();
    float p2 = 0.f;
    for (int j = lane; j < NBB; j += 64) { const float t = xv[j]; p2 += t*t; }
    #pragma unroll
    for (int off = 32; off > 0; off >>= 1) p2 += __shfl_xor(p2, off);
    const float rin = rsqrtf(p2);
    if (pass == 0) {
      for (int j = lane; j < NBB; j += 64) yv[j] = xv[j]*rin;
      __syncthreads();
    } else {
      float* Ub = Utri + ((size_t)n*NOCC2 + i)*NBB;
      for (int j = lane; j < NBB; j += 64) Ub[j] = xv[j]*rin;
    }
  }
}

// ---------------- back-transform: Uocc = H0...H829 * Utri ----------------
#define RPT 52
__global__ __launch_bounds__(512) void k_backxform(const float* __restrict__ Acopy,
                                                   const float* __restrict__ tauA,
                                                   const float* __restrict__ Utri,
                                                   float* __restrict__ Uocc) {
  const int cg = blockIdx.x;         // column quarter (0..3)
  const int n = blockIdx.y;
  const int tid = threadIdx.x;
  const int jc = tid & 31, g = tid >> 5;   // 16 row-groups x 52 rows
  const int col = cg*32 + jc;
  __shared__ float vlds[2][NBB];
  __shared__ float sred[16*32];
  const float* A = Acopy + (size_t)n*NBB*NBB;
  float U[RPT];
  const float* Ut = Utri + ((size_t)n*NOCC2 + col)*NBB + g*RPT;
  #pragma unroll
  for (int rr = 0; rr < RPT; ++rr) U[rr] = Ut[rr];
  const int rbase = g*RPT;
  {
    const int k = NBB-3, mm = NBB-1-k;
    for (int idx = tid; idx < mm; idx += 512) vlds[0][idx] = A[(size_t)k*NBB + (k+1+idx)];
  }
  __syncthreads();
  int buf = 0;
  for (int k = NBB-3; k >= 0; --k) {
    float pf0 = 0.f, pf1 = 0.f;
    const int m2 = NBB - k;
    if (k > 0) {
      const float* Arow = A + (size_t)(k-1)*NBB + k;
      if (tid < m2) pf0 = Arow[tid];
      if (tid + 512 < m2) pf1 = Arow[tid + 512];
    }
    const float tau = tauA[n*NBB + k];
    if (tau != 0.f) {
      float part = 0.f;
      #pragma unroll
      for (int rr = 0; rr < RPT; ++rr) {
        const int r = rbase + rr;
        if (r > k) part += U[rr]*vlds[buf][r-k-1];
      }
      sred[g*32 + jc] = part;
      __syncthreads();
      float ssum = 0.f;
      #pragma unroll
      for (int t = 0; t < 16; ++t) ssum += sred[t*32 + jc];
      const float s = tau*ssum;
      #pragma unroll
      for (int rr = 0; rr < RPT; ++rr) {
        const int r = rbase + rr;
        if (r > k) U[rr] -= s*vlds[buf][r-k-1];
      }
    }
    if (k > 0) {
      if (tid < m2) vlds[buf^1][tid] = pf0;
      if (tid + 512 < m2) vlds[buf^1][tid + 512] = pf1;
    }
    __syncthreads();
    buf ^= 1;
  }
  float* Ub = Uocc + (size_t)n*NBB*NOCC2;
  #pragma unroll
  for (int rr = 0; rr < RPT; ++rr) Ub[(size_t)(rbase+rr)*NOCC2 + col] = U[rr];
}

// ---------------- C = h_new * Uocc  (832x832 @ 832x128 per batch) ----------------
__global__ __launch_bounds__(256) void k_gemmC(const float* __restrict__ h,
                                               const float* __restrict__ Uocc,
                                               float* __restrict__ C) {
  const int rt = blockIdx.x, n = blockIdx.y;
  const int tid = threadIdx.x;
  __shared__ __align__(16) float hT[64*33];
  __shared__ __align__(16) float Ut[32*128];
  const int ty = tid >> 5, tx = tid & 31;
  float acc[8][4] = {};
  const float* hb = h + (size_t)n*NBB*NBB + (size_t)rt*64*NBB;
  const float* Ub = Uocc + (size_t)n*NBB*NOCC2;
  for (int k0 = 0; k0 < NBB; k0 += 32) {
    for (int idx = tid; idx < 64*32; idx += 256) {
      const int r = idx >> 5, c = idx & 31;
      hT[r*33 + c] = hb[(size_t)r*NBB + k0 + c];
    }
    for (int idx = tid; idx < 32*128; idx += 256) {
      const int r = idx >> 7, c = idx & 127;
      Ut[idx] = Ub[(size_t)(k0 + r)*NOCC2 + c];
    }
    __syncthreads();
    for (int kk = 0; kk < 32; ++kk) {
      const float4 b4 = *(const float4*)&Ut[kk*128 + tx*4];
      #pragma unroll
      for (int q = 0; q < 8; ++q) {
        const float a = hT[(ty*8 + q)*33 + kk];
        acc[q][0] += a*b4.x; acc[q][1] += a*b4.y; acc[q][2] += a*b4.z; acc[q][3] += a*b4.w;
      }
    }
    __syncthreads();
  }
  float* Cb = C + (size_t)n*NBB*NOCC2;
  #pragma unroll
  for (int q = 0; q < 8; ++q)
    #pragma unroll
    for (int p = 0; p < 4; ++p)
      Cb[(size_t)(rt*64 + ty*8 + q)*NOCC2 + tx*4 + p] = acc[q][p];
}

// ---------------- E = sum(e_occ) + Tr(Uocc^T h Uocc) + nuc ----------------
__global__ __launch_bounds__(256) void k_final(const float* __restrict__ eig,
                                               const float* __restrict__ Uocc, const float* __restrict__ C,
                                               const float* __restrict__ pos, const int* __restrict__ numbers,
                                               float* __restrict__ E_out) {
  const int n = blockIdx.x, tid = threadIdx.x;
  __shared__ float rb[256];
  float local = 0.f;
  for (int i = tid; i < NOCC2; i += 256) local += eig[n*NBB + i];
  const float* Ub = Uocc + (size_t)n*NBB*NOCC2;
  const float* Cb = C + (size_t)n*NBB*NOCC2;
  for (int idx = tid; idx < NBB*NOCC2; idx += 256) local += Ub[idx]*Cb[idx];
  float ln = 0.f;
  for (int t = tid; t < NPAIR; t += 256) {
    int kk, ll;
    pair_decode(t, kk, ll);
    const float dx = pos[(n*NK + kk)*3 + 0] - pos[(n*NK + ll)*3 + 0];
    const float dy = pos[(n*NK + kk)*3 + 1] - pos[(n*NK + ll)*3 + 1];
    const float dz = pos[(n*NK + kk)*3 + 2] - pos[(n*NK + ll)*3 + 2];
    const float d2 = dx*dx + dy*dy + dz*dz;
    const float Z = (float)(numbers[kk]*numbers[ll]);
    ln += Z / sqrtf(d2);
  }
  local += ln * A0C;
  rb[tid] = local;
  __syncthreads();
  for (int s = 128; s > 0; s >>= 1) {
    if (tid < s) rb[tid] += rb[tid + s];
    __syncthreads();
  }
  if (tid == 0) E_out[n] = rb[0];
}

extern "C" void kernel_launch(void* const* d_in, const int* in_sizes, int n_in,
                              void* d_out, int out_size, void* d_ws, size_t ws_size,
                              hipStream_t stream) {
  (void)in_sizes; (void)n_in; (void)out_size; (void)ws_size;
  const float* mu      = (const float*)d_in[0];
  const float* hnew    = (const float*)d_in[1];
  const float* pos     = (const float*)d_in[2];
  const float* Foff    = (const float*)d_in[3];
  const float* tW      = (const float*)d_in[4];
  const float* tb      = (const float*)d_in[5];
  const float* Won     = (const float*)d_in[6];
  const float* bon     = (const float*)d_in[7];
  const float* Woff    = (const float*)d_in[8];
  const float* boff    = (const float*)d_in[9];
  const int*   numbers = (const int*)d_in[10];

  float* out   = (float*)d_out;
  float* Fout  = out;                               // [16][832][832]
  float* e_out = out + (size_t)NBATCH*NBB*NBB;      // [16][832]
  float* E_out = e_out + (size_t)NBATCH*NBB;        // [16]

  float* ws    = (float*)d_ws;
  float* Acopy = ws + OFF_ACOPY;
  float* xbuf  = ws + OFF_X;
  float* Sbuf  = ws + OFF_S;
  float* dA    = ws + OFF_D;
  float* subA  = ws + OFF_SUB;
  float* tauA  = ws + OFF_TAU;
  float* eig   = ws + OFF_EIG;
  float* Utri  = ws + OFF_UTRI;
  float* Uocc  = ws + OFF_UOCC;
  float* Cbuf  = ws + OFF_C;     // overlays Utri
  float* ybufA = ws + OFF_YBUF;  // overlays Utri (dead until k_invit)
  int*   barA  = (int*)(ws + OFF_BARC);

  // zero the per-matrix barrier counters (graph-captured; runs every replay)
  hipMemsetAsync((void*)barA, 0, NBATCH*sizeof(int), stream);

  k_x<<<dim3(NK, NBATCH), dim3(256), 0, stream>>>(mu, tW, tb, xbuf);
  k_S<<<dim3(NBATCH), dim3(256), 0, stream>>>(xbuf, Sbuf);
  k_diag<<<dim3(NK, NBATCH), dim3(256), 0, stream>>>(xbuf, Sbuf, Won, bon, hnew, Foff, Fout, Acopy);
  k_off<<<dim3(6, 16, NBATCH), dim3(256), 0, stream>>>(xbuf, Woff, boff, hnew, Foff, Fout, Acopy);
  k_tridiag_fused<<<dim3(GW, NBATCH), dim3(TPW), 0, stream>>>(Acopy, dA, subA, tauA, ybufA, barA);
  k_bisect<<<dim3(4, NBATCH), dim3(256), 0, stream>>>(dA, subA, eig, e_out);
  k_invit<<<dim3(NOCC2, NBATCH), dim3(64), 0, stream>>>(dA, subA, eig, Utri);
  k_backxform<<<dim3(4, NBATCH), dim3(512), 0, stream>>>(Acopy, tauA, Utri, Uocc);
  k_gemmC<<<dim3(13, NBATCH), dim3(256), 0, stream>>>(hnew, Uocc, Cbuf);
  k_final<<<dim3(NBATCH), dim3(256), 0, stream>>>(eig, Uocc, Cbuf, pos, numbers, E_out);
}

// Round 16
// 20469.371 us; speedup vs baseline: 3.8191x; 1.3176x over previous
//
#include <hip/hip_runtime.h>
#include <math.h>
#include <stdint.h>

// Problem constants
#define NBATCH 16
#define NK     32
#define NTDS   768      // 3*DS
#define NMM    676      // BM*BM
#define NBM    26
#define NBB    832      // B = K*BM
#define NOCC2  128
#define NPAIR  496      // K*(K-1)/2
#define FSCALE 1.0e-4f
#define A0C    0.5291772f

// ---------------- workspace layout (in floats) ----------------
#define OFF_ACOPY 0ull
#define SZ_ACOPY  (16ull*832*832)
#define OFF_X     (OFF_ACOPY + SZ_ACOPY)
#define SZ_X      (16ull*32*768)
#define OFF_S     (OFF_X + SZ_X)
#define SZ_S      (16ull*768)
#define OFF_D     (OFF_S + SZ_S)
#define OFF_SUB   (OFF_D   + 16ull*832)
#define OFF_TAU   (OFF_SUB + 16ull*832)
#define OFF_EIG   (OFF_TAU + 16ull*832)
#define OFF_UTRI  (OFF_EIG + 16ull*832)
#define SZ_UTRI   (16ull*128*832)
#define OFF_UOCC  (OFF_UTRI + SZ_UTRI)
#define OFF_C     OFF_UTRI   /* C overlays Utri (dead after backxform) */
// tridiag scratch overlays the Utri region (Utri written only later by k_invit)
#define PB   16   // panel width (full V/W panels LDS-resident in every WG)
#define GW   4    // workgroups per matrix
#define GWL2 2
#define TPW  1024 // threads per workgroup
#define NWV  16   // waves per WG
#define QMAX 208  // max own rows per WG (832/4)
#define OFF_YBUF  OFF_UTRI                        /* 16*832 floats (y exchange) */
#define OFF_BARC  (OFF_YBUF + 16ull*832)          /* 16 ints */

__device__ __forceinline__ void pair_decode(int t, int& k, int& l) {
  int kk = (int)((1.0f + sqrtf(1.0f + 8.0f*(float)t)) * 0.5f);
  while (kk*(kk-1)/2 > t) --kk;
  while ((kk+1)*kk/2 <= t) ++kk;
  k = kk; l = t - kk*(kk-1)/2;
}

// Cross-WG READ: agent-scope bypass load (sc0 sc1) — reads through to the MALL.
__device__ __forceinline__ float gld(const float* p) {
  unsigned int u = __hip_atomic_load((const unsigned int*)p, __ATOMIC_RELAXED, __HIP_MEMORY_SCOPE_AGENT);
  return __uint_as_float(u);
}
// Cross-WG WRITE: agent-scope bypass store (sc0 sc1) — write-through to MALL.
__device__ __forceinline__ void gst(float* p, float v) {
  __hip_atomic_store((unsigned int*)p, __float_as_uint(v), __ATOMIC_RELAXED, __HIP_MEMORY_SCOPE_AGENT);
}

// ---------------- x = mu @ transfer_W + b ----------------
__global__ __launch_bounds__(256) void k_x(const float* __restrict__ mu,
                                           const float* __restrict__ tW,
                                           const float* __restrict__ tb,
                                           float* __restrict__ x) {
  const int k = blockIdx.x, n = blockIdx.y, tid = threadIdx.x;
  __shared__ float mus[384];
  const float* mub = mu + (size_t)(n*NK + k)*384;
  for (int i = tid; i < 384; i += 256) mus[i] = mub[i];
  __syncthreads();
  float* xb = x + (size_t)(n*NK + k)*NTDS;
  for (int oo = tid; oo < NTDS; oo += 256) {
    const int d = oo >> 8, i = oo & 255;
    float acc = tb[i];
    const float* mrow = &mus[d*128];
    for (int a = 0; a < 128; ++a) acc += mrow[a]*tW[a*256 + i];
    xb[oo] = acc;
  }
}

// ---------------- S[n][dd] = sum_k x[n][k][dd] ----------------
__global__ __launch_bounds__(256) void k_S(const float* __restrict__ x, float* __restrict__ S) {
  const int n = blockIdx.x, tid = threadIdx.x;
  for (int dd = tid; dd < NTDS; dd += 256) {
    float s = 0.f;
    for (int k = 0; k < NK; ++k) s += x[(size_t)(n*NK + k)*NTDS + dd];
    S[n*NTDS + dd] = s;
  }
}

// ---------------- diagonal blocks ----------------
__global__ __launch_bounds__(256) void k_diag(const float* __restrict__ x, const float* __restrict__ S,
                                              const float* __restrict__ Won, const float* __restrict__ bon,
                                              const float* __restrict__ hnew, const float* __restrict__ Foff,
                                              float* __restrict__ Fout, float* __restrict__ Acopy) {
  const int k = blockIdx.x, n = blockIdx.y, tid = threadIdx.x;
  __shared__ float q[NTDS];
  __shared__ float M[NMM];
  const float* xb = x + (size_t)(n*NK + k)*NTDS;
  const float* Sb = S + n*NTDS;
  for (int i = tid; i < NTDS; i += 256) q[i] = xb[i]*Sb[i];
  __syncthreads();
  for (int m = tid; m < NMM; m += 256) {
    float acc = 32.0f * bon[m];
    for (int dd = 0; dd < NTDS; ++dd) acc += q[dd]*Won[(size_t)dd*NMM + m];
    M[m] = acc;
  }
  __syncthreads();
  const float* hb = hnew + (size_t)n*NBB*NBB;
  float* Fb = Fout + (size_t)n*NBB*NBB;
  float* Ab = Acopy + (size_t)n*NBB*NBB;
  for (int m = tid; m < NMM; m += 256) {
    const int a = m/26, b = m - a*26;
    const float val = 0.5f*(M[m] + M[b*26 + a]);
    const int P = k*26 + a, Q = k*26 + b;
    const size_t idx = (size_t)P*NBB + Q;
    const float fo = Foff[idx];
    const float hv = hb[idx];
    const float Fv = (fabsf(hv) > 1e-7f) ? (val*FSCALE + fo) : fo;
    Fb[idx] = Fv; Ab[idx] = Fv;
  }
}

// ---------------- off-diagonal blocks: GEMM over pairs ----------------
__global__ __launch_bounds__(256) void k_off(const float* __restrict__ x,
                                             const float* __restrict__ Woff, const float* __restrict__ boff,
                                             const float* __restrict__ hnew, const float* __restrict__ Foff,
                                             float* __restrict__ Fout, float* __restrict__ Acopy) {
  const int ct = blockIdx.x, pt = blockIdx.y, n = blockIdx.z;
  const int tid = threadIdx.x;
  __shared__ __align__(16) float At[32*65];
  __shared__ __align__(16) float Bt[64*128];
  __shared__ int klk[32], kll[32];
  if (tid < 32) {
    int pr = pt*32 + tid, kk = 1, ll = 0;
    if (pr < NPAIR) pair_decode(pr, kk, ll);
    klk[tid] = kk; kll[tid] = ll;
  }
  __syncthreads();
  const int ty = tid >> 5, tx = tid & 31;
  const int r0 = ty*4, c0 = tx*4;
  float acc[4][4] = {};
  for (int dd0 = 0; dd0 < NTDS; dd0 += 64) {
    for (int idx = tid; idx < 2048; idx += 256) {
      const int r = idx >> 6, c = idx & 63;
      const int pr = pt*32 + r;
      float v = 0.f;
      if (pr < NPAIR) {
        const int kk = klk[r], ll = kll[r];
        v = x[(size_t)(n*NK + kk)*NTDS + dd0 + c] * x[(size_t)(n*NK + ll)*NTDS + dd0 + c];
      }
      At[r*65 + c] = v;
    }
    for (int idx = tid; idx < 8192; idx += 256) {
      const int r = idx >> 7, c = idx & 127;
      const int col = ct*128 + c;
      Bt[idx] = (col < NMM) ? Woff[(size_t)(dd0 + r)*NMM + col] : 0.f;
    }
    __syncthreads();
    for (int kk = 0; kk < 64; ++kk) {
      float av[4];
      av[0] = At[(r0+0)*65 + kk];
      av[1] = At[(r0+1)*65 + kk];
      av[2] = At[(r0+2)*65 + kk];
      av[3] = At[(r0+3)*65 + kk];
      const float4 b4 = *(const float4*)&Bt[kk*128 + c0];
      const float bb[4] = {b4.x, b4.y, b4.z, b4.w};
      #pragma unroll
      for (int qq = 0; qq < 4; ++qq)
        #pragma unroll
        for (int pp = 0; pp < 4; ++pp)
          acc[qq][pp] += av[qq]*bb[pp];
    }
    __syncthreads();
  }
  const float* hb = hnew + (size_t)n*NBB*NBB;
  float* Fb = Fout + (size_t)n*NBB*NBB;
  float* Ab = Acopy + (size_t)n*NBB*NBB;
  for (int qq = 0; qq < 4; ++qq) {
    const int pr = pt*32 + r0 + qq;
    if (pr >= NPAIR) continue;
    const int kk = klk[r0+qq], ll = kll[r0+qq];
    for (int pp = 0; pp < 4; ++pp) {
      const int m = ct*128 + c0 + pp;
      if (m >= NMM) continue;
      const float val = acc[qq][pp] + boff[m];
      const int a = m/26, b = m - a*26;
      const int P = kk*26 + a, Q = ll*26 + b;
      const size_t i1 = (size_t)P*NBB + Q;
      const float fo1 = Foff[i1], hv1 = hb[i1];
      const float Fv1 = (fabsf(hv1) > 1e-7f) ? (val*FSCALE + fo1) : fo1;
      Fb[i1] = Fv1; Ab[i1] = Fv1;
      const size_t i2 = (size_t)Q*NBB + P;
      const float fo2 = Foff[i2], hv2 = hb[i2];
      const float Fv2 = (fabsf(hv2) > 1e-7f) ? (val*FSCALE + fo2) : fo2;
      Fb[i2] = Fv2; Ab[i2] = Fv2;
    }
  }
}

// ================= fused single-barrier latrd tridiagonalization =================
// R16 (on the R15 fused structure, 881 epochs):
//   * c(k) read as SYMMETRIC ROW k (trailing matrix kept symmetric by the
//     full-row syr2k) -> coalesced; ISSUED AT EPOCH START so its MALL latency
//     hides under complete_prev (row k is stale-by-design within a panel).
//   * complete_prev dots wave-parallelized: wave 0 -> vav, wave p -> d1/d2[p-1]
//     (6 shfls/wave instead of 186/thread; cost scales with actual iprev).
// Coherence: R7-proven primitives; determinism: dsum computed identically
// (same order) in every WG.
__device__ __forceinline__ void rbar(int* cnt, int target) {
  __syncthreads();
  if (threadIdx.x == 0) {
    asm volatile("" ::: "memory");
    __hip_atomic_fetch_add(cnt, 1, __ATOMIC_RELAXED, __HIP_MEMORY_SCOPE_AGENT);
    while (__hip_atomic_load(cnt, __ATOMIC_RELAXED, __HIP_MEMORY_SCOPE_AGENT) < target)
      __builtin_amdgcn_s_sleep(1);
    asm volatile("" ::: "memory");
  }
  __syncthreads();
}
__device__ __forceinline__ void gbar(int* cnt, int target) {
  __syncthreads();
  if (threadIdx.x == 0) {
    __hip_atomic_fetch_add(cnt, 1, __ATOMIC_RELEASE, __HIP_MEMORY_SCOPE_AGENT);  // wbl2
    while (__hip_atomic_load(cnt, __ATOMIC_RELAXED, __HIP_MEMORY_SCOPE_AGENT) < target)
      __builtin_amdgcn_s_sleep(1);
  }
  __syncthreads();
}

__device__ __forceinline__ float wg_reduce16(float v, volatile float* sred) {
  #pragma unroll
  for (int off = 32; off > 0; off >>= 1) v += __shfl_down(v, off);
  const int tid = threadIdx.x;
  if ((tid & 63) == 0) sred[tid >> 6] = v;
  __syncthreads();
  float r = 0.f;
  #pragma unroll
  for (int t = 0; t < NWV; ++t) r += sred[t];
  __syncthreads();
  return r;
}

__global__ __launch_bounds__(TPW) void k_tridiag_fused(float* __restrict__ Acopy,
                                                       float* __restrict__ dA,
                                                       float* __restrict__ subA,
                                                       float* __restrict__ tauA,
                                                       float* __restrict__ ybufA,
                                                       int* __restrict__ barA) {
  const int g = blockIdx.x;          // WG within matrix (0..GW-1)
  const int n = blockIdx.y;          // matrix
  const int tid = threadIdx.x;
  const int lane = tid & 63, wv = tid >> 6;
  float* A    = Acopy + (size_t)n*NBB*NBB;
  float* ybuf = ybufA + (size_t)n*NBB;
  int*   cnt  = barA + n;

  __shared__ float Vf[NBB*(PB+1)];   // [j][p], stride 17 (full panel, redundant)
  __shared__ float Wf[NBB*(PB+1)];
  __shared__ float vsh[NBB];
  __shared__ __align__(16) float vsh4[NBB];
  __shared__ float csh[NBB];
  __shared__ float ysh[NBB];
  __shared__ float dsum[32];         // [0]=vav, [1+p]=d1[p], [16+p]=d2[p]
  __shared__ float sred[NWV];
  __shared__ float taus[PB];
  int ep = 0;

  // complete column kprev (compute w(kprev), store into Vf/Wf col iprev)
  auto complete_prev = [&](int kprev, int iprev) {
    { int j = kprev+1+tid; if (j < NBB) ysh[j] = gld(&ybuf[j]); }
    __syncthreads();
    // wave-parallel dots: wave 0 -> vav; wave w in [1..iprev] -> d1/d2[w-1]
    if (wv == 0) {
      float pv = 0.f;
      for (int j = kprev+1+lane; j < NBB; j += 64) pv += vsh[j]*ysh[j];
      #pragma unroll
      for (int off = 32; off > 0; off >>= 1) pv += __shfl_down(pv, off);
      if (lane == 0) dsum[0] = pv;
    } else if (wv <= iprev) {
      const int p = wv - 1;
      float a1 = 0.f, a2 = 0.f;
      for (int j = kprev+1+lane; j < NBB; j += 64) {
        const float vj = vsh[j];
        a1 += Vf[j*(PB+1)+p]*vj;
        a2 += Wf[j*(PB+1)+p]*vj;
      }
      #pragma unroll
      for (int off = 32; off > 0; off >>= 1) { a1 += __shfl_down(a1, off); a2 += __shfl_down(a2, off); }
      if (lane == 0) { dsum[1+p] = a1; dsum[16+p] = a2; }
    }
    __syncthreads();
    const float tau = taus[iprev];
    float s12 = 0.f;
    for (int p = 0; p < iprev; ++p) s12 += dsum[1+p]*dsum[16+p];
    const float corr = 0.5f*tau*tau*(dsum[0] - 2.f*s12);
    { int j = kprev+1+tid;
      if (j < NBB) {
        float wacc = 0.f;
        #pragma unroll
        for (int p = 0; p < PB-1; ++p) if (p < iprev)
          wacc += Vf[j*(PB+1)+p]*dsum[16+p] + Wf[j*(PB+1)+p]*dsum[1+p];
        const float wj = tau*(ysh[j] - wacc) - corr*vsh[j];
        Wf[j*(PB+1)+iprev] = wj;
        Vf[j*(PB+1)+iprev] = vsh[j];
      }
    }
    __syncthreads();
  };

  for (int k0 = 0; k0 < NBB-2; k0 += PB) {
    const int ilim = (NBB-2-k0 < PB) ? (NBB-2-k0) : PB;
    for (int i = 0; i < ilim; ++i) {
      const int k = k0 + i;
      // early-issue raw c(k): SYMMETRIC row-k read (coalesced); row k is
      // stable within the panel, so issue before complete_prev to hide latency
      float craw = 0.f;
      { int j = k + tid; if (j < NBB) craw = gld(&A[(size_t)k*NBB + j]); }

      if (i > 0) complete_prev(k-1, i-1);

      // ---- c(k) = raw - panel corrections (redundant, rows j >= k) ----
      { int j = k + tid;
        if (j < NBB) {
          float cacc = 0.f;
          #pragma unroll
          for (int p = 0; p < PB; ++p) if (p < i)
            cacc += Vf[j*(PB+1)+p]*Wf[k*(PB+1)+p] + Wf[j*(PB+1)+p]*Vf[k*(PB+1)+p];
          csh[j] = craw - cacc;
        }
      }
      __syncthreads();
      // ---- norm/alpha/tau (redundant; bitwise identical across WGs) ----
      float np2 = 0.f;
      { int j2 = k+2+tid; if (j2 < NBB) { const float c = csh[j2]; np2 = c*c; } }
      const float nrm = wg_reduce16(np2, sred);
      const float alpha = csh[k+1];
      float tau, scale, beta;
      if (nrm < 1e-26f) { beta = alpha; tau = 0.f; scale = 0.f; }
      else {
        beta  = -copysignf(sqrtf(alpha*alpha + nrm), alpha);
        tau   = (beta - alpha) / beta;
        scale = 1.0f / (alpha - beta);
      }
      if (tid == 0) taus[i] = tau;
      if (g == 0 && tid == 0) {
        subA[n*NBB + k + 1] = beta;
        tauA[n*NBB + k] = tau;
        dA[n*NBB + k] = csh[k];
      }
      // ---- v(k) ----
      { int j3 = k+1+tid;
        if (j3 < NBB) {
          const float val = (j3 == k+1) ? 1.0f : csh[j3]*scale;
          vsh[j3] = val; vsh4[j3] = val;
        }
      }
      __syncthreads();
      // reflector publish (row k, BYPASS) by owner WG
      if (g == (k & (GW-1))) {
        int j4 = k+1+tid;
        if (j4 < NBB) gst(&A[(size_t)k*NBB + j4], vsh[j4]);
      }
      // ---- distributed matvec y(k) over OWN rows; publish via gst ----
      {
        const int cs = k+1;
        const int nh = (4 - (cs & 3)) & 3;
        const int ca = cs + nh;
        const int q0 = (k + GW - g) >> GWL2;
        for (int q = q0 + wv; q < QMAX; q += NWV) {
          const int jr = GW*q + g;
          const float* Ar = A + (size_t)jr*NBB;
          float acc = 0.f;
          if (lane < nh) acc += Ar[cs+lane]*vsh[cs+lane];
          for (int c = ca + 4*lane; c < NBB; c += 256) {
            const float4 a4 = *(const float4*)&Ar[c];
            const float4 v4 = *(const float4*)&vsh4[c];
            acc += a4.x*v4.x + a4.y*v4.y + a4.z*v4.z + a4.w*v4.w;
          }
          #pragma unroll
          for (int off = 32; off > 0; off >>= 1) acc += __shfl_down(acc, off);
          if (lane == 0) gst(&ybuf[jr], acc);
        }
      }
      ++ep; rbar(cnt, ep*GW);
    }

    // ---- panel boundary: finish last w, then syr2k (own rows, cached) ----
    if (k0 + PB < NBB-2) {
      const int kp = k0 + PB;
      complete_prev(kp-1, PB-1);
      const int q0s = (kp + GW-1 - g) >> GWL2;
      for (int q = q0s + wv; q < QMAX; q += NWV) {
        const int jr = GW*q + g;
        float vr[PB], wr[PB];
        #pragma unroll
        for (int p = 0; p < PB; ++p) { vr[p] = Vf[jr*(PB+1)+p]; wr[p] = Wf[jr*(PB+1)+p]; }
        for (int c = kp + lane; c < NBB; c += 64) {
          float acc = 0.f;
          #pragma unroll
          for (int p = 0; p < PB; ++p)
            acc += vr[p]*Wf[c*(PB+1)+p] + wr[p]*Vf[c*(PB+1)+p];
          A[(size_t)jr*NBB + c] -= acc;   // own row, cached (cleaned by gbar)
        }
      }
      ++ep; gbar(cnt, ep*GW);   // RELEASE: clean syr2k dirt before next panel's glds
    }
  }

  // ---- final: complete w(NBB-3), epilogue diagonals ----
  {
    const int k0l = ((NBB-3)/PB)*PB;
    const int npl = NBB-2-k0l;           // last-panel column count
    complete_prev(NBB-3, npl-1);
    if (g == 0 && tid == 0) {
      const int r2 = NBB-2, r1 = NBB-1;
      float dm2 = gld(&A[(size_t)r2*NBB + r2]);
      float dm1 = gld(&A[(size_t)r1*NBB + r1]);
      float sb  = gld(&A[(size_t)r1*NBB + r2]);
      for (int p = 0; p < npl; ++p) {
        dm2 -= 2.f*Vf[r2*(PB+1)+p]*Wf[r2*(PB+1)+p];
        dm1 -= 2.f*Vf[r1*(PB+1)+p]*Wf[r1*(PB+1)+p];
        sb  -= Vf[r1*(PB+1)+p]*Wf[r2*(PB+1)+p] + Wf[r1*(PB+1)+p]*Vf[r2*(PB+1)+p];
      }
      dA[n*NBB + r2] = dm2;
      dA[n*NBB + r1] = dm1;
      subA[n*NBB + r1] = sb;
      subA[n*NBB + 0] = 0.f;
      tauA[n*NBB + r2] = 0.f;
      tauA[n*NBB + r1] = 0.f;
    }
  }
}

// ---------------- all eigenvalues via bisection (Sturm counts) ----------------
__global__ __launch_bounds__(256) void k_bisect(const float* __restrict__ dA, const float* __restrict__ subA,
                                                float* __restrict__ eig, float* __restrict__ e_out) {
  const int n = blockIdx.y;
  const int i = blockIdx.x*256 + threadIdx.x;
  __shared__ float ds[NBB], ss[NBB];
  const float* dg = dA + n*NBB;
  const float* sg = subA + n*NBB;
  for (int j = threadIdx.x; j < NBB; j += 256) { ds[j] = dg[j]; ss[j] = sg[j]; }
  __syncthreads();
  if (i >= NBB) return;
  float lo = 1e30f, hi = -1e30f;
  for (int j = 0; j < NBB; ++j) {
    const float r = fabsf(ss[j]) + ((j+1 < NBB) ? fabsf(ss[j+1]) : 0.f);
    lo = fminf(lo, ds[j]-r); hi = fmaxf(hi, ds[j]+r);
  }
  const float pad = 1e-3f*(hi-lo) + 1e-3f;
  lo -= pad; hi += pad;
  for (int it = 0; it < 30; ++it) {
    const float mid = 0.5f*(lo+hi);
    int cnt = 0;
    float qv = ds[0]-mid;
    if (qv < 0.f) cnt++;
    for (int j = 1; j < NBB; ++j) {
      const float e = ss[j];
      if (fabsf(qv) < 1e-20f) qv = -1e-20f;
      qv = ds[j]-mid - e*e/qv;
      if (qv < 0.f) cnt++;
    }
    if (cnt > i) hi = mid; else lo = mid;
  }
  const float lam = 0.5f*(lo+hi);
  eig[n*NBB + i] = lam;
  e_out[n*NBB + i] = lam;
}

// ---------------- inverse iteration on T for the 128 lowest ----------------
__global__ __launch_bounds__(64) void k_invit(const float* __restrict__ dA, const float* __restrict__ subA,
                                              const float* __restrict__ eig, float* __restrict__ Utri) {
  const int i = blockIdx.x, n = blockIdx.y;
  const int lane = threadIdx.x;
  __shared__ float ds[NBB], ss[NBB], ud[NBB], u1[NBB], u2[NBB], yv[NBB], xv[NBB];
  const float* dg = dA + n*NBB;
  const float* sg = subA + n*NBB;
  for (int j = lane; j < NBB; j += 64) { ds[j] = dg[j]; ss[j] = sg[j]; }
  const float lam = eig[n*NBB + i];
  for (int j = lane; j < NBB; j += 64) {
    uint32_t s = (uint32_t)(j*2654435761u) ^ (uint32_t)(i*40503u + 977u) ^ (uint32_t)(n*9973u);
    s ^= s >> 16; s *= 0x7feb352dU; s ^= s >> 15; s *= 0x846ca68bU; s ^= s >> 16;
    yv[j] = 0.5f + (float)(s & 0xFFFF) * (1.0f/65536.0f);
  }
  __syncthreads();
  const float PIV = 3e-6f;
  for (int pass = 0; pass < 2; ++pass) {
    if (lane == 0) {
      float cd = ds[0] - lam;
      float cu = ss[1];
      float cy = yv[0];
      for (int j = 0; j < NBB-1; ++j) {
        const float bl = ss[j+1];
        const float bd = ds[j+1] - lam;
        const float bu = (j+2 < NBB) ? ss[j+2] : 0.f;
        const float yb = yv[j+1];
        float tud, tu1, tu2, tm, ncd, ncu, ny;
        if (fabsf(bl) > fabsf(cd)) {
          tud = bl; tu1 = bd; tu2 = bu;
          if (fabsf(tud) < PIV) tud = (tud < 0.f) ? -PIV : PIV;
          tm  = cd / tud;
          ncd = cu - tm*bd;
          ncu = -tm*bu;
          ny  = cy - tm*yb;
          yv[j] = yb;
        } else {
          tud = cd; tu1 = cu; tu2 = 0.f;
          if (fabsf(tud) < PIV) tud = (tud < 0.f) ? -PIV : PIV;
          tm  = bl / tud;
          ncd = bd - tm*cu;
          ncu = bu;
          ny  = yb - tm*cy;
          yv[j] = cy;
        }
        ud[j] = tud; u1[j] = tu1; u2[j] = tu2;
        cd = ncd; cu = ncu; cy = ny;
      }
      if (fabsf(cd) < PIV) cd = (cd < 0.f) ? -PIV : PIV;
      ud[NBB-1] = cd; u1[NBB-1] = 0.f; u2[NBB-1] = 0.f; yv[NBB-1] = cy;
      float x2 = yv[NBB-1]/ud[NBB-1];
      xv[NBB-1] = x2;
      float x1 = (yv[NBB-2] - u1[NBB-2]*x2)/ud[NBB-2];
      xv[NBB-2] = x1;
      for (int j = NBB-3; j >= 0; --j) {
        const float xj = (yv[j] - u1[j]*x1 - u2[j]*x2)/ud[j];
        xv[j] = xj;
        x2 = x1; x1 = xj;
      }
    }
    __syncthreads();
    float p2 = 0.f;
    for (int j = lane; j < NBB; j += 64) { const float t = xv[j]; p2 += t*t; }
    #pragma unroll
    for (int off = 32; off > 0; off >>= 1) p2 += __shfl_xor(p2, off);
    const float rin = rsqrtf(p2);
    if (pass == 0) {
      for (int j = lane; j < NBB; j += 64) yv[j] = xv[j]*rin;
      __syncthreads();
    } else {
      float* Ub = Utri + ((size_t)n*NOCC2 + i)*NBB;
      for (int j = lane; j < NBB; j += 64) Ub[j] = xv[j]*rin;
    }
  }
}

// ---------------- back-transform: Uocc = H0...H829 * Utri ----------------
#define RPT 52
__global__ __launch_bounds__(512) void k_backxform(const float* __restrict__ Acopy,
                                                   const float* __restrict__ tauA,
                                                   const float* __restrict__ Utri,
                                                   float* __restrict__ Uocc) {
  const int cg = blockIdx.x;         // column quarter (0..3)
  const int n = blockIdx.y;
  const int tid = threadIdx.x;
  const int jc = tid & 31, g = tid >> 5;   // 16 row-groups x 52 rows
  const int col = cg*32 + jc;
  __shared__ float vlds[2][NBB];
  __shared__ float sred[16*32];
  const float* A = Acopy + (size_t)n*NBB*NBB;
  float U[RPT];
  const float* Ut = Utri + ((size_t)n*NOCC2 + col)*NBB + g*RPT;
  #pragma unroll
  for (int rr = 0; rr < RPT; ++rr) U[rr] = Ut[rr];
  const int rbase = g*RPT;
  {
    const int k = NBB-3, mm = NBB-1-k;
    for (int idx = tid; idx < mm; idx += 512) vlds[0][idx] = A[(size_t)k*NBB + (k+1+idx)];
  }
  __syncthreads();
  int buf = 0;
  for (int k = NBB-3; k >= 0; --k) {
    float pf0 = 0.f, pf1 = 0.f;
    const int m2 = NBB - k;
    if (k > 0) {
      const float* Arow = A + (size_t)(k-1)*NBB + k;
      if (tid < m2) pf0 = Arow[tid];
      if (tid + 512 < m2) pf1 = Arow[tid + 512];
    }
    const float tau = tauA[n*NBB + k];
    if (tau != 0.f) {
      float part = 0.f;
      #pragma unroll
      for (int rr = 0; rr < RPT; ++rr) {
        const int r = rbase + rr;
        if (r > k) part += U[rr]*vlds[buf][r-k-1];
      }
      sred[g*32 + jc] = part;
      __syncthreads();
      float ssum = 0.f;
      #pragma unroll
      for (int t = 0; t < 16; ++t) ssum += sred[t*32 + jc];
      const float s = tau*ssum;
      #pragma unroll
      for (int rr = 0; rr < RPT; ++rr) {
        const int r = rbase + rr;
        if (r > k) U[rr] -= s*vlds[buf][r-k-1];
      }
    }
    if (k > 0) {
      if (tid < m2) vlds[buf^1][tid] = pf0;
      if (tid + 512 < m2) vlds[buf^1][tid + 512] = pf1;
    }
    __syncthreads();
    buf ^= 1;
  }
  float* Ub = Uocc + (size_t)n*NBB*NOCC2;
  #pragma unroll
  for (int rr = 0; rr < RPT; ++rr) Ub[(size_t)(rbase+rr)*NOCC2 + col] = U[rr];
}

// ---------------- C = h_new * Uocc  (832x832 @ 832x128 per batch) ----------------
__global__ __launch_bounds__(256) void k_gemmC(const float* __restrict__ h,
                                               const float* __restrict__ Uocc,
                                               float* __restrict__ C) {
  const int rt = blockIdx.x, n = blockIdx.y;
  const int tid = threadIdx.x;
  __shared__ __align__(16) float hT[64*33];
  __shared__ __align__(16) float Ut[32*128];
  const int ty = tid >> 5, tx = tid & 31;
  float acc[8][4] = {};
  const float* hb = h + (size_t)n*NBB*NBB + (size_t)rt*64*NBB;
  const float* Ub = Uocc + (size_t)n*NBB*NOCC2;
  for (int k0 = 0; k0 < NBB; k0 += 32) {
    for (int idx = tid; idx < 64*32; idx += 256) {
      const int r = idx >> 5, c = idx & 31;
      hT[r*33 + c] = hb[(size_t)r*NBB + k0 + c];
    }
    for (int idx = tid; idx < 32*128; idx += 256) {
      const int r = idx >> 7, c = idx & 127;
      Ut[idx] = Ub[(size_t)(k0 + r)*NOCC2 + c];
    }
    __syncthreads();
    for (int kk = 0; kk < 32; ++kk) {
      const float4 b4 = *(const float4*)&Ut[kk*128 + tx*4];
      #pragma unroll
      for (int q = 0; q < 8; ++q) {
        const float a = hT[(ty*8 + q)*33 + kk];
        acc[q][0] += a*b4.x; acc[q][1] += a*b4.y; acc[q][2] += a*b4.z; acc[q][3] += a*b4.w;
      }
    }
    __syncthreads();
  }
  float* Cb = C + (size_t)n*NBB*NOCC2;
  #pragma unroll
  for (int q = 0; q < 8; ++q)
    #pragma unroll
    for (int p = 0; p < 4; ++p)
      Cb[(size_t)(rt*64 + ty*8 + q)*NOCC2 + tx*4 + p] = acc[q][p];
}

// ---------------- E = sum(e_occ) + Tr(Uocc^T h Uocc) + nuc ----------------
__global__ __launch_bounds__(256) void k_final(const float* __restrict__ eig,
                                               const float* __restrict__ Uocc, const float* __restrict__ C,
                                               const float* __restrict__ pos, const int* __restrict__ numbers,
                                               float* __restrict__ E_out) {
  const int n = blockIdx.x, tid = threadIdx.x;
  __shared__ float rb[256];
  float local = 0.f;
  for (int i = tid; i < NOCC2; i += 256) local += eig[n*NBB + i];
  const float* Ub = Uocc + (size_t)n*NBB*NOCC2;
  const float* Cb = C + (size_t)n*NBB*NOCC2;
  for (int idx = tid; idx < NBB*NOCC2; idx += 256) local += Ub[idx]*Cb[idx];
  float ln = 0.f;
  for (int t = tid; t < NPAIR; t += 256) {
    int kk, ll;
    pair_decode(t, kk, ll);
    const float dx = pos[(n*NK + kk)*3 + 0] - pos[(n*NK + ll)*3 + 0];
    const float dy = pos[(n*NK + kk)*3 + 1] - pos[(n*NK + ll)*3 + 1];
    const float dz = pos[(n*NK + kk)*3 + 2] - pos[(n*NK + ll)*3 + 2];
    const float d2 = dx*dx + dy*dy + dz*dz;
    const float Z = (float)(numbers[kk]*numbers[ll]);
    ln += Z / sqrtf(d2);
  }
  local += ln * A0C;
  rb[tid] = local;
  __syncthreads();
  for (int s = 128; s > 0; s >>= 1) {
    if (tid < s) rb[tid] += rb[tid + s];
    __syncthreads();
  }
  if (tid == 0) E_out[n] = rb[0];
}

extern "C" void kernel_launch(void* const* d_in, const int* in_sizes, int n_in,
                              void* d_out, int out_size, void* d_ws, size_t ws_size,
                              hipStream_t stream) {
  (void)in_sizes; (void)n_in; (void)out_size; (void)ws_size;
  const float* mu      = (const float*)d_in[0];
  const float* hnew    = (const float*)d_in[1];
  const float* pos     = (const float*)d_in[2];
  const float* Foff    = (const float*)d_in[3];
  const float* tW      = (const float*)d_in[4];
  const float* tb      = (const float*)d_in[5];
  const float* Won     = (const float*)d_in[6];
  const float* bon     = (const float*)d_in[7];
  const float* Woff    = (const float*)d_in[8];
  const float* boff    = (const float*)d_in[9];
  const int*   numbers = (const int*)d_in[10];

  float* out   = (float*)d_out;
  float* Fout  = out;                               // [16][832][832]
  float* e_out = out + (size_t)NBATCH*NBB*NBB;      // [16][832]
  float* E_out = e_out + (size_t)NBATCH*NBB;        // [16]

  float* ws    = (float*)d_ws;
  float* Acopy = ws + OFF_ACOPY;
  float* xbuf  = ws + OFF_X;
  float* Sbuf  = ws + OFF_S;
  float* dA    = ws + OFF_D;
  float* subA  = ws + OFF_SUB;
  float* tauA  = ws + OFF_TAU;
  float* eig   = ws + OFF_EIG;
  float* Utri  = ws + OFF_UTRI;
  float* Uocc  = ws + OFF_UOCC;
  float* Cbuf  = ws + OFF_C;     // overlays Utri
  float* ybufA = ws + OFF_YBUF;  // overlays Utri (dead until k_invit)
  int*   barA  = (int*)(ws + OFF_BARC);

  // zero the per-matrix barrier counters (graph-captured; runs every replay)
  hipMemsetAsync((void*)barA, 0, NBATCH*sizeof(int), stream);

  k_x<<<dim3(NK, NBATCH), dim3(256), 0, stream>>>(mu, tW, tb, xbuf);
  k_S<<<dim3(NBATCH), dim3(256), 0, stream>>>(xbuf, Sbuf);
  k_diag<<<dim3(NK, NBATCH), dim3(256), 0, stream>>>(xbuf, Sbuf, Won, bon, hnew, Foff, Fout, Acopy);
  k_off<<<dim3(6, 16, NBATCH), dim3(256), 0, stream>>>(xbuf, Woff, boff, hnew, Foff, Fout, Acopy);
  k_tridiag_fused<<<dim3(GW, NBATCH), dim3(TPW), 0, stream>>>(Acopy, dA, subA, tauA, ybufA, barA);
  k_bisect<<<dim3(4, NBATCH), dim3(256), 0, stream>>>(dA, subA, eig, e_out);
  k_invit<<<dim3(NOCC2, NBATCH), dim3(64), 0, stream>>>(dA, subA, eig, Utri);
  k_backxform<<<dim3(4, NBATCH), dim3(512), 0, stream>>>(Acopy, tauA, Utri, Uocc);
  k_gemmC<<<dim3(13, NBATCH), dim3(256), 0, stream>>>(hnew, Uocc, Cbuf);
  k_final<<<dim3(NBATCH), dim3(256), 0, stream>>>(eig, Uocc, Cbuf, pos, numbers, E_out);
}

// Round 18
// 20449.329 us; speedup vs baseline: 3.8228x; 1.0010x over previous
//
#include <hip/hip_runtime.h>
#include <math.h>
#include <stdint.h>

// Problem constants
#define NBATCH 16
#define NK     32
#define NTDS   768      // 3*DS
#define NMM    676      // BM*BM
#define NBM    26
#define NBB    832      // B = K*BM
#define NOCC2  128
#define NPAIR  496      // K*(K-1)/2
#define FSCALE 1.0e-4f
#define A0C    0.5291772f

// ---------------- workspace layout (in floats) ----------------
#define OFF_ACOPY 0ull
#define SZ_ACOPY  (16ull*832*832)
#define OFF_X     (OFF_ACOPY + SZ_ACOPY)
#define SZ_X      (16ull*32*768)
#define OFF_S     (OFF_X + SZ_X)
#define SZ_S      (16ull*768)
#define OFF_D     (OFF_S + SZ_S)
#define OFF_SUB   (OFF_D   + 16ull*832)
#define OFF_TAU   (OFF_SUB + 16ull*832)
#define OFF_EIG   (OFF_TAU + 16ull*832)
#define OFF_UTRI  (OFF_EIG + 16ull*832)
#define SZ_UTRI   (16ull*128*832)
#define OFF_UOCC  (OFF_UTRI + SZ_UTRI)
#define OFF_C     OFF_UTRI   /* C overlays Utri (dead after backxform) */
// tridiag scratch overlays the Utri region (Utri written only later by k_invit)
#define PB   16   // panel width (full V/W panels LDS-resident in every WG)
#define GW   4    // workgroups per matrix
#define GWL2 2
#define TPW  1024 // threads per workgroup
#define NWV  16   // waves per WG
#define QMAX 208  // max own rows per WG (832/4)
#define OFF_YBUF  OFF_UTRI                        /* 16*832 floats (y exchange) */
#define OFF_BARC  (OFF_YBUF + 16ull*832)          /* 16 ints */

__device__ __forceinline__ void pair_decode(int t, int& k, int& l) {
  int kk = (int)((1.0f + sqrtf(1.0f + 8.0f*(float)t)) * 0.5f);
  while (kk*(kk-1)/2 > t) --kk;
  while ((kk+1)*kk/2 <= t) ++kk;
  k = kk; l = t - kk*(kk-1)/2;
}

// Cross-WG READ: agent-scope bypass load (sc0 sc1) — reads through to the MALL.
__device__ __forceinline__ float gld(const float* p) {
  unsigned int u = __hip_atomic_load((const unsigned int*)p, __ATOMIC_RELAXED, __HIP_MEMORY_SCOPE_AGENT);
  return __uint_as_float(u);
}
// Cross-WG WRITE: agent-scope bypass store (sc0 sc1) — write-through to MALL.
__device__ __forceinline__ void gst(float* p, float v) {
  __hip_atomic_store((unsigned int*)p, __float_as_uint(v), __ATOMIC_RELAXED, __HIP_MEMORY_SCOPE_AGENT);
}

// ---------------- x = mu @ transfer_W + b ----------------
__global__ __launch_bounds__(256) void k_x(const float* __restrict__ mu,
                                           const float* __restrict__ tW,
                                           const float* __restrict__ tb,
                                           float* __restrict__ x) {
  const int k = blockIdx.x, n = blockIdx.y, tid = threadIdx.x;
  __shared__ float mus[384];
  const float* mub = mu + (size_t)(n*NK + k)*384;
  for (int i = tid; i < 384; i += 256) mus[i] = mub[i];
  __syncthreads();
  float* xb = x + (size_t)(n*NK + k)*NTDS;
  for (int oo = tid; oo < NTDS; oo += 256) {
    const int d = oo >> 8, i = oo & 255;
    float acc = tb[i];
    const float* mrow = &mus[d*128];
    for (int a = 0; a < 128; ++a) acc += mrow[a]*tW[a*256 + i];
    xb[oo] = acc;
  }
}

// ---------------- S[n][dd] = sum_k x[n][k][dd] ----------------
__global__ __launch_bounds__(256) void k_S(const float* __restrict__ x, float* __restrict__ S) {
  const int n = blockIdx.x, tid = threadIdx.x;
  for (int dd = tid; dd < NTDS; dd += 256) {
    float s = 0.f;
    for (int k = 0; k < NK; ++k) s += x[(size_t)(n*NK + k)*NTDS + dd];
    S[n*NTDS + dd] = s;
  }
}

// ---------------- diagonal blocks ----------------
__global__ __launch_bounds__(256) void k_diag(const float* __restrict__ x, const float* __restrict__ S,
                                              const float* __restrict__ Won, const float* __restrict__ bon,
                                              const float* __restrict__ hnew, const float* __restrict__ Foff,
                                              float* __restrict__ Fout, float* __restrict__ Acopy) {
  const int k = blockIdx.x, n = blockIdx.y, tid = threadIdx.x;
  __shared__ float q[NTDS];
  __shared__ float M[NMM];
  const float* xb = x + (size_t)(n*NK + k)*NTDS;
  const float* Sb = S + n*NTDS;
  for (int i = tid; i < NTDS; i += 256) q[i] = xb[i]*Sb[i];
  __syncthreads();
  for (int m = tid; m < NMM; m += 256) {
    float acc = 32.0f * bon[m];
    for (int dd = 0; dd < NTDS; ++dd) acc += q[dd]*Won[(size_t)dd*NMM + m];
    M[m] = acc;
  }
  __syncthreads();
  const float* hb = hnew + (size_t)n*NBB*NBB;
  float* Fb = Fout + (size_t)n*NBB*NBB;
  float* Ab = Acopy + (size_t)n*NBB*NBB;
  for (int m = tid; m < NMM; m += 256) {
    const int a = m/26, b = m - a*26;
    const float val = 0.5f*(M[m] + M[b*26 + a]);
    const int P = k*26 + a, Q = k*26 + b;
    const size_t idx = (size_t)P*NBB + Q;
    const float fo = Foff[idx];
    const float hv = hb[idx];
    const float Fv = (fabsf(hv) > 1e-7f) ? (val*FSCALE + fo) : fo;
    Fb[idx] = Fv; Ab[idx] = Fv;
  }
}

// ---------------- off-diagonal blocks: GEMM over pairs ----------------
__global__ __launch_bounds__(256) void k_off(const float* __restrict__ x,
                                             const float* __restrict__ Woff, const float* __restrict__ boff,
                                             const float* __restrict__ hnew, const float* __restrict__ Foff,
                                             float* __restrict__ Fout, float* __restrict__ Acopy) {
  const int ct = blockIdx.x, pt = blockIdx.y, n = blockIdx.z;
  const int tid = threadIdx.x;
  __shared__ __align__(16) float At[32*65];
  __shared__ __align__(16) float Bt[64*128];
  __shared__ int klk[32], kll[32];
  if (tid < 32) {
    int pr = pt*32 + tid, kk = 1, ll = 0;
    if (pr < NPAIR) pair_decode(pr, kk, ll);
    klk[tid] = kk; kll[tid] = ll;
  }
  __syncthreads();
  const int ty = tid >> 5, tx = tid & 31;
  const int r0 = ty*4, c0 = tx*4;
  float acc[4][4] = {};
  for (int dd0 = 0; dd0 < NTDS; dd0 += 64) {
    for (int idx = tid; idx < 2048; idx += 256) {
      const int r = idx >> 6, c = idx & 63;
      const int pr = pt*32 + r;
      float v = 0.f;
      if (pr < NPAIR) {
        const int kk = klk[r], ll = kll[r];
        v = x[(size_t)(n*NK + kk)*NTDS + dd0 + c] * x[(size_t)(n*NK + ll)*NTDS + dd0 + c];
      }
      At[r*65 + c] = v;
    }
    for (int idx = tid; idx < 8192; idx += 256) {
      const int r = idx >> 7, c = idx & 127;
      const int col = ct*128 + c;
      Bt[idx] = (col < NMM) ? Woff[(size_t)(dd0 + r)*NMM + col] : 0.f;
    }
    __syncthreads();
    for (int kk = 0; kk < 64; ++kk) {
      float av[4];
      av[0] = At[(r0+0)*65 + kk];
      av[1] = At[(r0+1)*65 + kk];
      av[2] = At[(r0+2)*65 + kk];
      av[3] = At[(r0+3)*65 + kk];
      const float4 b4 = *(const float4*)&Bt[kk*128 + c0];
      const float bb[4] = {b4.x, b4.y, b4.z, b4.w};
      #pragma unroll
      for (int qq = 0; qq < 4; ++qq)
        #pragma unroll
        for (int pp = 0; pp < 4; ++pp)
          acc[qq][pp] += av[qq]*bb[pp];
    }
    __syncthreads();
  }
  const float* hb = hnew + (size_t)n*NBB*NBB;
  float* Fb = Fout + (size_t)n*NBB*NBB;
  float* Ab = Acopy + (size_t)n*NBB*NBB;
  for (int qq = 0; qq < 4; ++qq) {
    const int pr = pt*32 + r0 + qq;
    if (pr >= NPAIR) continue;
    const int kk = klk[r0+qq], ll = kll[r0+qq];
    for (int pp = 0; pp < 4; ++pp) {
      const int m = ct*128 + c0 + pp;
      if (m >= NMM) continue;
      const float val = acc[qq][pp] + boff[m];
      const int a = m/26, b = m - a*26;
      const int P = kk*26 + a, Q = ll*26 + b;
      const size_t i1 = (size_t)P*NBB + Q;
      const float fo1 = Foff[i1], hv1 = hb[i1];
      const float Fv1 = (fabsf(hv1) > 1e-7f) ? (val*FSCALE + fo1) : fo1;
      Fb[i1] = Fv1; Ab[i1] = Fv1;
      const size_t i2 = (size_t)Q*NBB + P;
      const float fo2 = Foff[i2], hv2 = hb[i2];
      const float Fv2 = (fabsf(hv2) > 1e-7f) ? (val*FSCALE + fo2) : fo2;
      Fb[i2] = Fv2; Ab[i2] = Fv2;
    }
  }
}

// ================= fused single-barrier latrd tridiagonalization =================
// R18 = R16 verbatim (proven: 13.8 ms, absmax 2.4e-4). R17's dual-matrix
// interleave produced wrong eigenvalues (unisolated race in the bundled
// {PB=8, deferred reflectors, split barriers} change) and is abandoned.
//   * c(k) read as SYMMETRIC ROW k (coalesced), issued at epoch start so its
//     MALL latency hides under complete_prev.
//   * complete_prev dots wave-parallelized (wave 0 -> vav, wave p -> d1/d2).
// Coherence: R7-proven primitives; dsum computed identically in every WG.
__device__ __forceinline__ void rbar(int* cnt, int target) {
  __syncthreads();
  if (threadIdx.x == 0) {
    asm volatile("" ::: "memory");
    __hip_atomic_fetch_add(cnt, 1, __ATOMIC_RELAXED, __HIP_MEMORY_SCOPE_AGENT);
    while (__hip_atomic_load(cnt, __ATOMIC_RELAXED, __HIP_MEMORY_SCOPE_AGENT) < target)
      __builtin_amdgcn_s_sleep(1);
    asm volatile("" ::: "memory");
  }
  __syncthreads();
}
__device__ __forceinline__ void gbar(int* cnt, int target) {
  __syncthreads();
  if (threadIdx.x == 0) {
    __hip_atomic_fetch_add(cnt, 1, __ATOMIC_RELEASE, __HIP_MEMORY_SCOPE_AGENT);  // wbl2
    while (__hip_atomic_load(cnt, __ATOMIC_RELAXED, __HIP_MEMORY_SCOPE_AGENT) < target)
      __builtin_amdgcn_s_sleep(1);
  }
  __syncthreads();
}

__device__ __forceinline__ float wg_reduce16(float v, volatile float* sred) {
  #pragma unroll
  for (int off = 32; off > 0; off >>= 1) v += __shfl_down(v, off);
  const int tid = threadIdx.x;
  if ((tid & 63) == 0) sred[tid >> 6] = v;
  __syncthreads();
  float r = 0.f;
  #pragma unroll
  for (int t = 0; t < NWV; ++t) r += sred[t];
  __syncthreads();
  return r;
}

__global__ __launch_bounds__(TPW) void k_tridiag_fused(float* __restrict__ Acopy,
                                                       float* __restrict__ dA,
                                                       float* __restrict__ subA,
                                                       float* __restrict__ tauA,
                                                       float* __restrict__ ybufA,
                                                       int* __restrict__ barA) {
  const int g = blockIdx.x;          // WG within matrix (0..GW-1)
  const int n = blockIdx.y;          // matrix
  const int tid = threadIdx.x;
  const int lane = tid & 63, wv = tid >> 6;
  float* A    = Acopy + (size_t)n*NBB*NBB;
  float* ybuf = ybufA + (size_t)n*NBB;
  int*   cnt  = barA + n;

  __shared__ float Vf[NBB*(PB+1)];   // [j][p], stride 17 (full panel, redundant)
  __shared__ float Wf[NBB*(PB+1)];
  __shared__ float vsh[NBB];
  __shared__ __align__(16) float vsh4[NBB];
  __shared__ float csh[NBB];
  __shared__ float ysh[NBB];
  __shared__ float dsum[32];         // [0]=vav, [1+p]=d1[p], [16+p]=d2[p]
  __shared__ float sred[NWV];
  __shared__ float taus[PB];
  int ep = 0;

  // complete column kprev (compute w(kprev), store into Vf/Wf col iprev)
  auto complete_prev = [&](int kprev, int iprev) {
    { int j = kprev+1+tid; if (j < NBB) ysh[j] = gld(&ybuf[j]); }
    __syncthreads();
    // wave-parallel dots: wave 0 -> vav; wave w in [1..iprev] -> d1/d2[w-1]
    if (wv == 0) {
      float pv = 0.f;
      for (int j = kprev+1+lane; j < NBB; j += 64) pv += vsh[j]*ysh[j];
      #pragma unroll
      for (int off = 32; off > 0; off >>= 1) pv += __shfl_down(pv, off);
      if (lane == 0) dsum[0] = pv;
    } else if (wv <= iprev) {
      const int p = wv - 1;
      float a1 = 0.f, a2 = 0.f;
      for (int j = kprev+1+lane; j < NBB; j += 64) {
        const float vj = vsh[j];
        a1 += Vf[j*(PB+1)+p]*vj;
        a2 += Wf[j*(PB+1)+p]*vj;
      }
      #pragma unroll
      for (int off = 32; off > 0; off >>= 1) { a1 += __shfl_down(a1, off); a2 += __shfl_down(a2, off); }
      if (lane == 0) { dsum[1+p] = a1; dsum[16+p] = a2; }
    }
    __syncthreads();
    const float tau = taus[iprev];
    float s12 = 0.f;
    for (int p = 0; p < iprev; ++p) s12 += dsum[1+p]*dsum[16+p];
    const float corr = 0.5f*tau*tau*(dsum[0] - 2.f*s12);
    { int j = kprev+1+tid;
      if (j < NBB) {
        float wacc = 0.f;
        #pragma unroll
        for (int p = 0; p < PB-1; ++p) if (p < iprev)
          wacc += Vf[j*(PB+1)+p]*dsum[16+p] + Wf[j*(PB+1)+p]*dsum[1+p];
        const float wj = tau*(ysh[j] - wacc) - corr*vsh[j];
        Wf[j*(PB+1)+iprev] = wj;
        Vf[j*(PB+1)+iprev] = vsh[j];
      }
    }
    __syncthreads();
  };

  for (int k0 = 0; k0 < NBB-2; k0 += PB) {
    const int ilim = (NBB-2-k0 < PB) ? (NBB-2-k0) : PB;
    for (int i = 0; i < ilim; ++i) {
      const int k = k0 + i;
      // early-issue raw c(k): SYMMETRIC row-k read (coalesced); row k is
      // stable within the panel, so issue before complete_prev to hide latency
      float craw = 0.f;
      { int j = k + tid; if (j < NBB) craw = gld(&A[(size_t)k*NBB + j]); }

      if (i > 0) complete_prev(k-1, i-1);

      // ---- c(k) = raw - panel corrections (redundant, rows j >= k) ----
      { int j = k + tid;
        if (j < NBB) {
          float cacc = 0.f;
          #pragma unroll
          for (int p = 0; p < PB; ++p) if (p < i)
            cacc += Vf[j*(PB+1)+p]*Wf[k*(PB+1)+p] + Wf[j*(PB+1)+p]*Vf[k*(PB+1)+p];
          csh[j] = craw - cacc;
        }
      }
      __syncthreads();
      // ---- norm/alpha/tau (redundant; bitwise identical across WGs) ----
      float np2 = 0.f;
      { int j2 = k+2+tid; if (j2 < NBB) { const float c = csh[j2]; np2 = c*c; } }
      const float nrm = wg_reduce16(np2, sred);
      const float alpha = csh[k+1];
      float tau, scale, beta;
      if (nrm < 1e-26f) { beta = alpha; tau = 0.f; scale = 0.f; }
      else {
        beta  = -copysignf(sqrtf(alpha*alpha + nrm), alpha);
        tau   = (beta - alpha) / beta;
        scale = 1.0f / (alpha - beta);
      }
      if (tid == 0) taus[i] = tau;
      if (g == 0 && tid == 0) {
        subA[n*NBB + k + 1] = beta;
        tauA[n*NBB + k] = tau;
        dA[n*NBB + k] = csh[k];
      }
      // ---- v(k) ----
      { int j3 = k+1+tid;
        if (j3 < NBB) {
          const float val = (j3 == k+1) ? 1.0f : csh[j3]*scale;
          vsh[j3] = val; vsh4[j3] = val;
        }
      }
      __syncthreads();
      // reflector publish (row k, BYPASS) by owner WG
      if (g == (k & (GW-1))) {
        int j4 = k+1+tid;
        if (j4 < NBB) gst(&A[(size_t)k*NBB + j4], vsh[j4]);
      }
      // ---- distributed matvec y(k) over OWN rows; publish via gst ----
      {
        const int cs = k+1;
        const int nh = (4 - (cs & 3)) & 3;
        const int ca = cs + nh;
        const int q0 = (k + GW - g) >> GWL2;
        for (int q = q0 + wv; q < QMAX; q += NWV) {
          const int jr = GW*q + g;
          const float* Ar = A + (size_t)jr*NBB;
          float acc = 0.f;
          if (lane < nh) acc += Ar[cs+lane]*vsh[cs+lane];
          for (int c = ca + 4*lane; c < NBB; c += 256) {
            const float4 a4 = *(const float4*)&Ar[c];
            const float4 v4 = *(const float4*)&vsh4[c];
            acc += a4.x*v4.x + a4.y*v4.y + a4.z*v4.z + a4.w*v4.w;
          }
          #pragma unroll
          for (int off = 32; off > 0; off >>= 1) acc += __shfl_down(acc, off);
          if (lane == 0) gst(&ybuf[jr], acc);
        }
      }
      ++ep; rbar(cnt, ep*GW);
    }

    // ---- panel boundary: finish last w, then syr2k (own rows, cached) ----
    if (k0 + PB < NBB-2) {
      const int kp = k0 + PB;
      complete_prev(kp-1, PB-1);
      const int q0s = (kp + GW-1 - g) >> GWL2;
      for (int q = q0s + wv; q < QMAX; q += NWV) {
        const int jr = GW*q + g;
        float vr[PB], wr[PB];
        #pragma unroll
        for (int p = 0; p < PB; ++p) { vr[p] = Vf[jr*(PB+1)+p]; wr[p] = Wf[jr*(PB+1)+p]; }
        for (int c = kp + lane; c < NBB; c += 64) {
          float acc = 0.f;
          #pragma unroll
          for (int p = 0; p < PB; ++p)
            acc += vr[p]*Wf[c*(PB+1)+p] + wr[p]*Vf[c*(PB+1)+p];
          A[(size_t)jr*NBB + c] -= acc;   // own row, cached (cleaned by gbar)
        }
      }
      ++ep; gbar(cnt, ep*GW);   // RELEASE: clean syr2k dirt before next panel's glds
    }
  }

  // ---- final: complete w(NBB-3), epilogue diagonals ----
  {
    const int k0l = ((NBB-3)/PB)*PB;
    const int npl = NBB-2-k0l;           // last-panel column count
    complete_prev(NBB-3, npl-1);
    if (g == 0 && tid == 0) {
      const int r2 = NBB-2, r1 = NBB-1;
      float dm2 = gld(&A[(size_t)r2*NBB + r2]);
      float dm1 = gld(&A[(size_t)r1*NBB + r1]);
      float sb  = gld(&A[(size_t)r1*NBB + r2]);
      for (int p = 0; p < npl; ++p) {
        dm2 -= 2.f*Vf[r2*(PB+1)+p]*Wf[r2*(PB+1)+p];
        dm1 -= 2.f*Vf[r1*(PB+1)+p]*Wf[r1*(PB+1)+p];
        sb  -= Vf[r1*(PB+1)+p]*Wf[r2*(PB+1)+p] + Wf[r1*(PB+1)+p]*Vf[r2*(PB+1)+p];
      }
      dA[n*NBB + r2] = dm2;
      dA[n*NBB + r1] = dm1;
      subA[n*NBB + r1] = sb;
      subA[n*NBB + 0] = 0.f;
      tauA[n*NBB + r2] = 0.f;
      tauA[n*NBB + r1] = 0.f;
    }
  }
}

// ---------------- all eigenvalues via bisection (Sturm counts) ----------------
__global__ __launch_bounds__(256) void k_bisect(const float* __restrict__ dA, const float* __restrict__ subA,
                                                float* __restrict__ eig, float* __restrict__ e_out) {
  const int n = blockIdx.y;
  const int i = blockIdx.x*256 + threadIdx.x;
  __shared__ float ds[NBB], ss[NBB];
  const float* dg = dA + n*NBB;
  const float* sg = subA + n*NBB;
  for (int j = threadIdx.x; j < NBB; j += 256) { ds[j] = dg[j]; ss[j] = sg[j]; }
  __syncthreads();
  if (i >= NBB) return;
  float lo = 1e30f, hi = -1e30f;
  for (int j = 0; j < NBB; ++j) {
    const float r = fabsf(ss[j]) + ((j+1 < NBB) ? fabsf(ss[j+1]) : 0.f);
    lo = fminf(lo, ds[j]-r); hi = fmaxf(hi, ds[j]+r);
  }
  const float pad = 1e-3f*(hi-lo) + 1e-3f;
  lo -= pad; hi += pad;
  for (int it = 0; it < 30; ++it) {
    const float mid = 0.5f*(lo+hi);
    int cnt = 0;
    float qv = ds[0]-mid;
    if (qv < 0.f) cnt++;
    for (int j = 1; j < NBB; ++j) {
      const float e = ss[j];
      if (fabsf(qv) < 1e-20f) qv = -1e-20f;
      qv = ds[j]-mid - e*e/qv;
      if (qv < 0.f) cnt++;
    }
    if (cnt > i) hi = mid; else lo = mid;
  }
  const float lam = 0.5f*(lo+hi);
  eig[n*NBB + i] = lam;
  e_out[n*NBB + i] = lam;
}

// ---------------- inverse iteration on T for the 128 lowest ----------------
__global__ __launch_bounds__(64) void k_invit(const float* __restrict__ dA, const float* __restrict__ subA,
                                              const float* __restrict__ eig, float* __restrict__ Utri) {
  const int i = blockIdx.x, n = blockIdx.y;
  const int lane = threadIdx.x;
  __shared__ float ds[NBB], ss[NBB], ud[NBB], u1[NBB], u2[NBB], yv[NBB], xv[NBB];
  const float* dg = dA + n*NBB;
  const float* sg = subA + n*NBB;
  for (int j = lane; j < NBB; j += 64) { ds[j] = dg[j]; ss[j] = sg[j]; }
  const float lam = eig[n*NBB + i];
  for (int j = lane; j < NBB; j += 64) {
    uint32_t s = (uint32_t)(j*2654435761u) ^ (uint32_t)(i*40503u + 977u) ^ (uint32_t)(n*9973u);
    s ^= s >> 16; s *= 0x7feb352dU; s ^= s >> 15; s *= 0x846ca68bU; s ^= s >> 16;
    yv[j] = 0.5f + (float)(s & 0xFFFF) * (1.0f/65536.0f);
  }
  __syncthreads();
  const float PIV = 3e-6f;
  for (int pass = 0; pass < 2; ++pass) {
    if (lane == 0) {
      float cd = ds[0] - lam;
      float cu = ss[1];
      float cy = yv[0];
      for (int j = 0; j < NBB-1; ++j) {
        const float bl = ss[j+1];
        const float bd = ds[j+1] - lam;
        const float bu = (j+2 < NBB) ? ss[j+2] : 0.f;
        const float yb = yv[j+1];
        float tud, tu1, tu2, tm, ncd, ncu, ny;
        if (fabsf(bl) > fabsf(cd)) {
          tud = bl; tu1 = bd; tu2 = bu;
          if (fabsf(tud) < PIV) tud = (tud < 0.f) ? -PIV : PIV;
          tm  = cd / tud;
          ncd = cu - tm*bd;
          ncu = -tm*bu;
          ny  = cy - tm*yb;
          yv[j] = yb;
        } else {
          tud = cd; tu1 = cu; tu2 = 0.f;
          if (fabsf(tud) < PIV) tud = (tud < 0.f) ? -PIV : PIV;
          tm  = bl / tud;
          ncd = bd - tm*cu;
          ncu = bu;
          ny  = yb - tm*cy;
          yv[j] = cy;
        }
        ud[j] = tud; u1[j] = tu1; u2[j] = tu2;
        cd = ncd; cu = ncu; cy = ny;
      }
      if (fabsf(cd) < PIV) cd = (cd < 0.f) ? -PIV : PIV;
      ud[NBB-1] = cd; u1[NBB-1] = 0.f; u2[NBB-1] = 0.f; yv[NBB-1] = cy;
      float x2 = yv[NBB-1]/ud[NBB-1];
      xv[NBB-1] = x2;
      float x1 = (yv[NBB-2] - u1[NBB-2]*x2)/ud[NBB-2];
      xv[NBB-2] = x1;
      for (int j = NBB-3; j >= 0; --j) {
        const float xj = (yv[j] - u1[j]*x1 - u2[j]*x2)/ud[j];
        xv[j] = xj;
        x2 = x1; x1 = xj;
      }
    }
    __syncthreads();
    float p2 = 0.f;
    for (int j = lane; j < NBB; j += 64) { const float t = xv[j]; p2 += t*t; }
    #pragma unroll
    for (int off = 32; off > 0; off >>= 1) p2 += __shfl_xor(p2, off);
    const float rin = rsqrtf(p2);
    if (pass == 0) {
      for (int j = lane; j < NBB; j += 64) yv[j] = xv[j]*rin;
      __syncthreads();
    } else {
      float* Ub = Utri + ((size_t)n*NOCC2 + i)*NBB;
      for (int j = lane; j < NBB; j += 64) Ub[j] = xv[j]*rin;
    }
  }
}

// ---------------- back-transform: Uocc = H0...H829 * Utri ----------------
#define RPT 52
__global__ __launch_bounds__(512) void k_backxform(const float* __restrict__ Acopy,
                                                   const float* __restrict__ tauA,
                                                   const float* __restrict__ Utri,
                                                   float* __restrict__ Uocc) {
  const int cg = blockIdx.x;         // column quarter (0..3)
  const int n = blockIdx.y;
  const int tid = threadIdx.x;
  const int jc = tid & 31, g = tid >> 5;   // 16 row-groups x 52 rows
  const int col = cg*32 + jc;
  __shared__ float vlds[2][NBB];
  __shared__ float sred[16*32];
  const float* A = Acopy + (size_t)n*NBB*NBB;
  float U[RPT];
  const float* Ut = Utri + ((size_t)n*NOCC2 + col)*NBB + g*RPT;
  #pragma unroll
  for (int rr = 0; rr < RPT; ++rr) U[rr] = Ut[rr];
  const int rbase = g*RPT;
  {
    const int k = NBB-3, mm = NBB-1-k;
    for (int idx = tid; idx < mm; idx += 512) vlds[0][idx] = A[(size_t)k*NBB + (k+1+idx)];
  }
  __syncthreads();
  int buf = 0;
  for (int k = NBB-3; k >= 0; --k) {
    float pf0 = 0.f, pf1 = 0.f;
    const int m2 = NBB - k;
    if (k > 0) {
      const float* Arow = A + (size_t)(k-1)*NBB + k;
      if (tid < m2) pf0 = Arow[tid];
      if (tid + 512 < m2) pf1 = Arow[tid + 512];
    }
    const float tau = tauA[n*NBB + k];
    if (tau != 0.f) {
      float part = 0.f;
      #pragma unroll
      for (int rr = 0; rr < RPT; ++rr) {
        const int r = rbase + rr;
        if (r > k) part += U[rr]*vlds[buf][r-k-1];
      }
      sred[g*32 + jc] = part;
      __syncthreads();
      float ssum = 0.f;
      #pragma unroll
      for (int t = 0; t < 16; ++t) ssum += sred[t*32 + jc];
      const float s = tau*ssum;
      #pragma unroll
      for (int rr = 0; rr < RPT; ++rr) {
        const int r = rbase + rr;
        if (r > k) U[rr] -= s*vlds[buf][r-k-1];
      }
    }
    if (k > 0) {
      if (tid < m2) vlds[buf^1][tid] = pf0;
      if (tid + 512 < m2) vlds[buf^1][tid + 512] = pf1;
    }
    __syncthreads();
    buf ^= 1;
  }
  float* Ub = Uocc + (size_t)n*NBB*NOCC2;
  #pragma unroll
  for (int rr = 0; rr < RPT; ++rr) Ub[(size_t)(rbase+rr)*NOCC2 + col] = U[rr];
}

// ---------------- C = h_new * Uocc  (832x832 @ 832x128 per batch) ----------------
__global__ __launch_bounds__(256) void k_gemmC(const float* __restrict__ h,
                                               const float* __restrict__ Uocc,
                                               float* __restrict__ C) {
  const int rt = blockIdx.x, n = blockIdx.y;
  const int tid = threadIdx.x;
  __shared__ __align__(16) float hT[64*33];
  __shared__ __align__(16) float Ut[32*128];
  const int ty = tid >> 5, tx = tid & 31;
  float acc[8][4] = {};
  const float* hb = h + (size_t)n*NBB*NBB + (size_t)rt*64*NBB;
  const float* Ub = Uocc + (size_t)n*NBB*NOCC2;
  for (int k0 = 0; k0 < NBB; k0 += 32) {
    for (int idx = tid; idx < 64*32; idx += 256) {
      const int r = idx >> 5, c = idx & 31;
      hT[r*33 + c] = hb[(size_t)r*NBB + k0 + c];
    }
    for (int idx = tid; idx < 32*128; idx += 256) {
      const int r = idx >> 7, c = idx & 127;
      Ut[idx] = Ub[(size_t)(k0 + r)*NOCC2 + c];
    }
    __syncthreads();
    for (int kk = 0; kk < 32; ++kk) {
      const float4 b4 = *(const float4*)&Ut[kk*128 + tx*4];
      #pragma unroll
      for (int q = 0; q < 8; ++q) {
        const float a = hT[(ty*8 + q)*33 + kk];
        acc[q][0] += a*b4.x; acc[q][1] += a*b4.y; acc[q][2] += a*b4.z; acc[q][3] += a*b4.w;
      }
    }
    __syncthreads();
  }
  float* Cb = C + (size_t)n*NBB*NOCC2;
  #pragma unroll
  for (int q = 0; q < 8; ++q)
    #pragma unroll
    for (int p = 0; p < 4; ++p)
      Cb[(size_t)(rt*64 + ty*8 + q)*NOCC2 + tx*4 + p] = acc[q][p];
}

// ---------------- E = sum(e_occ) + Tr(Uocc^T h Uocc) + nuc ----------------
__global__ __launch_bounds__(256) void k_final(const float* __restrict__ eig,
                                               const float* __restrict__ Uocc, const float* __restrict__ C,
                                               const float* __restrict__ pos, const int* __restrict__ numbers,
                                               float* __restrict__ E_out) {
  const int n = blockIdx.x, tid = threadIdx.x;
  __shared__ float rb[256];
  float local = 0.f;
  for (int i = tid; i < NOCC2; i += 256) local += eig[n*NBB + i];
  const float* Ub = Uocc + (size_t)n*NBB*NOCC2;
  const float* Cb = C + (size_t)n*NBB*NOCC2;
  for (int idx = tid; idx < NBB*NOCC2; idx += 256) local += Ub[idx]*Cb[idx];
  float ln = 0.f;
  for (int t = tid; t < NPAIR; t += 256) {
    int kk, ll;
    pair_decode(t, kk, ll);
    const float dx = pos[(n*NK + kk)*3 + 0] - pos[(n*NK + ll)*3 + 0];
    const float dy = pos[(n*NK + kk)*3 + 1] - pos[(n*NK + ll)*3 + 1];
    const float dz = pos[(n*NK + kk)*3 + 2] - pos[(n*NK + ll)*3 + 2];
    const float d2 = dx*dx + dy*dy + dz*dz;
    const float Z = (float)(numbers[kk]*numbers[ll]);
    ln += Z / sqrtf(d2);
  }
  local += ln * A0C;
  rb[tid] = local;
  __syncthreads();
  for (int s = 128; s > 0; s >>= 1) {
    if (tid < s) rb[tid] += rb[tid + s];
    __syncthreads();
  }
  if (tid == 0) E_out[n] = rb[0];
}

extern "C" void kernel_launch(void* const* d_in, const int* in_sizes, int n_in,
                              void* d_out, int out_size, void* d_ws, size_t ws_size,
                              hipStream_t stream) {
  (void)in_sizes; (void)n_in; (void)out_size; (void)ws_size;
  const float* mu      = (const float*)d_in[0];
  const float* hnew    = (const float*)d_in[1];
  const float* pos     = (const float*)d_in[2];
  const float* Foff    = (const float*)d_in[3];
  const float* tW      = (const float*)d_in[4];
  const float* tb      = (const float*)d_in[5];
  const float* Won     = (const float*)d_in[6];
  const float* bon     = (const float*)d_in[7];
  const float* Woff    = (const float*)d_in[8];
  const float* boff    = (const float*)d_in[9];
  const int*   numbers = (const int*)d_in[10];

  float* out   = (float*)d_out;
  float* Fout  = out;                               // [16][832][832]
  float* e_out = out + (size_t)NBATCH*NBB*NBB;      // [16][832]
  float* E_out = e_out + (size_t)NBATCH*NBB;        // [16]

  float* ws    = (float*)d_ws;
  float* Acopy = ws + OFF_ACOPY;
  float* xbuf  = ws + OFF_X;
  float* Sbuf  = ws + OFF_S;
  float* dA    = ws + OFF_D;
  float* subA  = ws + OFF_SUB;
  float* tauA  = ws + OFF_TAU;
  float* eig   = ws + OFF_EIG;
  float* Utri  = ws + OFF_UTRI;
  float* Uocc  = ws + OFF_UOCC;
  float* Cbuf  = ws + OFF_C;     // overlays Utri
  float* ybufA = ws + OFF_YBUF;  // overlays Utri (dead until k_invit)
  int*   barA  = (int*)(ws + OFF_BARC);

  // zero the per-matrix barrier counters (graph-captured; runs every replay)
  hipMemsetAsync((void*)barA, 0, NBATCH*sizeof(int), stream);

  k_x<<<dim3(NK, NBATCH), dim3(256), 0, stream>>>(mu, tW, tb, xbuf);
  k_S<<<dim3(NBATCH), dim3(256), 0, stream>>>(xbuf, Sbuf);
  k_diag<<<dim3(NK, NBATCH), dim3(256), 0, stream>>>(xbuf, Sbuf, Won, bon, hnew, Foff, Fout, Acopy);
  k_off<<<dim3(6, 16, NBATCH), dim3(256), 0, stream>>>(xbuf, Woff, boff, hnew, Foff, Fout, Acopy);
  k_tridiag_fused<<<dim3(GW, NBATCH), dim3(TPW), 0, stream>>>(Acopy, dA, subA, tauA, ybufA, barA);
  k_bisect<<<dim3(4, NBATCH), dim3(256), 0, stream>>>(dA, subA, eig, e_out);
  k_invit<<<dim3(NOCC2, NBATCH), dim3(64), 0, stream>>>(dA, subA, eig, Utri);
  k_backxform<<<dim3(4, NBATCH), dim3(512), 0, stream>>>(Acopy, tauA, Utri, Uocc);
  k_gemmC<<<dim3(13, NBATCH), dim3(256), 0, stream>>>(hnew, Uocc, Cbuf);
  k_final<<<dim3(NBATCH), dim3(256), 0, stream>>>(eig, Uocc, Cbuf, pos, numbers, E_out);
}